// Round 7
// baseline (631.406 us; speedup 1.0000x reference)
//
#include <hip/hip_runtime.h>
#include <cstddef>

#define NE 32768
#define NM 65536
#define NR 49152
#define NTOT 147456
#define E2 262144
#define NDPAD 65536
#define RPS 65537
#define W1T_OFF 131072
#define W2T_OFF 327680

typedef __attribute__((ext_vector_type(8))) short bf16x8;
typedef __attribute__((ext_vector_type(4))) float f32x4;
typedef __attribute__((ext_vector_type(2))) float f32x2;

__device__ __forceinline__ unsigned short f2bf(float x) {
    unsigned u = __float_as_uint(x);
    return (unsigned short)((u + 0x7FFFu + ((u >> 16) & 1u)) >> 16);
}
__device__ __forceinline__ float bf2f(unsigned s) { return __uint_as_float(s << 16); }
__device__ __forceinline__ unsigned pk2(float a, float b) {
    return (unsigned)f2bf(a) | ((unsigned)f2bf(b) << 16);
}
__device__ __forceinline__ bf16x8 pack8(const float* v) {
    union { bf16x8 b; unsigned u[4]; } r;
#pragma unroll
    for (int i = 0; i < 4; ++i) r.u[i] = pk2(v[2 * i], v[2 * i + 1]);
    return r.b;
}
__device__ __forceinline__ bf16x8 pack8v(f32x4 a, f32x4 b) {
    union { bf16x8 v; unsigned u[4]; } r;
    r.u[0] = pk2(a[0], a[1]); r.u[1] = pk2(a[2], a[3]);
    r.u[2] = pk2(b[0], b[1]); r.u[3] = pk2(b[2], b[3]);
    return r.v;
}
// fp8 e4m3 (OCP on gfx950) pack/unpack via HW converts
__device__ __forceinline__ unsigned short pkfp8(float a, float b) {
    return (unsigned short)__builtin_amdgcn_cvt_pk_fp8_f32(a, b, 0u, false);
}
__device__ __forceinline__ f32x2 upfp8(unsigned short v) {
    return __builtin_amdgcn_cvt_pk_f32_fp8((unsigned)v, false);
}
__device__ __forceinline__ void gll16(const void* g, void* l) {
    __builtin_amdgcn_global_load_lds(
        (const __attribute__((address_space(1))) void*)g,
        (__attribute__((address_space(3))) void*)l, 16, 0, 0);
}

// ---------------------------------------------------------------------------
// Weights -> bf16 FRAGMENT-PACKED (square mats; w1t nf-major; w2t ks-major).
// ---------------------------------------------------------------------------
__global__ __launch_bounds__(256) void convw(
    const float* __restrict__ wp, const float* __restrict__ wl,
    const float* __restrict__ w1, const float* __restrict__ w2,
    unsigned short* __restrict__ wbf)
{
    int i = blockIdx.x * 256 + threadIdx.x;
    float v;
    if (i < 131072) {
        int mat = i >> 14, r = i & 16383;
        int frag = r >> 9, lane = (r >> 3) & 63, j = r & 7;
        int nf = frag >> 2, ks = frag & 3;
        int n = nf * 16 + (lane & 15);
        int k = ks * 32 + (lane >> 4) * 8 + j;
        const float* src = (mat < 3) ? (wp + mat * 16384) : (wl + (mat - 3) * 16384);
        v = src[k * 128 + n];
    } else if (i < 327680) {
        int ii = i - 131072; int mat = ii >> 16, r = ii & 65535;
        int frag = r >> 9, lane = (r >> 3) & 63, j = r & 7;
        int nf = frag >> 2, ks = frag & 3;
        int n = nf * 16 + (lane & 15);
        int k = ks * 32 + (lane >> 4) * 8 + j;
        v = w1[mat * 65536 + k * 512 + n];
    } else {
        int ii = i - 327680; int mat = ii >> 16, r = ii & 65535;
        int frag = r >> 9, lane = (r >> 3) & 63, j = r & 7;
        int ks = frag >> 3, nf = frag & 7;
        int n = nf * 16 + (lane & 15);
        int k = ks * 32 + (lane >> 4) * 8 + j;
        v = w2[mat * 65536 + k * 128 + n];
    }
    wbf[i] = f2bf(v);
}

// ---------------------------------------------------------------------------
// WQ[site] = W . a  (128 x 8 logit-fold matrices), fragment-packed.
// ---------------------------------------------------------------------------
__global__ __launch_bounds__(256) void wqk(
    const float* __restrict__ wl, const float* __restrict__ a_src,
    const float* __restrict__ a_dst, unsigned short* __restrict__ wq)
{
    const int wi[7]  = {0, 2, 0, 1, 2, 3, 4};
    const int loi[7] = {0, 2, 0, 1, 2, 3, 4};
    const int lod[7] = {1, 1, 0, 0, 0, 0, 0};
    const int hii[7] = {-1, -1, -1, 1, -1, 3, 4};
    int site = blockIdx.x >> 2, ks = blockIdx.x & 3, t = threadIdx.x;
    const float* W = wl + wi[site] * 16384;
#pragma unroll
    for (int rep = 0; rep < 2; ++rep) {
        int e = t * 2 + rep;
        int lane = e >> 3, j = e & 7;
        int n = lane & 15;
        int k = ks * 32 + (lane >> 4) * 8 + j;
        float v = 0.f;
        if (n < 4) {
            const float* a = (lod[site] ? a_dst : a_src) + loi[site] * 128;
#pragma unroll 8
            for (int d = 0; d < 32; ++d) v += W[k * 128 + n * 32 + d] * a[n * 32 + d];
        } else if (n < 8 && hii[site] >= 0) {
            const float* a = a_dst + hii[site] * 128;
            int hh = n - 4;
#pragma unroll 8
            for (int d = 0; d < 32; ++d) v += W[k * 128 + hh * 32 + d] * a[hh * 32 + d];
        }
        wq[((site * 4 + ks) * 64 + lane) * 8 + j] = f2bf(v);
    }
}

// ---------------------------------------------------------------------------
__global__ __launch_bounds__(256) void ln1_kernel(
    const float* __restrict__ he, const float* __restrict__ hm, const float* __restrict__ hr,
    const float* __restrict__ g, const float* __restrict__ b, unsigned* __restrict__ nout)
{
    int row  = blockIdx.x * 4 + (threadIdx.x >> 6);
    int lane = threadIdx.x & 63;
    const float* src; int ti; int lr;
    if (row < NE)           { src = he; ti = 0; lr = row; }
    else if (row < NE + NM) { src = hm; ti = 1; lr = row - NE; }
    else                    { src = hr; ti = 2; lr = row - NE - NM; }
    float2 x = *(const float2*)(src + (size_t)lr * 128 + lane * 2);
    float s = x.x + x.y;
#pragma unroll
    for (int o = 32; o; o >>= 1) s += __shfl_xor(s, o);
    float mean = s * (1.0f / 128.0f);
    float dx = x.x - mean, dy = x.y - mean;
    float v = dx * dx + dy * dy;
#pragma unroll
    for (int o = 32; o; o >>= 1) v += __shfl_xor(v, o);
    float rstd = rsqrtf(v * (1.0f / 128.0f) + 1e-5f);
    int c = lane * 2;
    float y0 = g[ti * 128 + c]     * dx * rstd + b[ti * 128 + c];
    float y1 = g[ti * 128 + c + 1] * dy * rstd + b[ti * 128 + c + 1];
    nout[(size_t)row * 64 + lane] = pk2(y0, y1);
}

// ---------------------------------------------------------------------------
// GEMM + optional fused logits; Z output now FP8 (u16 = 2 cols per lane).
// ---------------------------------------------------------------------------
template <int LOG, bool BIAS>
__global__ __launch_bounds__(256) void gemm_v2(
    const unsigned short* __restrict__ A, const unsigned short* __restrict__ Wt,
    const float* __restrict__ bias, unsigned short* __restrict__ Zp,
    const unsigned short* __restrict__ WQ, float* __restrict__ oa, float* __restrict__ ob)
{
    __shared__ unsigned short WL[16384];
    int t = threadIdx.x, w = t >> 6, l = t & 63;
    int l15 = l & 15, lq = l >> 4;
#pragma unroll
    for (int i = 0; i < 8; ++i)
        gll16(Wt + i * 2048 + t * 8, (char*)WL + i * 4096 + t * 16);
    size_t row0 = (size_t)blockIdx.x * 128 + w * 32;
    f32x4 acc[2][8]; f32x4 accl[2];
#pragma unroll
    for (int r = 0; r < 2; ++r) {
        accl[r] = (f32x4){0.f, 0.f, 0.f, 0.f};
#pragma unroll
        for (int n = 0; n < 8; ++n) acc[r][n] = (f32x4){0.f, 0.f, 0.f, 0.f};
    }
    bf16x8 qf[4];
    if constexpr (LOG >= 1) {
#pragma unroll
        for (int ks = 0; ks < 4; ++ks) qf[ks] = *(const bf16x8*)(WQ + (ks * 64 + l) * 8);
    }
    __syncthreads();
#pragma unroll
    for (int ks = 0; ks < 4; ++ks) {
        int k0 = ks * 32 + lq * 8;
        bf16x8 a0 = *(const bf16x8*)(A + (row0 + l15) * 128 + k0);
        bf16x8 a1 = *(const bf16x8*)(A + (row0 + 16 + l15) * 128 + k0);
#pragma unroll
        for (int n = 0; n < 8; ++n) {
            bf16x8 bw = *(const bf16x8*)(WL + ((n * 4 + ks) * 64 + l) * 8);
            acc[0][n] = __builtin_amdgcn_mfma_f32_16x16x32_bf16(a0, bw, acc[0][n], 0, 0, 0);
            acc[1][n] = __builtin_amdgcn_mfma_f32_16x16x32_bf16(a1, bw, acc[1][n], 0, 0, 0);
        }
        if constexpr (LOG >= 1) {
            accl[0] = __builtin_amdgcn_mfma_f32_16x16x32_bf16(a0, qf[ks], accl[0], 0, 0, 0);
            accl[1] = __builtin_amdgcn_mfma_f32_16x16x32_bf16(a1, qf[ks], accl[1], 0, 0, 0);
        }
    }
#pragma unroll
    for (int n = 0; n < 4; ++n) {
        float bl = BIAS ? bias[n * 16 + l15] : 0.f;
        float bh = BIAS ? bias[n * 16 + l15 + 64] : 0.f;
#pragma unroll
        for (int r = 0; r < 2; ++r)
#pragma unroll
            for (int reg = 0; reg < 4; ++reg) {
                size_t row = row0 + r * 16 + lq * 4 + reg;
                Zp[row * 64 + n * 16 + l15] = pkfp8(acc[r][n][reg] + bl, acc[r][n + 4][reg] + bh);
            }
    }
    if constexpr (LOG >= 1) {
#pragma unroll
        for (int r = 0; r < 2; ++r)
#pragma unroll
            for (int reg = 0; reg < 4; ++reg) {
                size_t row = row0 + r * 16 + lq * 4 + reg;
                if (l15 < 4) oa[row * 4 + l15] = accl[r][reg];
                else if (LOG == 2 && l15 < 8) ob[row * 4 + (l15 - 4)] = accl[r][reg];
            }
    }
}

// ---------------------------------------------------------------------------
// CSR build, two-level bucket partition (unchanged).
// ---------------------------------------------------------------------------
struct P8 { const int* a[8]; };
#define CHUNK 2048

__global__ __launch_bounds__(256) void bucket_count(P8 dsts, unsigned* __restrict__ bcnt)
{
    __shared__ unsigned lh[256];
    int blk = blockIdx.x, rel = blk >> 7, cb = blk & 127, t = threadIdx.x;
    lh[t] = 0; __syncthreads();
    const int* dp = dsts.a[rel] + cb * CHUNK;
#pragma unroll
    for (int it = 0; it < 8; ++it) atomicAdd(&lh[dp[it * 256 + t] >> 8], 1u);
    __syncthreads();
    atomicAdd(&bcnt[rel * 256 + t], lh[t]);
}

__global__ __launch_bounds__(256) void scanB(const unsigned* __restrict__ bcnt,
                                             unsigned* __restrict__ bbase,
                                             unsigned* __restrict__ bcur)
{
    __shared__ unsigned ts[256];
    int t = threadIdx.x;
    unsigned v[8]; unsigned run = 0;
#pragma unroll
    for (int i = 0; i < 8; ++i) { v[i] = bcnt[t * 8 + i]; run += v[i]; }
    ts[t] = run; __syncthreads();
    for (int off = 1; off < 256; off <<= 1) {
        unsigned x = (t >= off) ? ts[t - off] : 0u;
        __syncthreads(); ts[t] += x; __syncthreads();
    }
    unsigned base = ts[t] - run;
#pragma unroll
    for (int i = 0; i < 8; ++i) { bbase[t * 8 + i] = base; bcur[t * 8 + i] = base; base += v[i]; }
    if (t == 255) bbase[2048] = base;
}

__global__ __launch_bounds__(256) void bucket_fill(P8 dsts, P8 srcs,
                                                   unsigned* __restrict__ bcur,
                                                   unsigned long long* __restrict__ bb)
{
    __shared__ unsigned lh[256], lbase[256], lcur[256];
    int blk = blockIdx.x, rel = blk >> 7, cb = blk & 127, t = threadIdx.x;
    lh[t] = 0; lcur[t] = 0; __syncthreads();
    const int* dp = dsts.a[rel] + cb * CHUNK;
    const int* sp = srcs.a[rel] + cb * CHUNK;
    int dv[8];
#pragma unroll
    for (int it = 0; it < 8; ++it) { dv[it] = dp[it * 256 + t]; atomicAdd(&lh[dv[it] >> 8], 1u); }
    __syncthreads();
    lbase[t] = atomicAdd(&bcur[rel * 256 + t], lh[t]);
    __syncthreads();
#pragma unroll
    for (int it = 0; it < 8; ++it) {
        unsigned e = (unsigned)(cb * CHUNK + it * 256 + t);
        unsigned d = (unsigned)dv[it];
        unsigned s = (unsigned)sp[it * 256 + t];
        unsigned pos = atomicAdd(&lcur[d >> 8], 1u);
        bb[lbase[d >> 8] + pos] =
            (unsigned long long)s | ((unsigned long long)d << 16) | ((unsigned long long)e << 32);
    }
}

__global__ __launch_bounds__(256) void bucket_hist(const unsigned long long* __restrict__ bb,
                                                   const unsigned* __restrict__ bbase,
                                                   unsigned* __restrict__ hist)
{
    __shared__ unsigned lh[256];
    int blk = blockIdx.x, rel = blk >> 8, b = blk & 255, t = threadIdx.x;
    lh[t] = 0; __syncthreads();
    unsigned s0 = bbase[blk], s1 = bbase[blk + 1];
    for (unsigned i = s0 + t; i < s1; i += 256)
        atomicAdd(&lh[(unsigned)(bb[i] >> 16) & 255u], 1u);
    __syncthreads();
    hist[(size_t)rel * NDPAD + b * 256 + t] = lh[t];
}

__global__ __launch_bounds__(256) void scan1(const unsigned* __restrict__ hist,
                                             unsigned* __restrict__ rowptr,
                                             unsigned* __restrict__ blksum)
{
    __shared__ unsigned s[256];
    int b = blockIdx.x, rel = b >> 8, c = b & 255, t = threadIdx.x;
    unsigned v = hist[(size_t)rel * NDPAD + c * 256 + t];
    s[t] = v; __syncthreads();
    for (int off = 1; off < 256; off <<= 1) {
        unsigned x = (t >= off) ? s[t - off] : 0u;
        __syncthreads();
        s[t] += x;
        __syncthreads();
    }
    rowptr[(size_t)rel * RPS + c * 256 + t] = s[t] - v;
    if (t == 255) blksum[rel * 256 + c] = s[255];
}

__global__ __launch_bounds__(256) void scan2(unsigned* __restrict__ blksum,
                                             unsigned* __restrict__ rowptr)
{
    __shared__ unsigned s[256];
    int rel = blockIdx.x, t = threadIdx.x;
    unsigned v = blksum[rel * 256 + t];
    s[t] = v; __syncthreads();
    for (int off = 1; off < 256; off <<= 1) {
        unsigned x = (t >= off) ? s[t - off] : 0u;
        __syncthreads();
        s[t] += x;
        __syncthreads();
    }
    blksum[rel * 256 + t] = s[t] - v;
    if (t == 255) rowptr[(size_t)rel * RPS + 65536] = s[255];
}

__global__ __launch_bounds__(256) void scan3(unsigned* __restrict__ rowptr,
                                             const unsigned* __restrict__ blksum)
{
    int b = blockIdx.x, rel = b >> 8, c = b & 255, t = threadIdx.x;
    rowptr[(size_t)rel * RPS + c * 256 + t] += blksum[rel * 256 + c];
}

__global__ __launch_bounds__(256) void bucket_place(const unsigned long long* __restrict__ bb,
                                                    const unsigned* __restrict__ bbase,
                                                    const unsigned* __restrict__ rowptr,
                                                    int2* __restrict__ epair)
{
    __shared__ unsigned lrp[256], lcur[256];
    int blk = blockIdx.x, rel = blk >> 8, b = blk & 255, t = threadIdx.x;
    lrp[t] = rowptr[(size_t)rel * RPS + b * 256 + t];
    lcur[t] = 0; __syncthreads();
    unsigned s0 = bbase[blk], s1 = bbase[blk + 1];
    for (unsigned i = s0 + t; i < s1; i += 256) {
        unsigned long long pk = bb[i];
        unsigned s = (unsigned)pk & 0xffffu;
        unsigned d8 = (unsigned)(pk >> 16) & 255u;
        unsigned e = (unsigned)(pk >> 32);
        unsigned pos = atomicAdd(&lcur[d8], 1u);
        epair[(size_t)rel * E2 + lrp[d8] + pos] = make_int2((int)s, (int)e);
    }
}

// ---------------------------------------------------------------------------
// Per-edge (ef @ M) EDGE-ORDERED, packed bf16x4.
// ---------------------------------------------------------------------------
__global__ __launch_bounds__(256) void ef4e_kernel(
    const float* __restrict__ efm, const float* __restrict__ efs,
    const float* __restrict__ efb, const float* __restrict__ eft,
    const float* __restrict__ we, const float* __restrict__ ae,
    uint2* __restrict__ ef4e)
{
    __shared__ float M[8][4];
    int b = blockIdx.x, t = threadIdx.x;
    int er = b >> 10;
    const float* ef = (er == 0) ? efm : (er == 1) ? efs : (er == 2) ? efb : eft;
    if (t < 32) {
        int f = t >> 2, hh = t & 3;
        float s = 0.f;
#pragma unroll 8
        for (int d = 0; d < 32; ++d) s += we[er * 1024 + f * 128 + hh * 32 + d] * ae[er * 128 + hh * 32 + d];
        M[f][hh] = s;
    }
    __syncthreads();
    int e = (b & 1023) * 256 + t;
    float4 a = *(const float4*)(ef + (size_t)e * 8);
    float4 c = *(const float4*)(ef + (size_t)e * 8 + 4);
    float o0 = a.x*M[0][0]+a.y*M[1][0]+a.z*M[2][0]+a.w*M[3][0]+c.x*M[4][0]+c.y*M[5][0]+c.z*M[6][0]+c.w*M[7][0];
    float o1 = a.x*M[0][1]+a.y*M[1][1]+a.z*M[2][1]+a.w*M[3][1]+c.x*M[4][1]+c.y*M[5][1]+c.z*M[6][1]+c.w*M[7][1];
    float o2 = a.x*M[0][2]+a.y*M[1][2]+a.z*M[2][2]+a.w*M[3][2]+c.x*M[4][2]+c.y*M[5][2]+c.z*M[6][2]+c.w*M[7][2];
    float o3 = a.x*M[0][3]+a.y*M[1][3]+a.z*M[2][3]+a.w*M[3][3]+c.x*M[4][3]+c.y*M[5][3]+c.z*M[6][3]+c.w*M[7][3];
    uint2 o; o.x = pk2(o0, o1); o.y = pk2(o2, o3);
    ef4e[(size_t)er * E2 + e] = o;
}

// ---------------------------------------------------------------------------
// Segment helpers: batch-8 pipelines, fp8 Z rows, 32-bit addressing.
// ---------------------------------------------------------------------------
__device__ __forceinline__ void phys_seg(
    const unsigned* __restrict__ rowptr, const int2* __restrict__ epair,
    const unsigned short* __restrict__ Zp, int d, unsigned lu, float& r0, float& r1)
{
    unsigned s0 = rowptr[d], s1 = rowptr[d + 1];
    float a0 = 0.f, a1 = 0.f;
    for (unsigned base = s0; base < s1; base += 8) {
        unsigned nb = s1 - base; if (nb > 8) nb = 8;
        unsigned zi[8];
#pragma unroll
        for (int i = 0; i < 8; ++i) {
            unsigned ci = base + ((unsigned)i < nb ? (unsigned)i : nb - 1);
            zi[i] = ((unsigned)epair[ci].x << 6) | lu;
        }
        unsigned short z[8];
#pragma unroll
        for (int i = 0; i < 8; ++i) z[i] = Zp[zi[i]];
#pragma unroll
        for (int i = 0; i < 8; ++i)
            if ((unsigned)i < nb) { f32x2 zf = upfp8(z[i]); a0 += zf.x; a1 += zf.y; }
    }
    int cnt = (int)(s1 - s0);
    float inv = 1.0f / (float)(cnt > 0 ? cnt : 1);
    r0 += a0 * inv; r1 += a1 * inv;
}

template <bool HAS_EF>
__device__ __forceinline__ void gat_seg(
    const unsigned* __restrict__ rowptr, const int2* __restrict__ epair,
    const unsigned short* __restrict__ Zp, const float* __restrict__ ls,
    const float* __restrict__ ld, const uint2* __restrict__ ef4e,
    int d, unsigned lu, int hs, float& r0, float& r1)
{
    float4 ldv4 = *(const float4*)(ld + ((unsigned)d << 2));
    float ldlo = hs ? ldv4.y : ldv4.x;
    float ldhi = hs ? ldv4.w : ldv4.z;
    unsigned s0 = rowptr[d], s1 = rowptr[d + 1];
    float n0 = 0.f, n1 = 0.f, dlo = 0.f, dhi = 0.f;
    for (unsigned base = s0; base < s1; base += 8) {
        unsigned nb = s1 - base; if (nb > 8) nb = 8;
        int2 ep[8];
#pragma unroll
        for (int i = 0; i < 8; ++i)
            ep[i] = epair[base + ((unsigned)i < nb ? (unsigned)i : nb - 1)];
        unsigned short z[8]; float4 lsv[8]; uint2 e4[8];
#pragma unroll
        for (int i = 0; i < 8; ++i) {
            z[i] = Zp[((unsigned)ep[i].x << 6) | lu];
            lsv[i] = *(const float4*)(ls + ((unsigned)ep[i].x << 2));
            if (HAS_EF) e4[i] = ef4e[(unsigned)ep[i].y];
        }
#pragma unroll
        for (int i = 0; i < 8; ++i) {
            if ((unsigned)i >= nb) break;
            float glo = (hs ? lsv[i].y : lsv[i].x) + ldlo;
            float ghi = (hs ? lsv[i].w : lsv[i].z) + ldhi;
            if (HAS_EF) {
                glo += bf2f(hs ? (e4[i].x >> 16) : (e4[i].x & 0xffffu));
                ghi += bf2f(hs ? (e4[i].y >> 16) : (e4[i].y & 0xffffu));
            }
            glo = glo > 0.f ? glo : 0.2f * glo;
            ghi = ghi > 0.f ? ghi : 0.2f * ghi;
            float xlo = __expf(glo), xhi = __expf(ghi);
            f32x2 zf = upfp8(z[i]);
            n0 += xlo * zf.x; dlo += xlo;
            n1 += xhi * zf.y; dhi += xhi;
        }
    }
    r0 += n0 / fmaxf(dlo, 1e-9f);
    r1 += n1 / fmaxf(dhi, 1e-9f);
}

// ---------------------------------------------------------------------------
// Gather kernels: single + dual-relation fused (one acc write per target).
// ---------------------------------------------------------------------------
template <bool ACC>
__global__ __launch_bounds__(256) void phys_gather(
    const unsigned* __restrict__ rowptr, const int2* __restrict__ epair,
    const unsigned short* __restrict__ Zp, unsigned* __restrict__ accp, int n_nodes)
{
    int t = threadIdx.x, w = t >> 6;
    unsigned lu = (unsigned)(t & 63);
    int d = blockIdx.x * 4 + w;
    if (d >= n_nodes) return;
    float r0 = 0.f, r1 = 0.f;
    phys_seg(rowptr, epair, Zp, d, lu, r0, r1);
    unsigned* ap = accp + (((unsigned)d << 6) | lu);
    if (ACC) { unsigned o = *ap; r0 += bf2f(o & 0xffffu); r1 += bf2f(o >> 16); }
    *ap = pk2(r0, r1);
}

template <bool ACC>
__global__ __launch_bounds__(256) void dual_phys(
    const unsigned* __restrict__ rpA, const int2* __restrict__ epA,
    const unsigned short* __restrict__ ZA,
    const unsigned* __restrict__ rpB, const int2* __restrict__ epB,
    const unsigned short* __restrict__ ZB,
    unsigned* __restrict__ accp, int n_nodes)
{
    int t = threadIdx.x, w = t >> 6;
    unsigned lu = (unsigned)(t & 63);
    int d = blockIdx.x * 4 + w;
    if (d >= n_nodes) return;
    float r0 = 0.f, r1 = 0.f;
    phys_seg(rpA, epA, ZA, d, lu, r0, r1);
    phys_seg(rpB, epB, ZB, d, lu, r0, r1);
    unsigned* ap = accp + (((unsigned)d << 6) | lu);
    if (ACC) { unsigned o = *ap; r0 += bf2f(o & 0xffffu); r1 += bf2f(o >> 16); }
    *ap = pk2(r0, r1);
}

template <bool EF, bool ACC>
__global__ __launch_bounds__(256) void gat_gather(
    const unsigned* __restrict__ rowptr, const int2* __restrict__ epair,
    const unsigned short* __restrict__ Zp, const float* __restrict__ ls,
    const float* __restrict__ ld, const uint2* __restrict__ ef4e,
    unsigned* __restrict__ accp, int n_nodes)
{
    int t = threadIdx.x, w = t >> 6;
    unsigned lu = (unsigned)(t & 63);
    int d = blockIdx.x * 4 + w;
    if (d >= n_nodes) return;
    int hs = (int)(lu >> 5);
    float r0 = 0.f, r1 = 0.f;
    gat_seg<EF>(rowptr, epair, Zp, ls, ld, ef4e, d, lu, hs, r0, r1);
    unsigned* ap = accp + (((unsigned)d << 6) | lu);
    if (ACC) { unsigned o = *ap; r0 += bf2f(o & 0xffffu); r1 += bf2f(o >> 16); }
    *ap = pk2(r0, r1);
}

template <bool EFA, bool EFB, bool ACC>
__global__ __launch_bounds__(256) void dual_gat(
    const unsigned* __restrict__ rpA, const int2* __restrict__ epA,
    const unsigned short* __restrict__ ZA, const float* __restrict__ lsA,
    const float* __restrict__ ldA, const uint2* __restrict__ efA,
    const unsigned* __restrict__ rpB, const int2* __restrict__ epB,
    const unsigned short* __restrict__ ZB, const float* __restrict__ lsB,
    const float* __restrict__ ldB, const uint2* __restrict__ efB,
    unsigned* __restrict__ accp, int n_nodes)
{
    int t = threadIdx.x, w = t >> 6;
    unsigned lu = (unsigned)(t & 63);
    int d = blockIdx.x * 4 + w;
    if (d >= n_nodes) return;
    int hs = (int)(lu >> 5);
    float r0 = 0.f, r1 = 0.f;
    gat_seg<EFA>(rpA, epA, ZA, lsA, ldA, efA, d, lu, hs, r0, r1);
    gat_seg<EFB>(rpB, epB, ZB, lsB, ldB, efB, d, lu, hs, r0, r1);
    unsigned* ap = accp + (((unsigned)d << 6) | lu);
    if (ACC) { unsigned o = *ap; r0 += bf2f(o & 0xffffu); r1 += bf2f(o >> 16); }
    *ap = pk2(r0, r1);
}

// ---------------------------------------------------------------------------
// FFN v5 (unchanged): 128 rows/block, double-buffered weight LDS.
// ---------------------------------------------------------------------------
__global__ __launch_bounds__(256, 2) void ffn_v5(
    const float* __restrict__ h, const unsigned* __restrict__ accp,
    const float* __restrict__ g, const float* __restrict__ b,
    const unsigned short* __restrict__ w1t, const float* __restrict__ b1,
    const unsigned short* __restrict__ w2t, const float* __restrict__ b2,
    float* __restrict__ out, float invC)
{
    __shared__ unsigned short WB[2][16384];
    __shared__ float HW[4][1024];
    int t = threadIdx.x, w = t >> 6, l = t & 63;
    int l15 = l & 15, lq = l >> 4;
    size_t rw = (size_t)blockIdx.x * 128 + w * 32;
    float* myHW = HW[w];

    bf16x8 af[2][4];
#pragma unroll
    for (int rf = 0; rf < 2; ++rf) {
        size_t myrow = rw + rf * 16 + l15;
        const unsigned* ap = accp + myrow * 64 + lq * 8;
        uint4 ua0 = *(const uint4*)(ap);
        uint4 ua1 = *(const uint4*)(ap + 4);
        uint4 ub0 = *(const uint4*)(ap + 32);
        uint4 ub1 = *(const uint4*)(ap + 36);
        const float* hp = h + myrow * 128 + lq * 8;
        float4 hf[4][2];
        hf[0][0] = *(const float4*)(hp);      hf[0][1] = *(const float4*)(hp + 4);
        hf[1][0] = *(const float4*)(hp + 32); hf[1][1] = *(const float4*)(hp + 36);
        hf[2][0] = *(const float4*)(hp + 64); hf[2][1] = *(const float4*)(hp + 68);
        hf[3][0] = *(const float4*)(hp + 96); hf[3][1] = *(const float4*)(hp + 100);
        unsigned ua[8] = {ua0.x, ua0.y, ua0.z, ua0.w, ua1.x, ua1.y, ua1.z, ua1.w};
        unsigned ub[8] = {ub0.x, ub0.y, ub0.z, ub0.w, ub1.x, ub1.y, ub1.z, ub1.w};
        float hv[4][8];
#pragma unroll
        for (int j = 0; j < 8; ++j) {
            hv[0][j] = ((const float*)hf[0])[j] + bf2f(ua[j] & 0xffffu) * invC;
            hv[1][j] = ((const float*)hf[1])[j] + bf2f(ub[j] & 0xffffu) * invC;
            hv[2][j] = ((const float*)hf[2])[j] + bf2f(ua[j] >> 16) * invC;
            hv[3][j] = ((const float*)hf[3])[j] + bf2f(ub[j] >> 16) * invC;
        }
        float s = 0.f;
#pragma unroll
        for (int ks = 0; ks < 4; ++ks)
#pragma unroll
            for (int j = 0; j < 8; ++j) s += hv[ks][j];
        s += __shfl_xor(s, 16); s += __shfl_xor(s, 32);
        float mean = s * (1.0f / 128.0f);
        float v = 0.f;
#pragma unroll
        for (int ks = 0; ks < 4; ++ks)
#pragma unroll
            for (int j = 0; j < 8; ++j) { float dd = hv[ks][j] - mean; v += dd * dd; }
        v += __shfl_xor(v, 16); v += __shfl_xor(v, 32);
        float rstd = rsqrtf(v * (1.0f / 128.0f) + 1e-5f);
#pragma unroll
        for (int ks = 0; ks < 4; ++ks) {
            int col0 = ks * 32 + lq * 8;
            float y[8];
#pragma unroll
            for (int j = 0; j < 8; ++j)
                y[j] = g[col0 + j] * (hv[ks][j] - mean) * rstd + b[col0 + j];
            af[rf][ks] = pack8(y);
        }
    }

#pragma unroll
    for (int i = 0; i < 4; ++i) {
        gll16(w1t + i * 2048 + t * 8, (char*)WB[0] + i * 4096 + t * 16);
        gll16(w2t + i * 2048 + t * 8, (char*)WB[0] + 16384 + i * 4096 + t * 16);
    }
    f32x4 facc[2][8];
#pragma unroll
    for (int rf = 0; rf < 2; ++rf)
#pragma unroll
        for (int n = 0; n < 8; ++n) facc[rf][n] = (f32x4){0.f, 0.f, 0.f, 0.f};
    __syncthreads();

    int buf = 0;
    int swR = (l15 & 7) << 2;
    for (int ch = 0; ch < 8; ++ch) {
        if (ch < 7) {
            const unsigned short* s1p = w1t + (ch + 1) * 8192;
            const unsigned short* s2p = w2t + (ch + 1) * 8192;
#pragma unroll
            for (int i = 0; i < 4; ++i) {
                gll16(s1p + i * 2048 + t * 8, (char*)WB[buf ^ 1] + i * 4096 + t * 16);
                gll16(s2p + i * 2048 + t * 8, (char*)WB[buf ^ 1] + 16384 + i * 4096 + t * 16);
            }
        }
        f32x4 acc1[2][4];
#pragma unroll
        for (int rf = 0; rf < 2; ++rf)
#pragma unroll
            for (int n = 0; n < 4; ++n) acc1[rf][n] = (f32x4){0.f, 0.f, 0.f, 0.f};
#pragma unroll
        for (int ks = 0; ks < 4; ++ks)
#pragma unroll
            for (int nf = 0; nf < 4; ++nf) {
                bf16x8 bw = *(const bf16x8*)(WB[buf] + ((nf * 4 + ks) * 64 + l) * 8);
                acc1[0][nf] = __builtin_amdgcn_mfma_f32_16x16x32_bf16(af[0][ks], bw, acc1[0][nf], 0, 0, 0);
                acc1[1][nf] = __builtin_amdgcn_mfma_f32_16x16x32_bf16(af[1][ks], bw, acc1[1][nf], 0, 0, 0);
            }
#pragma unroll
        for (int rf = 0; rf < 2; ++rf) {
#pragma unroll
            for (int nf = 0; nf < 4; ++nf) {
                float bv = b1[ch * 64 + nf * 16 + l15];
#pragma unroll
                for (int reg = 0; reg < 4; ++reg) {
                    int row = lq * 4 + reg;
                    float x = acc1[rf][nf][reg] + bv;
                    float ge = 0.5f * x * (1.0f + erff(x * 0.70710678118654752f));
                    myHW[row * 64 + ((nf * 16 + l15) ^ ((row & 7) << 2))] = ge;
                }
            }
#pragma unroll
            for (int ks2 = 0; ks2 < 2; ++ks2) {
                int cb = ks2 * 32 + lq * 8;
                f32x4 x0 = *(const f32x4*)(myHW + l15 * 64 + (cb ^ swR));
                f32x4 x1 = *(const f32x4*)(myHW + l15 * 64 + ((cb + 4) ^ swR));
                bf16x8 a2 = pack8v(x0, x1);
#pragma unroll
                for (int nf = 0; nf < 8; ++nf) {
                    bf16x8 bw = *(const bf16x8*)(WB[buf] + 8192 + ((ks2 * 8 + nf) * 64 + l) * 8);
                    facc[rf][nf] = __builtin_amdgcn_mfma_f32_16x16x32_bf16(a2, bw, facc[rf][nf], 0, 0, 0);
                }
            }
        }
        __syncthreads();
        buf ^= 1;
    }
#pragma unroll
    for (int rf = 0; rf < 2; ++rf)
#pragma unroll
        for (int nf = 0; nf < 8; ++nf) {
            int col = nf * 16 + l15;
            float bv = b2[col];
            int ci = col & 63;
            bool hi = col >= 64;
#pragma unroll
            for (int reg = 0; reg < 4; ++reg) {
                size_t row = rw + rf * 16 + lq * 4 + reg;
                unsigned pv = accp[row * 64 + ci];
                float av = bf2f(hi ? (pv >> 16) : (pv & 0xffffu));
                out[row * 128 + col] = h[row * 128 + col] + av * invC + facc[rf][nf][reg] + bv;
            }
        }
}

// ---------------------------------------------------------------------------
extern "C" void kernel_launch(void* const* d_in, const int* in_sizes, int n_in,
                              void* d_out, int out_size, void* d_ws, size_t ws_size,
                              hipStream_t stream)
{
    const float* h_enz  = (const float*)d_in[0];
    const float* h_met  = (const float*)d_in[1];
    const float* h_rxn  = (const float*)d_in[2];
    const float* ef_mod = (const float*)d_in[3];
    const float* ef_sig = (const float*)d_in[4];
    const float* ef_brg = (const float*)d_in[5];
    const float* ef_trn = (const float*)d_in[6];
    const float* ln1_g  = (const float*)d_in[7];
    const float* ln1_b  = (const float*)d_in[8];
    const float* ln2_g  = (const float*)d_in[9];
    const float* ln2_b  = (const float*)d_in[10];
    const float* wp     = (const float*)d_in[11];
    const float* bp     = (const float*)d_in[12];
    const float* wl     = (const float*)d_in[13];
    const float* a_src  = (const float*)d_in[14];
    const float* a_dst  = (const float*)d_in[15];
    const float* we     = (const float*)d_in[16];
    const float* a_edge = (const float*)d_in[17];
    const float* w1     = (const float*)d_in[18];
    const float* b1     = (const float*)d_in[19];
    const float* w2     = (const float*)d_in[20];
    const float* b2     = (const float*)d_in[21];
    const int* src_sub  = (const int*)d_in[22];
    const int* dst_sub  = (const int*)d_in[23];
    const int* src_prod = (const int*)d_in[24];
    const int* dst_prod = (const int*)d_in[25];
    const int* src_cat  = (const int*)d_in[26];
    const int* dst_cat  = (const int*)d_in[27];
    const int* src_mod  = (const int*)d_in[28];
    const int* dst_mod  = (const int*)d_in[29];
    const int* src_reg  = (const int*)d_in[30];
    const int* dst_reg  = (const int*)d_in[31];
    const int* src_sig  = (const int*)d_in[32];
    const int* dst_sig  = (const int*)d_in[33];
    const int* src_brg  = (const int*)d_in[34];
    const int* dst_brg  = (const int*)d_in[35];
    const int* src_trn  = (const int*)d_in[36];
    const int* dst_trn  = (const int*)d_in[37];
    float* out = (float*)d_out;

    // workspace (~92 MB; proven budget >= 116.6 MB)
    char* p = (char*)d_ws;
    unsigned* accp = (unsigned*)p;            p += (size_t)NTOT * 64 * 4;     // 37.75 MB
    unsigned short* ZpA = (unsigned short*)p; p += (size_t)NM * 64 * 2;       // 8.39 MB
    unsigned long long* bukbuf = (unsigned long long*)p;                      // alias (16.78):
    unsigned short* ZpB = (unsigned short*)p; p += (size_t)8 * E2 * 8;        // 16.78 MB
    int2* epair = (int2*)p;                   p += (size_t)8 * E2 * 8;        // 16.78 MB
    unsigned* hist = (unsigned*)p;                                            // alias:
    uint2* ef4e = (uint2*)p;                  p += (size_t)4 * E2 * 8;        // 8.39 MB
    float* ls3 = (float*)p;                   p += (size_t)NE * 4 * 4;
    float* ld3 = (float*)p;                   p += (size_t)NR * 4 * 4;
    float* ls4 = (float*)p;                   p += (size_t)NE * 4 * 4;
    float* ld4 = (float*)p;                   p += (size_t)NE * 4 * 4;
    float* ls5 = (float*)p;                   p += (size_t)NM * 4 * 4;
    float* ld5 = (float*)p;                   p += (size_t)NE * 4 * 4;
    float* ls6 = (float*)p;                   p += (size_t)NM * 4 * 4;
    float* ld6 = (float*)p;                   p += (size_t)NM * 4 * 4;
    float* ls7 = (float*)p;                   p += (size_t)NM * 4 * 4;
    float* ld7 = (float*)p;                   p += (size_t)NM * 4 * 4;
    unsigned short* wbf = (unsigned short*)p; p += (size_t)524288 * 2;
    unsigned short* wq  = (unsigned short*)p; p += (size_t)7 * 2048 * 2;
    unsigned* rowptr = (unsigned*)p;          p += (size_t)8 * RPS * 4;
    unsigned* bcnt = (unsigned*)p;            p += 2048 * 4;
    unsigned* bbase = (unsigned*)p;           p += 2049 * 4;
    unsigned* bcur = (unsigned*)p;            p += 2048 * 4;
    unsigned* blksum = (unsigned*)p;          p += (size_t)8 * 256 * 4;
    if (ws_size < (size_t)(p - (char*)d_ws)) return;

    unsigned* nrm32 = (unsigned*)d_out;
    const unsigned short* nbf_enz = (const unsigned short*)d_out;
    const unsigned short* nbf_met = nbf_enz + (size_t)NE * 128;
    const unsigned short* nbf_rxn = nbf_enz + (size_t)(NE + NM) * 128;
    unsigned* acc_enz = accp;
    unsigned* acc_met = accp + (size_t)NE * 64;
    unsigned* acc_rxn = accp + (size_t)(NE + NM) * 64;

    P8 dsts, srcs;
    dsts.a[0] = dst_sub;  srcs.a[0] = src_sub;
    dsts.a[1] = dst_prod; srcs.a[1] = src_prod;
    dsts.a[2] = dst_cat;  srcs.a[2] = src_cat;
    dsts.a[3] = dst_mod;  srcs.a[3] = src_mod;
    dsts.a[4] = dst_reg;  srcs.a[4] = src_reg;
    dsts.a[5] = dst_sig;  srcs.a[5] = src_sig;
    dsts.a[6] = dst_brg;  srcs.a[6] = src_brg;
    dsts.a[7] = dst_trn;  srcs.a[7] = src_trn;

    // ---- prep: weights, LN1, bucketed CSR, edge-ordered ef.M
    hipMemsetAsync(bcnt, 0, 2048 * 4, stream);
    convw<<<2048, 256, 0, stream>>>(wp, wl, w1, w2, wbf);
    ln1_kernel<<<NTOT / 4, 256, 0, stream>>>(h_enz, h_met, h_rxn, ln1_g, ln1_b, nrm32);
    wqk<<<28, 256, 0, stream>>>(wl, a_src, a_dst, wq);
    bucket_count<<<1024, 256, 0, stream>>>(dsts, bcnt);
    scanB<<<1, 256, 0, stream>>>(bcnt, bbase, bcur);
    bucket_fill<<<1024, 256, 0, stream>>>(dsts, srcs, bcur, bukbuf);
    bucket_hist<<<2048, 256, 0, stream>>>(bukbuf, bbase, hist);
    scan1<<<2048, 256, 0, stream>>>(hist, rowptr, blksum);
    scan2<<<8, 256, 0, stream>>>(blksum, rowptr);
    scan3<<<2048, 256, 0, stream>>>(rowptr, blksum);
    bucket_place<<<2048, 256, 0, stream>>>(bukbuf, bbase, rowptr, epair);
    ef4e_kernel<<<4096, 256, 0, stream>>>(ef_mod, ef_sig, ef_brg, ef_trn, we, a_edge, ef4e);

#define RP(r) (rowptr + (size_t)(r) * RPS)
#define EP(r) (epair + (size_t)(r) * E2)
#define WQS(s) (wq + (size_t)(s) * 2048)
#define EF4(er) (ef4e + (size_t)(er) * E2)

    // ---- rxn: rel0 (met, phys) + rel2 (enz, phys) fused; then rel3 (gat)
    gemm_v2<0, true><<<NM / 128, 256, 0, stream>>>(nbf_met, wbf + 0 * 16384, bp + 0, ZpA,
                                                   nullptr, nullptr, nullptr);
    gemm_v2<1, true><<<NE / 128, 256, 0, stream>>>(nbf_enz, wbf + 2 * 16384, bp + 256, ZpB,
                                                   WQS(1), ld5, nullptr);
    dual_phys<false><<<NR / 4, 256, 0, stream>>>(RP(0), EP(0), ZpA, RP(2), EP(2), ZpB,
                                                 acc_rxn, NR);
    // ---- rel1 (rxn->met, phys) init acc_met; gemm also emits rel3 dst logits
    gemm_v2<1, true><<<NR / 128, 256, 0, stream>>>(nbf_rxn, wbf + 1 * 16384, bp + 128, ZpA,
                                                   WQS(0), ld3, nullptr);
    phys_gather<false><<<NM / 4, 256, 0, stream>>>(RP(1), EP(1), ZpA, acc_met, NM);
    // ---- rel3 (enz->rxn, gat + ef) accum acc_rxn
    gemm_v2<1, false><<<NE / 128, 256, 0, stream>>>(nbf_enz, wbf + 3 * 16384, nullptr, ZpB,
                                                    WQS(2), ls3, nullptr);
    gat_gather<true, true><<<NR / 4, 256, 0, stream>>>(RP(3), EP(3), ZpB, ls3, ld3, EF4(0),
                                                       acc_rxn, NR);
    // ---- enz: rel4 (no ef) + rel5 (ef) fused, single write
    gemm_v2<2, false><<<NE / 128, 256, 0, stream>>>(nbf_enz, wbf + 4 * 16384, nullptr, ZpA,
                                                    WQS(3), ls4, ld4);
    gemm_v2<1, false><<<NM / 128, 256, 0, stream>>>(nbf_met, wbf + 5 * 16384, nullptr, ZpB,
                                                    WQS(4), ls5, nullptr);
    dual_gat<false, true, false><<<NE / 4, 256, 0, stream>>>(
        RP(4), EP(4), ZpA, ls4, ld4, nullptr,
        RP(5), EP(5), ZpB, ls5, ld5, EF4(1), acc_enz, NE);
    // ---- met: rel6 + rel7 fused, accum onto rel1's init
    gemm_v2<2, false><<<NM / 128, 256, 0, stream>>>(nbf_met, wbf + 6 * 16384, nullptr, ZpA,
                                                    WQS(5), ls6, ld6);
    gemm_v2<2, false><<<NM / 128, 256, 0, stream>>>(nbf_met, wbf + 7 * 16384, nullptr, ZpB,
                                                    WQS(6), ls7, ld7);
    dual_gat<true, true, true><<<NM / 4, 256, 0, stream>>>(
        RP(6), EP(6), ZpA, ls6, ld6, EF4(2),
        RP(7), EP(7), ZpB, ls7, ld7, EF4(3), acc_met, NM);

    // ---- fused combine + LN2 + FFN (+residual), per node type
    ffn_v5<<<NE / 128, 256, 0, stream>>>(h_enz, acc_enz, ln2_g + 0, ln2_b + 0,
                                         wbf + W1T_OFF + 0 * 65536, b1 + 0,
                                         wbf + W2T_OFF + 0 * 65536, b2 + 0,
                                         out + 0, 0.5f);
    ffn_v5<<<NM / 128, 256, 0, stream>>>(h_met, acc_met, ln2_g + 128, ln2_b + 128,
                                         wbf + W1T_OFF + 1 * 65536, b1 + 512,
                                         wbf + W2T_OFF + 1 * 65536, b2 + 128,
                                         out + (size_t)NE * 128, 1.0f / 3.0f);
    ffn_v5<<<NR / 128, 256, 0, stream>>>(h_rxn, acc_rxn, ln2_g + 256, ln2_b + 256,
                                         wbf + W1T_OFF + 2 * 65536, b1 + 1024,
                                         wbf + W2T_OFF + 2 * 65536, b2 + 256,
                                         out + (size_t)(NE + NM) * 128, 1.0f / 3.0f);
#undef RP
#undef EP
#undef WQS
#undef EF4
}

// Round 8
// 469.390 us; speedup vs baseline: 1.3452x; 1.3452x over previous
//
#include <hip/hip_runtime.h>
#include <cstddef>

#define NE 32768
#define NM 65536
#define NR 49152
#define NTOT 147456
#define E2 262144
#define NDPAD 65536
#define RPS 65537
#define W1T_OFF 131072
#define W2T_OFF 327680

typedef __attribute__((ext_vector_type(8))) short bf16x8;
typedef __attribute__((ext_vector_type(4))) float f32x4;
typedef __attribute__((ext_vector_type(2))) float f32x2;

__device__ __forceinline__ unsigned short f2bf(float x) {
    unsigned u = __float_as_uint(x);
    return (unsigned short)((u + 0x7FFFu + ((u >> 16) & 1u)) >> 16);
}
__device__ __forceinline__ float bf2f(unsigned s) { return __uint_as_float(s << 16); }
__device__ __forceinline__ unsigned pk2(float a, float b) {
    return (unsigned)f2bf(a) | ((unsigned)f2bf(b) << 16);
}
__device__ __forceinline__ bf16x8 pack8(const float* v) {
    union { bf16x8 b; unsigned u[4]; } r;
#pragma unroll
    for (int i = 0; i < 4; ++i) r.u[i] = pk2(v[2 * i], v[2 * i + 1]);
    return r.b;
}
__device__ __forceinline__ bf16x8 pack8v(f32x4 a, f32x4 b) {
    union { bf16x8 v; unsigned u[4]; } r;
    r.u[0] = pk2(a[0], a[1]); r.u[1] = pk2(a[2], a[3]);
    r.u[2] = pk2(b[0], b[1]); r.u[3] = pk2(b[2], b[3]);
    return r.v;
}
// fp8 e4m3 (OCP on gfx950) pack via HW convert
__device__ __forceinline__ unsigned short pkfp8(float a, float b) {
    return (unsigned short)__builtin_amdgcn_cvt_pk_fp8_f32(a, b, 0u, false);
}
__device__ __forceinline__ void gll16(const void* g, void* l) {
    __builtin_amdgcn_global_load_lds(
        (const __attribute__((address_space(1))) void*)g,
        (__attribute__((address_space(3))) void*)l, 16, 0, 0);
}

// ---------------------------------------------------------------------------
// Weights -> bf16 FRAGMENT-PACKED (square mats; w1t nf-major; w2t ks-major).
// ---------------------------------------------------------------------------
__global__ __launch_bounds__(256) void convw(
    const float* __restrict__ wp, const float* __restrict__ wl,
    const float* __restrict__ w1, const float* __restrict__ w2,
    unsigned short* __restrict__ wbf)
{
    int i = blockIdx.x * 256 + threadIdx.x;
    float v;
    if (i < 131072) {
        int mat = i >> 14, r = i & 16383;
        int frag = r >> 9, lane = (r >> 3) & 63, j = r & 7;
        int nf = frag >> 2, ks = frag & 3;
        int n = nf * 16 + (lane & 15);
        int k = ks * 32 + (lane >> 4) * 8 + j;
        const float* src = (mat < 3) ? (wp + mat * 16384) : (wl + (mat - 3) * 16384);
        v = src[k * 128 + n];
    } else if (i < 327680) {
        int ii = i - 131072; int mat = ii >> 16, r = ii & 65535;
        int frag = r >> 9, lane = (r >> 3) & 63, j = r & 7;
        int nf = frag >> 2, ks = frag & 3;
        int n = nf * 16 + (lane & 15);
        int k = ks * 32 + (lane >> 4) * 8 + j;
        v = w1[mat * 65536 + k * 512 + n];
    } else {
        int ii = i - 327680; int mat = ii >> 16, r = ii & 65535;
        int frag = r >> 9, lane = (r >> 3) & 63, j = r & 7;
        int ks = frag >> 3, nf = frag & 7;
        int n = nf * 16 + (lane & 15);
        int k = ks * 32 + (lane >> 4) * 8 + j;
        v = w2[mat * 65536 + k * 128 + n];
    }
    wbf[i] = f2bf(v);
}

// ---------------------------------------------------------------------------
// WQ[site] = W . a  (128 x 8 logit-fold matrices), fragment-packed.
// ---------------------------------------------------------------------------
__global__ __launch_bounds__(256) void wqk(
    const float* __restrict__ wl, const float* __restrict__ a_src,
    const float* __restrict__ a_dst, unsigned short* __restrict__ wq)
{
    const int wi[7]  = {0, 2, 0, 1, 2, 3, 4};
    const int loi[7] = {0, 2, 0, 1, 2, 3, 4};
    const int lod[7] = {1, 1, 0, 0, 0, 0, 0};
    const int hii[7] = {-1, -1, -1, 1, -1, 3, 4};
    int site = blockIdx.x >> 2, ks = blockIdx.x & 3, t = threadIdx.x;
    const float* W = wl + wi[site] * 16384;
#pragma unroll
    for (int rep = 0; rep < 2; ++rep) {
        int e = t * 2 + rep;
        int lane = e >> 3, j = e & 7;
        int n = lane & 15;
        int k = ks * 32 + (lane >> 4) * 8 + j;
        float v = 0.f;
        if (n < 4) {
            const float* a = (lod[site] ? a_dst : a_src) + loi[site] * 128;
#pragma unroll 8
            for (int d = 0; d < 32; ++d) v += W[k * 128 + n * 32 + d] * a[n * 32 + d];
        } else if (n < 8 && hii[site] >= 0) {
            const float* a = a_dst + hii[site] * 128;
            int hh = n - 4;
#pragma unroll 8
            for (int d = 0; d < 32; ++d) v += W[k * 128 + hh * 32 + d] * a[hh * 32 + d];
        }
        wq[((site * 4 + ks) * 64 + lane) * 8 + j] = f2bf(v);
    }
}

// ---------------------------------------------------------------------------
__global__ __launch_bounds__(256) void ln1_kernel(
    const float* __restrict__ he, const float* __restrict__ hm, const float* __restrict__ hr,
    const float* __restrict__ g, const float* __restrict__ b, unsigned* __restrict__ nout)
{
    int row  = blockIdx.x * 4 + (threadIdx.x >> 6);
    int lane = threadIdx.x & 63;
    const float* src; int ti; int lr;
    if (row < NE)           { src = he; ti = 0; lr = row; }
    else if (row < NE + NM) { src = hm; ti = 1; lr = row - NE; }
    else                    { src = hr; ti = 2; lr = row - NE - NM; }
    float2 x = *(const float2*)(src + (size_t)lr * 128 + lane * 2);
    float s = x.x + x.y;
#pragma unroll
    for (int o = 32; o; o >>= 1) s += __shfl_xor(s, o);
    float mean = s * (1.0f / 128.0f);
    float dx = x.x - mean, dy = x.y - mean;
    float v = dx * dx + dy * dy;
#pragma unroll
    for (int o = 32; o; o >>= 1) v += __shfl_xor(v, o);
    float rstd = rsqrtf(v * (1.0f / 128.0f) + 1e-5f);
    int c = lane * 2;
    float y0 = g[ti * 128 + c]     * dx * rstd + b[ti * 128 + c];
    float y1 = g[ti * 128 + c + 1] * dy * rstd + b[ti * 128 + c + 1];
    nout[(size_t)row * 64 + lane] = pk2(y0, y1);
}

// ---------------------------------------------------------------------------
// GEMM + optional fused logits; Z output FP8 (u16 p -> cols (p, p+64)).
// ---------------------------------------------------------------------------
template <int LOG, bool BIAS>
__global__ __launch_bounds__(256) void gemm_v2(
    const unsigned short* __restrict__ A, const unsigned short* __restrict__ Wt,
    const float* __restrict__ bias, unsigned short* __restrict__ Zp,
    const unsigned short* __restrict__ WQ, float* __restrict__ oa, float* __restrict__ ob)
{
    __shared__ unsigned short WL[16384];
    int t = threadIdx.x, w = t >> 6, l = t & 63;
    int l15 = l & 15, lq = l >> 4;
#pragma unroll
    for (int i = 0; i < 8; ++i)
        gll16(Wt + i * 2048 + t * 8, (char*)WL + i * 4096 + t * 16);
    size_t row0 = (size_t)blockIdx.x * 128 + w * 32;
    f32x4 acc[2][8]; f32x4 accl[2];
#pragma unroll
    for (int r = 0; r < 2; ++r) {
        accl[r] = (f32x4){0.f, 0.f, 0.f, 0.f};
#pragma unroll
        for (int n = 0; n < 8; ++n) acc[r][n] = (f32x4){0.f, 0.f, 0.f, 0.f};
    }
    bf16x8 qf[4];
    if constexpr (LOG >= 1) {
#pragma unroll
        for (int ks = 0; ks < 4; ++ks) qf[ks] = *(const bf16x8*)(WQ + (ks * 64 + l) * 8);
    }
    __syncthreads();
#pragma unroll
    for (int ks = 0; ks < 4; ++ks) {
        int k0 = ks * 32 + lq * 8;
        bf16x8 a0 = *(const bf16x8*)(A + (row0 + l15) * 128 + k0);
        bf16x8 a1 = *(const bf16x8*)(A + (row0 + 16 + l15) * 128 + k0);
#pragma unroll
        for (int n = 0; n < 8; ++n) {
            bf16x8 bw = *(const bf16x8*)(WL + ((n * 4 + ks) * 64 + l) * 8);
            acc[0][n] = __builtin_amdgcn_mfma_f32_16x16x32_bf16(a0, bw, acc[0][n], 0, 0, 0);
            acc[1][n] = __builtin_amdgcn_mfma_f32_16x16x32_bf16(a1, bw, acc[1][n], 0, 0, 0);
        }
        if constexpr (LOG >= 1) {
            accl[0] = __builtin_amdgcn_mfma_f32_16x16x32_bf16(a0, qf[ks], accl[0], 0, 0, 0);
            accl[1] = __builtin_amdgcn_mfma_f32_16x16x32_bf16(a1, qf[ks], accl[1], 0, 0, 0);
        }
    }
#pragma unroll
    for (int n = 0; n < 4; ++n) {
        float bl = BIAS ? bias[n * 16 + l15] : 0.f;
        float bh = BIAS ? bias[n * 16 + l15 + 64] : 0.f;
#pragma unroll
        for (int r = 0; r < 2; ++r)
#pragma unroll
            for (int reg = 0; reg < 4; ++reg) {
                size_t row = row0 + r * 16 + lq * 4 + reg;
                Zp[row * 64 + n * 16 + l15] = pkfp8(acc[r][n][reg] + bl, acc[r][n + 4][reg] + bh);
            }
    }
    if constexpr (LOG >= 1) {
#pragma unroll
        for (int r = 0; r < 2; ++r)
#pragma unroll
            for (int reg = 0; reg < 4; ++reg) {
                size_t row = row0 + r * 16 + lq * 4 + reg;
                if (l15 < 4) oa[row * 4 + l15] = accl[r][reg];
                else if (LOG == 2 && l15 < 8) ob[row * 4 + (l15 - 4)] = accl[r][reg];
            }
    }
}

// ---------------------------------------------------------------------------
// CSR build, two-level bucket partition (unchanged).
// ---------------------------------------------------------------------------
struct P8 { const int* a[8]; };
#define CHUNK 2048

__global__ __launch_bounds__(256) void bucket_count(P8 dsts, unsigned* __restrict__ bcnt)
{
    __shared__ unsigned lh[256];
    int blk = blockIdx.x, rel = blk >> 7, cb = blk & 127, t = threadIdx.x;
    lh[t] = 0; __syncthreads();
    const int* dp = dsts.a[rel] + cb * CHUNK;
#pragma unroll
    for (int it = 0; it < 8; ++it) atomicAdd(&lh[dp[it * 256 + t] >> 8], 1u);
    __syncthreads();
    atomicAdd(&bcnt[rel * 256 + t], lh[t]);
}

__global__ __launch_bounds__(256) void scanB(const unsigned* __restrict__ bcnt,
                                             unsigned* __restrict__ bbase,
                                             unsigned* __restrict__ bcur)
{
    __shared__ unsigned ts[256];
    int t = threadIdx.x;
    unsigned v[8]; unsigned run = 0;
#pragma unroll
    for (int i = 0; i < 8; ++i) { v[i] = bcnt[t * 8 + i]; run += v[i]; }
    ts[t] = run; __syncthreads();
    for (int off = 1; off < 256; off <<= 1) {
        unsigned x = (t >= off) ? ts[t - off] : 0u;
        __syncthreads(); ts[t] += x; __syncthreads();
    }
    unsigned base = ts[t] - run;
#pragma unroll
    for (int i = 0; i < 8; ++i) { bbase[t * 8 + i] = base; bcur[t * 8 + i] = base; base += v[i]; }
    if (t == 255) bbase[2048] = base;
}

__global__ __launch_bounds__(256) void bucket_fill(P8 dsts, P8 srcs,
                                                   unsigned* __restrict__ bcur,
                                                   unsigned long long* __restrict__ bb)
{
    __shared__ unsigned lh[256], lbase[256], lcur[256];
    int blk = blockIdx.x, rel = blk >> 7, cb = blk & 127, t = threadIdx.x;
    lh[t] = 0; lcur[t] = 0; __syncthreads();
    const int* dp = dsts.a[rel] + cb * CHUNK;
    const int* sp = srcs.a[rel] + cb * CHUNK;
    int dv[8];
#pragma unroll
    for (int it = 0; it < 8; ++it) { dv[it] = dp[it * 256 + t]; atomicAdd(&lh[dv[it] >> 8], 1u); }
    __syncthreads();
    lbase[t] = atomicAdd(&bcur[rel * 256 + t], lh[t]);
    __syncthreads();
#pragma unroll
    for (int it = 0; it < 8; ++it) {
        unsigned e = (unsigned)(cb * CHUNK + it * 256 + t);
        unsigned d = (unsigned)dv[it];
        unsigned s = (unsigned)sp[it * 256 + t];
        unsigned pos = atomicAdd(&lcur[d >> 8], 1u);
        bb[lbase[d >> 8] + pos] =
            (unsigned long long)s | ((unsigned long long)d << 16) | ((unsigned long long)e << 32);
    }
}

__global__ __launch_bounds__(256) void bucket_hist(const unsigned long long* __restrict__ bb,
                                                   const unsigned* __restrict__ bbase,
                                                   unsigned* __restrict__ hist)
{
    __shared__ unsigned lh[256];
    int blk = blockIdx.x, rel = blk >> 8, b = blk & 255, t = threadIdx.x;
    lh[t] = 0; __syncthreads();
    unsigned s0 = bbase[blk], s1 = bbase[blk + 1];
    for (unsigned i = s0 + t; i < s1; i += 256)
        atomicAdd(&lh[(unsigned)(bb[i] >> 16) & 255u], 1u);
    __syncthreads();
    hist[(size_t)rel * NDPAD + b * 256 + t] = lh[t];
}

__global__ __launch_bounds__(256) void scan1(const unsigned* __restrict__ hist,
                                             unsigned* __restrict__ rowptr,
                                             unsigned* __restrict__ blksum)
{
    __shared__ unsigned s[256];
    int b = blockIdx.x, rel = b >> 8, c = b & 255, t = threadIdx.x;
    unsigned v = hist[(size_t)rel * NDPAD + c * 256 + t];
    s[t] = v; __syncthreads();
    for (int off = 1; off < 256; off <<= 1) {
        unsigned x = (t >= off) ? s[t - off] : 0u;
        __syncthreads();
        s[t] += x;
        __syncthreads();
    }
    rowptr[(size_t)rel * RPS + c * 256 + t] = s[t] - v;
    if (t == 255) blksum[rel * 256 + c] = s[255];
}

__global__ __launch_bounds__(256) void scan2(unsigned* __restrict__ blksum,
                                             unsigned* __restrict__ rowptr)
{
    __shared__ unsigned s[256];
    int rel = blockIdx.x, t = threadIdx.x;
    unsigned v = blksum[rel * 256 + t];
    s[t] = v; __syncthreads();
    for (int off = 1; off < 256; off <<= 1) {
        unsigned x = (t >= off) ? s[t - off] : 0u;
        __syncthreads();
        s[t] += x;
        __syncthreads();
    }
    blksum[rel * 256 + t] = s[t] - v;
    if (t == 255) rowptr[(size_t)rel * RPS + 65536] = s[255];
}

__global__ __launch_bounds__(256) void scan3(unsigned* __restrict__ rowptr,
                                             const unsigned* __restrict__ blksum)
{
    int b = blockIdx.x, rel = b >> 8, c = b & 255, t = threadIdx.x;
    rowptr[(size_t)rel * RPS + c * 256 + t] += blksum[rel * 256 + c];
}

__global__ __launch_bounds__(256) void bucket_place(const unsigned long long* __restrict__ bb,
                                                    const unsigned* __restrict__ bbase,
                                                    const unsigned* __restrict__ rowptr,
                                                    int2* __restrict__ epair)
{
    __shared__ unsigned lrp[256], lcur[256];
    int blk = blockIdx.x, rel = blk >> 8, b = blk & 255, t = threadIdx.x;
    lrp[t] = rowptr[(size_t)rel * RPS + b * 256 + t];
    lcur[t] = 0; __syncthreads();
    unsigned s0 = bbase[blk], s1 = bbase[blk + 1];
    for (unsigned i = s0 + t; i < s1; i += 256) {
        unsigned long long pk = bb[i];
        unsigned s = (unsigned)pk & 0xffffu;
        unsigned d8 = (unsigned)(pk >> 16) & 255u;
        unsigned e = (unsigned)(pk >> 32);
        unsigned pos = atomicAdd(&lcur[d8], 1u);
        epair[(size_t)rel * E2 + lrp[d8] + pos] = make_int2((int)s, (int)e);
    }
}

// ---------------------------------------------------------------------------
// Per-edge (ef @ M) EDGE-ORDERED, packed bf16x4.
// ---------------------------------------------------------------------------
__global__ __launch_bounds__(256) void ef4e_kernel(
    const float* __restrict__ efm, const float* __restrict__ efs,
    const float* __restrict__ efb, const float* __restrict__ eft,
    const float* __restrict__ we, const float* __restrict__ ae,
    uint2* __restrict__ ef4e)
{
    __shared__ float M[8][4];
    int b = blockIdx.x, t = threadIdx.x;
    int er = b >> 10;
    const float* ef = (er == 0) ? efm : (er == 1) ? efs : (er == 2) ? efb : eft;
    if (t < 32) {
        int f = t >> 2, hh = t & 3;
        float s = 0.f;
#pragma unroll 8
        for (int d = 0; d < 32; ++d) s += we[er * 1024 + f * 128 + hh * 32 + d] * ae[er * 128 + hh * 32 + d];
        M[f][hh] = s;
    }
    __syncthreads();
    int e = (b & 1023) * 256 + t;
    float4 a = *(const float4*)(ef + (size_t)e * 8);
    float4 c = *(const float4*)(ef + (size_t)e * 8 + 4);
    float o0 = a.x*M[0][0]+a.y*M[1][0]+a.z*M[2][0]+a.w*M[3][0]+c.x*M[4][0]+c.y*M[5][0]+c.z*M[6][0]+c.w*M[7][0];
    float o1 = a.x*M[0][1]+a.y*M[1][1]+a.z*M[2][1]+a.w*M[3][1]+c.x*M[4][1]+c.y*M[5][1]+c.z*M[6][1]+c.w*M[7][1];
    float o2 = a.x*M[0][2]+a.y*M[1][2]+a.z*M[2][2]+a.w*M[3][2]+c.x*M[4][2]+c.y*M[5][2]+c.z*M[6][2]+c.w*M[7][2];
    float o3 = a.x*M[0][3]+a.y*M[1][3]+a.z*M[2][3]+a.w*M[3][3]+c.x*M[4][3]+c.y*M[5][3]+c.z*M[6][3]+c.w*M[7][3];
    uint2 o; o.x = pk2(o0, o1); o.y = pk2(o2, o3);
    ef4e[(size_t)er * E2 + e] = o;
}

// ---------------------------------------------------------------------------
// Quarter-wave segment helpers: 16 lanes per dst, lane m holds u16 positions
// 4m..4m+3 of the fp8 Z row = cols {4m..4m+3} (head m>>3) and +64 (head 2+m>>3).
// 4 dsts per wave -> 4 independent load chains in flight.
// ---------------------------------------------------------------------------
__device__ __forceinline__ void phys_seg16(
    const unsigned* __restrict__ rowptr, const int2* __restrict__ epair,
    const unsigned short* __restrict__ Zp, int d, unsigned m,
    float rlo[4], float rhi[4])
{
    unsigned s0 = rowptr[d], s1 = rowptr[d + 1];
    float alo[4] = {0, 0, 0, 0}, ahi[4] = {0, 0, 0, 0};
    for (unsigned base = s0; base < s1; base += 4) {
        unsigned nb = s1 - base; if (nb > 4) nb = 4;
        int2 ep[4];
#pragma unroll
        for (int i = 0; i < 4; ++i)
            ep[i] = epair[base + ((unsigned)i < nb ? (unsigned)i : nb - 1)];
        uint2 zv[4];
#pragma unroll
        for (int i = 0; i < 4; ++i)
            zv[i] = ((const uint2*)(Zp + ((unsigned)ep[i].x << 6)))[m];
#pragma unroll
        for (int i = 0; i < 4; ++i) {
            if ((unsigned)i >= nb) break;
            f32x2 a0 = __builtin_amdgcn_cvt_pk_f32_fp8(zv[i].x, false);
            f32x2 a1 = __builtin_amdgcn_cvt_pk_f32_fp8(zv[i].x, true);
            f32x2 a2 = __builtin_amdgcn_cvt_pk_f32_fp8(zv[i].y, false);
            f32x2 a3 = __builtin_amdgcn_cvt_pk_f32_fp8(zv[i].y, true);
            alo[0] += a0.x; ahi[0] += a0.y;
            alo[1] += a1.x; ahi[1] += a1.y;
            alo[2] += a2.x; ahi[2] += a2.y;
            alo[3] += a3.x; ahi[3] += a3.y;
        }
    }
    int cnt = (int)(s1 - s0);
    float inv = 1.0f / (float)(cnt > 0 ? cnt : 1);
#pragma unroll
    for (int j = 0; j < 4; ++j) { rlo[j] += alo[j] * inv; rhi[j] += ahi[j] * inv; }
}

template <bool HAS_EF>
__device__ __forceinline__ void gat_seg16(
    const unsigned* __restrict__ rowptr, const int2* __restrict__ epair,
    const unsigned short* __restrict__ Zp, const float* __restrict__ ls,
    const float* __restrict__ ld, const uint2* __restrict__ ef4e,
    int d, unsigned m, int hs, float rlo[4], float rhi[4])
{
    float4 ldv4 = *(const float4*)(ld + ((unsigned)d << 2));
    float ldlo = hs ? ldv4.y : ldv4.x;
    float ldhi = hs ? ldv4.w : ldv4.z;
    unsigned s0 = rowptr[d], s1 = rowptr[d + 1];
    float nlo[4] = {0, 0, 0, 0}, nhi[4] = {0, 0, 0, 0};
    float dlo = 0.f, dhi = 0.f;
    for (unsigned base = s0; base < s1; base += 4) {
        unsigned nb = s1 - base; if (nb > 4) nb = 4;
        int2 ep[4];
#pragma unroll
        for (int i = 0; i < 4; ++i)
            ep[i] = epair[base + ((unsigned)i < nb ? (unsigned)i : nb - 1)];
        uint2 zv[4]; float4 lsv[4]; uint2 e4[4];
#pragma unroll
        for (int i = 0; i < 4; ++i) {
            zv[i] = ((const uint2*)(Zp + ((unsigned)ep[i].x << 6)))[m];
            lsv[i] = *(const float4*)(ls + ((unsigned)ep[i].x << 2));
            if (HAS_EF) e4[i] = ef4e[(unsigned)ep[i].y];
        }
#pragma unroll
        for (int i = 0; i < 4; ++i) {
            if ((unsigned)i >= nb) break;
            float glo = (hs ? lsv[i].y : lsv[i].x) + ldlo;
            float ghi = (hs ? lsv[i].w : lsv[i].z) + ldhi;
            if (HAS_EF) {
                glo += bf2f(hs ? (e4[i].x >> 16) : (e4[i].x & 0xffffu));
                ghi += bf2f(hs ? (e4[i].y >> 16) : (e4[i].y & 0xffffu));
            }
            glo = glo > 0.f ? glo : 0.2f * glo;
            ghi = ghi > 0.f ? ghi : 0.2f * ghi;
            float xlo = __expf(glo), xhi = __expf(ghi);
            f32x2 a0 = __builtin_amdgcn_cvt_pk_f32_fp8(zv[i].x, false);
            f32x2 a1 = __builtin_amdgcn_cvt_pk_f32_fp8(zv[i].x, true);
            f32x2 a2 = __builtin_amdgcn_cvt_pk_f32_fp8(zv[i].y, false);
            f32x2 a3 = __builtin_amdgcn_cvt_pk_f32_fp8(zv[i].y, true);
            nlo[0] += xlo * a0.x; nhi[0] += xhi * a0.y;
            nlo[1] += xlo * a1.x; nhi[1] += xhi * a1.y;
            nlo[2] += xlo * a2.x; nhi[2] += xhi * a2.y;
            nlo[3] += xlo * a3.x; nhi[3] += xhi * a3.y;
            dlo += xlo; dhi += xhi;
        }
    }
    float ilo = 1.0f / fmaxf(dlo, 1e-9f), ihi = 1.0f / fmaxf(dhi, 1e-9f);
#pragma unroll
    for (int j = 0; j < 4; ++j) { rlo[j] += nlo[j] * ilo; rhi[j] += nhi[j] * ihi; }
}

// ---------------------------------------------------------------------------
// Gather kernels: 16 dsts/block (quarter-wave), coalesced uint4 acc I/O.
// ---------------------------------------------------------------------------
__device__ __forceinline__ void acc_write16(
    unsigned* __restrict__ accp, int d, unsigned m, bool acc,
    float rlo[4], float rhi[4])
{
    uint4* ap = (uint4*)(accp + ((unsigned)d << 6)) + m;
    if (acc) {
        uint4 o = *ap;
        rlo[0] += bf2f(o.x & 0xffffu); rhi[0] += bf2f(o.x >> 16);
        rlo[1] += bf2f(o.y & 0xffffu); rhi[1] += bf2f(o.y >> 16);
        rlo[2] += bf2f(o.z & 0xffffu); rhi[2] += bf2f(o.z >> 16);
        rlo[3] += bf2f(o.w & 0xffffu); rhi[3] += bf2f(o.w >> 16);
    }
    uint4 nv;
    nv.x = pk2(rlo[0], rhi[0]); nv.y = pk2(rlo[1], rhi[1]);
    nv.z = pk2(rlo[2], rhi[2]); nv.w = pk2(rlo[3], rhi[3]);
    *ap = nv;
}

template <bool ACC>
__global__ __launch_bounds__(256) void phys_gather(
    const unsigned* __restrict__ rowptr, const int2* __restrict__ epair,
    const unsigned short* __restrict__ Zp, unsigned* __restrict__ accp, int n_nodes)
{
    int t = threadIdx.x;
    unsigned m = (unsigned)(t & 15);
    int d = blockIdx.x * 16 + (t >> 4);
    if (d >= n_nodes) return;
    float rlo[4] = {0, 0, 0, 0}, rhi[4] = {0, 0, 0, 0};
    phys_seg16(rowptr, epair, Zp, d, m, rlo, rhi);
    acc_write16(accp, d, m, ACC, rlo, rhi);
}

template <bool ACC>
__global__ __launch_bounds__(256) void dual_phys(
    const unsigned* __restrict__ rpA, const int2* __restrict__ epA,
    const unsigned short* __restrict__ ZA,
    const unsigned* __restrict__ rpB, const int2* __restrict__ epB,
    const unsigned short* __restrict__ ZB,
    unsigned* __restrict__ accp, int n_nodes)
{
    int t = threadIdx.x;
    unsigned m = (unsigned)(t & 15);
    int d = blockIdx.x * 16 + (t >> 4);
    if (d >= n_nodes) return;
    float rlo[4] = {0, 0, 0, 0}, rhi[4] = {0, 0, 0, 0};
    phys_seg16(rpA, epA, ZA, d, m, rlo, rhi);
    phys_seg16(rpB, epB, ZB, d, m, rlo, rhi);
    acc_write16(accp, d, m, ACC, rlo, rhi);
}

template <bool EF, bool ACC>
__global__ __launch_bounds__(256) void gat_gather(
    const unsigned* __restrict__ rowptr, const int2* __restrict__ epair,
    const unsigned short* __restrict__ Zp, const float* __restrict__ ls,
    const float* __restrict__ ld, const uint2* __restrict__ ef4e,
    unsigned* __restrict__ accp, int n_nodes)
{
    int t = threadIdx.x;
    unsigned m = (unsigned)(t & 15);
    int d = blockIdx.x * 16 + (t >> 4);
    if (d >= n_nodes) return;
    int hs = (int)(m >> 3);
    float rlo[4] = {0, 0, 0, 0}, rhi[4] = {0, 0, 0, 0};
    gat_seg16<EF>(rowptr, epair, Zp, ls, ld, ef4e, d, m, hs, rlo, rhi);
    acc_write16(accp, d, m, ACC, rlo, rhi);
}

template <bool EFA, bool EFB, bool ACC>
__global__ __launch_bounds__(256) void dual_gat(
    const unsigned* __restrict__ rpA, const int2* __restrict__ epA,
    const unsigned short* __restrict__ ZA, const float* __restrict__ lsA,
    const float* __restrict__ ldA, const uint2* __restrict__ efA,
    const unsigned* __restrict__ rpB, const int2* __restrict__ epB,
    const unsigned short* __restrict__ ZB, const float* __restrict__ lsB,
    const float* __restrict__ ldB, const uint2* __restrict__ efB,
    unsigned* __restrict__ accp, int n_nodes)
{
    int t = threadIdx.x;
    unsigned m = (unsigned)(t & 15);
    int d = blockIdx.x * 16 + (t >> 4);
    if (d >= n_nodes) return;
    int hs = (int)(m >> 3);
    float rlo[4] = {0, 0, 0, 0}, rhi[4] = {0, 0, 0, 0};
    gat_seg16<EFA>(rpA, epA, ZA, lsA, ldA, efA, d, m, hs, rlo, rhi);
    gat_seg16<EFB>(rpB, epB, ZB, lsB, ldB, efB, d, m, hs, rlo, rhi);
    acc_write16(accp, d, m, ACC, rlo, rhi);
}

// ---------------------------------------------------------------------------
// FFN v5 (unchanged): 128 rows/block, double-buffered weight LDS.
// ---------------------------------------------------------------------------
__global__ __launch_bounds__(256, 2) void ffn_v5(
    const float* __restrict__ h, const unsigned* __restrict__ accp,
    const float* __restrict__ g, const float* __restrict__ b,
    const unsigned short* __restrict__ w1t, const float* __restrict__ b1,
    const unsigned short* __restrict__ w2t, const float* __restrict__ b2,
    float* __restrict__ out, float invC)
{
    __shared__ unsigned short WB[2][16384];
    __shared__ float HW[4][1024];
    int t = threadIdx.x, w = t >> 6, l = t & 63;
    int l15 = l & 15, lq = l >> 4;
    size_t rw = (size_t)blockIdx.x * 128 + w * 32;
    float* myHW = HW[w];

    bf16x8 af[2][4];
#pragma unroll
    for (int rf = 0; rf < 2; ++rf) {
        size_t myrow = rw + rf * 16 + l15;
        const unsigned* ap = accp + myrow * 64 + lq * 8;
        uint4 ua0 = *(const uint4*)(ap);
        uint4 ua1 = *(const uint4*)(ap + 4);
        uint4 ub0 = *(const uint4*)(ap + 32);
        uint4 ub1 = *(const uint4*)(ap + 36);
        const float* hp = h + myrow * 128 + lq * 8;
        float4 hf[4][2];
        hf[0][0] = *(const float4*)(hp);      hf[0][1] = *(const float4*)(hp + 4);
        hf[1][0] = *(const float4*)(hp + 32); hf[1][1] = *(const float4*)(hp + 36);
        hf[2][0] = *(const float4*)(hp + 64); hf[2][1] = *(const float4*)(hp + 68);
        hf[3][0] = *(const float4*)(hp + 96); hf[3][1] = *(const float4*)(hp + 100);
        unsigned ua[8] = {ua0.x, ua0.y, ua0.z, ua0.w, ua1.x, ua1.y, ua1.z, ua1.w};
        unsigned ub[8] = {ub0.x, ub0.y, ub0.z, ub0.w, ub1.x, ub1.y, ub1.z, ub1.w};
        float hv[4][8];
#pragma unroll
        for (int j = 0; j < 8; ++j) {
            hv[0][j] = ((const float*)hf[0])[j] + bf2f(ua[j] & 0xffffu) * invC;
            hv[1][j] = ((const float*)hf[1])[j] + bf2f(ub[j] & 0xffffu) * invC;
            hv[2][j] = ((const float*)hf[2])[j] + bf2f(ua[j] >> 16) * invC;
            hv[3][j] = ((const float*)hf[3])[j] + bf2f(ub[j] >> 16) * invC;
        }
        float s = 0.f;
#pragma unroll
        for (int ks = 0; ks < 4; ++ks)
#pragma unroll
            for (int j = 0; j < 8; ++j) s += hv[ks][j];
        s += __shfl_xor(s, 16); s += __shfl_xor(s, 32);
        float mean = s * (1.0f / 128.0f);
        float v = 0.f;
#pragma unroll
        for (int ks = 0; ks < 4; ++ks)
#pragma unroll
            for (int j = 0; j < 8; ++j) { float dd = hv[ks][j] - mean; v += dd * dd; }
        v += __shfl_xor(v, 16); v += __shfl_xor(v, 32);
        float rstd = rsqrtf(v * (1.0f / 128.0f) + 1e-5f);
#pragma unroll
        for (int ks = 0; ks < 4; ++ks) {
            int col0 = ks * 32 + lq * 8;
            float y[8];
#pragma unroll
            for (int j = 0; j < 8; ++j)
                y[j] = g[col0 + j] * (hv[ks][j] - mean) * rstd + b[col0 + j];
            af[rf][ks] = pack8(y);
        }
    }

#pragma unroll
    for (int i = 0; i < 4; ++i) {
        gll16(w1t + i * 2048 + t * 8, (char*)WB[0] + i * 4096 + t * 16);
        gll16(w2t + i * 2048 + t * 8, (char*)WB[0] + 16384 + i * 4096 + t * 16);
    }
    f32x4 facc[2][8];
#pragma unroll
    for (int rf = 0; rf < 2; ++rf)
#pragma unroll
        for (int n = 0; n < 8; ++n) facc[rf][n] = (f32x4){0.f, 0.f, 0.f, 0.f};
    __syncthreads();

    int buf = 0;
    int swR = (l15 & 7) << 2;
    for (int ch = 0; ch < 8; ++ch) {
        if (ch < 7) {
            const unsigned short* s1p = w1t + (ch + 1) * 8192;
            const unsigned short* s2p = w2t + (ch + 1) * 8192;
#pragma unroll
            for (int i = 0; i < 4; ++i) {
                gll16(s1p + i * 2048 + t * 8, (char*)WB[buf ^ 1] + i * 4096 + t * 16);
                gll16(s2p + i * 2048 + t * 8, (char*)WB[buf ^ 1] + 16384 + i * 4096 + t * 16);
            }
        }
        f32x4 acc1[2][4];
#pragma unroll
        for (int rf = 0; rf < 2; ++rf)
#pragma unroll
            for (int n = 0; n < 4; ++n) acc1[rf][n] = (f32x4){0.f, 0.f, 0.f, 0.f};
#pragma unroll
        for (int ks = 0; ks < 4; ++ks)
#pragma unroll
            for (int nf = 0; nf < 4; ++nf) {
                bf16x8 bw = *(const bf16x8*)(WB[buf] + ((nf * 4 + ks) * 64 + l) * 8);
                acc1[0][nf] = __builtin_amdgcn_mfma_f32_16x16x32_bf16(af[0][ks], bw, acc1[0][nf], 0, 0, 0);
                acc1[1][nf] = __builtin_amdgcn_mfma_f32_16x16x32_bf16(af[1][ks], bw, acc1[1][nf], 0, 0, 0);
            }
#pragma unroll
        for (int rf = 0; rf < 2; ++rf) {
#pragma unroll
            for (int nf = 0; nf < 4; ++nf) {
                float bv = b1[ch * 64 + nf * 16 + l15];
#pragma unroll
                for (int reg = 0; reg < 4; ++reg) {
                    int row = lq * 4 + reg;
                    float x = acc1[rf][nf][reg] + bv;
                    float ge = 0.5f * x * (1.0f + erff(x * 0.70710678118654752f));
                    myHW[row * 64 + ((nf * 16 + l15) ^ ((row & 7) << 2))] = ge;
                }
            }
#pragma unroll
            for (int ks2 = 0; ks2 < 2; ++ks2) {
                int cb = ks2 * 32 + lq * 8;
                f32x4 x0 = *(const f32x4*)(myHW + l15 * 64 + (cb ^ swR));
                f32x4 x1 = *(const f32x4*)(myHW + l15 * 64 + ((cb + 4) ^ swR));
                bf16x8 a2 = pack8v(x0, x1);
#pragma unroll
                for (int nf = 0; nf < 8; ++nf) {
                    bf16x8 bw = *(const bf16x8*)(WB[buf] + 8192 + ((ks2 * 8 + nf) * 64 + l) * 8);
                    facc[rf][nf] = __builtin_amdgcn_mfma_f32_16x16x32_bf16(a2, bw, facc[rf][nf], 0, 0, 0);
                }
            }
        }
        __syncthreads();
        buf ^= 1;
    }
#pragma unroll
    for (int rf = 0; rf < 2; ++rf)
#pragma unroll
        for (int nf = 0; nf < 8; ++nf) {
            int col = nf * 16 + l15;
            float bv = b2[col];
            int ci = col & 63;
            bool hi = col >= 64;
#pragma unroll
            for (int reg = 0; reg < 4; ++reg) {
                size_t row = rw + rf * 16 + lq * 4 + reg;
                unsigned pv = accp[row * 64 + ci];
                float av = bf2f(hi ? (pv >> 16) : (pv & 0xffffu));
                out[row * 128 + col] = h[row * 128 + col] + av * invC + facc[rf][nf][reg] + bv;
            }
        }
}

// ---------------------------------------------------------------------------
extern "C" void kernel_launch(void* const* d_in, const int* in_sizes, int n_in,
                              void* d_out, int out_size, void* d_ws, size_t ws_size,
                              hipStream_t stream)
{
    const float* h_enz  = (const float*)d_in[0];
    const float* h_met  = (const float*)d_in[1];
    const float* h_rxn  = (const float*)d_in[2];
    const float* ef_mod = (const float*)d_in[3];
    const float* ef_sig = (const float*)d_in[4];
    const float* ef_brg = (const float*)d_in[5];
    const float* ef_trn = (const float*)d_in[6];
    const float* ln1_g  = (const float*)d_in[7];
    const float* ln1_b  = (const float*)d_in[8];
    const float* ln2_g  = (const float*)d_in[9];
    const float* ln2_b  = (const float*)d_in[10];
    const float* wp     = (const float*)d_in[11];
    const float* bp     = (const float*)d_in[12];
    const float* wl     = (const float*)d_in[13];
    const float* a_src  = (const float*)d_in[14];
    const float* a_dst  = (const float*)d_in[15];
    const float* we     = (const float*)d_in[16];
    const float* a_edge = (const float*)d_in[17];
    const float* w1     = (const float*)d_in[18];
    const float* b1     = (const float*)d_in[19];
    const float* w2     = (const float*)d_in[20];
    const float* b2     = (const float*)d_in[21];
    const int* src_sub  = (const int*)d_in[22];
    const int* dst_sub  = (const int*)d_in[23];
    const int* src_prod = (const int*)d_in[24];
    const int* dst_prod = (const int*)d_in[25];
    const int* src_cat  = (const int*)d_in[26];
    const int* dst_cat  = (const int*)d_in[27];
    const int* src_mod  = (const int*)d_in[28];
    const int* dst_mod  = (const int*)d_in[29];
    const int* src_reg  = (const int*)d_in[30];
    const int* dst_reg  = (const int*)d_in[31];
    const int* src_sig  = (const int*)d_in[32];
    const int* dst_sig  = (const int*)d_in[33];
    const int* src_brg  = (const int*)d_in[34];
    const int* dst_brg  = (const int*)d_in[35];
    const int* src_trn  = (const int*)d_in[36];
    const int* dst_trn  = (const int*)d_in[37];
    float* out = (float*)d_out;

    // workspace (~92 MB; proven budget >= 116.6 MB)
    char* p = (char*)d_ws;
    unsigned* accp = (unsigned*)p;            p += (size_t)NTOT * 64 * 4;     // 37.75 MB
    unsigned short* ZpA = (unsigned short*)p; p += (size_t)NM * 64 * 2;       // 8.39 MB
    unsigned long long* bukbuf = (unsigned long long*)p;                      // alias (16.78):
    unsigned short* ZpB = (unsigned short*)p; p += (size_t)8 * E2 * 8;        // 16.78 MB
    int2* epair = (int2*)p;                   p += (size_t)8 * E2 * 8;        // 16.78 MB
    unsigned* hist = (unsigned*)p;                                            // alias:
    uint2* ef4e = (uint2*)p;                  p += (size_t)4 * E2 * 8;        // 8.39 MB
    float* ls3 = (float*)p;                   p += (size_t)NE * 4 * 4;
    float* ld3 = (float*)p;                   p += (size_t)NR * 4 * 4;
    float* ls4 = (float*)p;                   p += (size_t)NE * 4 * 4;
    float* ld4 = (float*)p;                   p += (size_t)NE * 4 * 4;
    float* ls5 = (float*)p;                   p += (size_t)NM * 4 * 4;
    float* ld5 = (float*)p;                   p += (size_t)NE * 4 * 4;
    float* ls6 = (float*)p;                   p += (size_t)NM * 4 * 4;
    float* ld6 = (float*)p;                   p += (size_t)NM * 4 * 4;
    float* ls7 = (float*)p;                   p += (size_t)NM * 4 * 4;
    float* ld7 = (float*)p;                   p += (size_t)NM * 4 * 4;
    unsigned short* wbf = (unsigned short*)p; p += (size_t)524288 * 2;
    unsigned short* wq  = (unsigned short*)p; p += (size_t)7 * 2048 * 2;
    unsigned* rowptr = (unsigned*)p;          p += (size_t)8 * RPS * 4;
    unsigned* bcnt = (unsigned*)p;            p += 2048 * 4;
    unsigned* bbase = (unsigned*)p;           p += 2049 * 4;
    unsigned* bcur = (unsigned*)p;            p += 2048 * 4;
    unsigned* blksum = (unsigned*)p;          p += (size_t)8 * 256 * 4;
    if (ws_size < (size_t)(p - (char*)d_ws)) return;

    unsigned* nrm32 = (unsigned*)d_out;
    const unsigned short* nbf_enz = (const unsigned short*)d_out;
    const unsigned short* nbf_met = nbf_enz + (size_t)NE * 128;
    const unsigned short* nbf_rxn = nbf_enz + (size_t)(NE + NM) * 128;
    unsigned* acc_enz = accp;
    unsigned* acc_met = accp + (size_t)NE * 64;
    unsigned* acc_rxn = accp + (size_t)(NE + NM) * 64;

    P8 dsts, srcs;
    dsts.a[0] = dst_sub;  srcs.a[0] = src_sub;
    dsts.a[1] = dst_prod; srcs.a[1] = src_prod;
    dsts.a[2] = dst_cat;  srcs.a[2] = src_cat;
    dsts.a[3] = dst_mod;  srcs.a[3] = src_mod;
    dsts.a[4] = dst_reg;  srcs.a[4] = src_reg;
    dsts.a[5] = dst_sig;  srcs.a[5] = src_sig;
    dsts.a[6] = dst_brg;  srcs.a[6] = src_brg;
    dsts.a[7] = dst_trn;  srcs.a[7] = src_trn;

    // ---- prep: weights, LN1, bucketed CSR, edge-ordered ef.M
    hipMemsetAsync(bcnt, 0, 2048 * 4, stream);
    convw<<<2048, 256, 0, stream>>>(wp, wl, w1, w2, wbf);
    ln1_kernel<<<NTOT / 4, 256, 0, stream>>>(h_enz, h_met, h_rxn, ln1_g, ln1_b, nrm32);
    wqk<<<28, 256, 0, stream>>>(wl, a_src, a_dst, wq);
    bucket_count<<<1024, 256, 0, stream>>>(dsts, bcnt);
    scanB<<<1, 256, 0, stream>>>(bcnt, bbase, bcur);
    bucket_fill<<<1024, 256, 0, stream>>>(dsts, srcs, bcur, bukbuf);
    bucket_hist<<<2048, 256, 0, stream>>>(bukbuf, bbase, hist);
    scan1<<<2048, 256, 0, stream>>>(hist, rowptr, blksum);
    scan2<<<8, 256, 0, stream>>>(blksum, rowptr);
    scan3<<<2048, 256, 0, stream>>>(rowptr, blksum);
    bucket_place<<<2048, 256, 0, stream>>>(bukbuf, bbase, rowptr, epair);
    ef4e_kernel<<<4096, 256, 0, stream>>>(ef_mod, ef_sig, ef_brg, ef_trn, we, a_edge, ef4e);

#define RP(r) (rowptr + (size_t)(r) * RPS)
#define EP(r) (epair + (size_t)(r) * E2)
#define WQS(s) (wq + (size_t)(s) * 2048)
#define EF4(er) (ef4e + (size_t)(er) * E2)

    // ---- rxn: rel0 (met, phys) + rel2 (enz, phys) fused; then rel3 (gat)
    gemm_v2<0, true><<<NM / 128, 256, 0, stream>>>(nbf_met, wbf + 0 * 16384, bp + 0, ZpA,
                                                   nullptr, nullptr, nullptr);
    gemm_v2<1, true><<<NE / 128, 256, 0, stream>>>(nbf_enz, wbf + 2 * 16384, bp + 256, ZpB,
                                                   WQS(1), ld5, nullptr);
    dual_phys<false><<<NR / 16, 256, 0, stream>>>(RP(0), EP(0), ZpA, RP(2), EP(2), ZpB,
                                                  acc_rxn, NR);
    // ---- rel1 (rxn->met, phys) init acc_met; gemm also emits rel3 dst logits
    gemm_v2<1, true><<<NR / 128, 256, 0, stream>>>(nbf_rxn, wbf + 1 * 16384, bp + 128, ZpA,
                                                   WQS(0), ld3, nullptr);
    phys_gather<false><<<NM / 16, 256, 0, stream>>>(RP(1), EP(1), ZpA, acc_met, NM);
    // ---- rel3 (enz->rxn, gat + ef) accum acc_rxn
    gemm_v2<1, false><<<NE / 128, 256, 0, stream>>>(nbf_enz, wbf + 3 * 16384, nullptr, ZpB,
                                                    WQS(2), ls3, nullptr);
    gat_gather<true, true><<<NR / 16, 256, 0, stream>>>(RP(3), EP(3), ZpB, ls3, ld3, EF4(0),
                                                        acc_rxn, NR);
    // ---- enz: rel4 (no ef) + rel5 (ef) fused, single write
    gemm_v2<2, false><<<NE / 128, 256, 0, stream>>>(nbf_enz, wbf + 4 * 16384, nullptr, ZpA,
                                                    WQS(3), ls4, ld4);
    gemm_v2<1, false><<<NM / 128, 256, 0, stream>>>(nbf_met, wbf + 5 * 16384, nullptr, ZpB,
                                                    WQS(4), ls5, nullptr);
    dual_gat<false, true, false><<<NE / 16, 256, 0, stream>>>(
        RP(4), EP(4), ZpA, ls4, ld4, nullptr,
        RP(5), EP(5), ZpB, ls5, ld5, EF4(1), acc_enz, NE);
    // ---- met: rel6 + rel7 fused, accum onto rel1's init
    gemm_v2<2, false><<<NM / 128, 256, 0, stream>>>(nbf_met, wbf + 6 * 16384, nullptr, ZpA,
                                                    WQS(5), ls6, ld6);
    gemm_v2<2, false><<<NM / 128, 256, 0, stream>>>(nbf_met, wbf + 7 * 16384, nullptr, ZpB,
                                                    WQS(6), ls7, ld7);
    dual_gat<true, true, true><<<NM / 16, 256, 0, stream>>>(
        RP(6), EP(6), ZpA, ls6, ld6, EF4(2),
        RP(7), EP(7), ZpB, ls7, ld7, EF4(3), acc_met, NM);

    // ---- fused combine + LN2 + FFN (+residual), per node type
    ffn_v5<<<NE / 128, 256, 0, stream>>>(h_enz, acc_enz, ln2_g + 0, ln2_b + 0,
                                         wbf + W1T_OFF + 0 * 65536, b1 + 0,
                                         wbf + W2T_OFF + 0 * 65536, b2 + 0,
                                         out + 0, 0.5f);
    ffn_v5<<<NM / 128, 256, 0, stream>>>(h_met, acc_met, ln2_g + 128, ln2_b + 128,
                                         wbf + W1T_OFF + 1 * 65536, b1 + 512,
                                         wbf + W2T_OFF + 1 * 65536, b2 + 128,
                                         out + (size_t)NE * 128, 1.0f / 3.0f);
    ffn_v5<<<NR / 128, 256, 0, stream>>>(h_rxn, acc_rxn, ln2_g + 256, ln2_b + 256,
                                         wbf + W1T_OFF + 2 * 65536, b1 + 1024,
                                         wbf + W2T_OFF + 2 * 65536, b2 + 256,
                                         out + (size_t)(NE + NM) * 128, 1.0f / 3.0f);
#undef RP
#undef EP
#undef WQS
#undef EF4
}

// Round 9
// 443.853 us; speedup vs baseline: 1.4226x; 1.0575x over previous
//
#include <hip/hip_runtime.h>
#include <cstddef>

#define NE 32768
#define NM 65536
#define NR 49152
#define NTOT 147456
#define E2 262144
#define RPS 65537
#define W1T_OFF 131072
#define W2T_OFF 327680
#define LN1_BLK 36864
#define CONV_BLK 2048

typedef __attribute__((ext_vector_type(8))) short bf16x8;
typedef __attribute__((ext_vector_type(4))) float f32x4;
typedef __attribute__((ext_vector_type(2))) float f32x2;

__device__ __forceinline__ unsigned short f2bf(float x) {
    unsigned u = __float_as_uint(x);
    return (unsigned short)((u + 0x7FFFu + ((u >> 16) & 1u)) >> 16);
}
__device__ __forceinline__ float bf2f(unsigned s) { return __uint_as_float(s << 16); }
__device__ __forceinline__ unsigned pk2(float a, float b) {
    return (unsigned)f2bf(a) | ((unsigned)f2bf(b) << 16);
}
__device__ __forceinline__ bf16x8 pack8(const float* v) {
    union { bf16x8 b; unsigned u[4]; } r;
#pragma unroll
    for (int i = 0; i < 4; ++i) r.u[i] = pk2(v[2 * i], v[2 * i + 1]);
    return r.b;
}
__device__ __forceinline__ bf16x8 pack8v(f32x4 a, f32x4 b) {
    union { bf16x8 v; unsigned u[4]; } r;
    r.u[0] = pk2(a[0], a[1]); r.u[1] = pk2(a[2], a[3]);
    r.u[2] = pk2(b[0], b[1]); r.u[3] = pk2(b[2], b[3]);
    return r.v;
}
__device__ __forceinline__ unsigned short pkfp8(float a, float b) {
    return (unsigned short)__builtin_amdgcn_cvt_pk_fp8_f32(a, b, 0u, false);
}
__device__ __forceinline__ void gll16(const void* g, void* l) {
    __builtin_amdgcn_global_load_lds(
        (const __attribute__((address_space(1))) void*)g,
        (__attribute__((address_space(3))) void*)l, 16, 0, 0);
}
// tanh-form GELU: x * sigmoid(1.59577x + 0.0713548x^3); |err| <~1e-3
__device__ __forceinline__ float gelu(float x) {
    float y = x * (1.5957691216f + 0.0713548163f * (x * x));
    float e = __expf(-y);
    return x / (1.0f + e);
}

// ---------------------------------------------------------------------------
// prep_all = ln1 (blocks [0,36864)) + convw ([36864,38912)) + wqk (last 28).
// ---------------------------------------------------------------------------
__global__ __launch_bounds__(256) void prep_all(
    const float* __restrict__ he, const float* __restrict__ hm, const float* __restrict__ hr,
    const float* __restrict__ g1, const float* __restrict__ b1g, unsigned* __restrict__ nout,
    const float* __restrict__ wp, const float* __restrict__ wl,
    const float* __restrict__ w1, const float* __restrict__ w2,
    unsigned short* __restrict__ wbf,
    const float* __restrict__ a_src, const float* __restrict__ a_dst,
    unsigned short* __restrict__ wq)
{
    int blk = blockIdx.x, t = threadIdx.x;
    if (blk < LN1_BLK) {
        // ---- LN1 -> packed bf16 pairs
        int row  = blk * 4 + (t >> 6);
        int lane = t & 63;
        const float* src; int ti; int lr;
        if (row < NE)           { src = he; ti = 0; lr = row; }
        else if (row < NE + NM) { src = hm; ti = 1; lr = row - NE; }
        else                    { src = hr; ti = 2; lr = row - NE - NM; }
        float2 x = *(const float2*)(src + (size_t)lr * 128 + lane * 2);
        float s = x.x + x.y;
#pragma unroll
        for (int o = 32; o; o >>= 1) s += __shfl_xor(s, o);
        float mean = s * (1.0f / 128.0f);
        float dx = x.x - mean, dy = x.y - mean;
        float v = dx * dx + dy * dy;
#pragma unroll
        for (int o = 32; o; o >>= 1) v += __shfl_xor(v, o);
        float rstd = rsqrtf(v * (1.0f / 128.0f) + 1e-5f);
        int c = lane * 2;
        float y0 = g1[ti * 128 + c]     * dx * rstd + b1g[ti * 128 + c];
        float y1 = g1[ti * 128 + c + 1] * dy * rstd + b1g[ti * 128 + c + 1];
        nout[(size_t)row * 64 + lane] = pk2(y0, y1);
    } else if (blk < LN1_BLK + CONV_BLK) {
        // ---- weights -> bf16 fragment-packed
        int i = (blk - LN1_BLK) * 256 + t;
        float v;
        if (i < 131072) {
            int mat = i >> 14, r = i & 16383;
            int frag = r >> 9, lane = (r >> 3) & 63, j = r & 7;
            int nf = frag >> 2, ks = frag & 3;
            int n = nf * 16 + (lane & 15);
            int k = ks * 32 + (lane >> 4) * 8 + j;
            const float* src = (mat < 3) ? (wp + mat * 16384) : (wl + (mat - 3) * 16384);
            v = src[k * 128 + n];
        } else if (i < 327680) {
            int ii = i - 131072; int mat = ii >> 16, r = ii & 65535;
            int frag = r >> 9, lane = (r >> 3) & 63, j = r & 7;
            int nf = frag >> 2, ks = frag & 3;
            int n = nf * 16 + (lane & 15);
            int k = ks * 32 + (lane >> 4) * 8 + j;
            v = w1[mat * 65536 + k * 512 + n];
        } else {
            int ii = i - 327680; int mat = ii >> 16, r = ii & 65535;
            int frag = r >> 9, lane = (r >> 3) & 63, j = r & 7;
            int ks = frag >> 3, nf = frag & 7;
            int n = nf * 16 + (lane & 15);
            int k = ks * 32 + (lane >> 4) * 8 + j;
            v = w2[mat * 65536 + k * 128 + n];
        }
        wbf[i] = f2bf(v);
    } else {
        // ---- WQ = W . a  logit-fold matrices (28 blocks)
        const int wi[7]  = {0, 2, 0, 1, 2, 3, 4};
        const int loi[7] = {0, 2, 0, 1, 2, 3, 4};
        const int lod[7] = {1, 1, 0, 0, 0, 0, 0};
        const int hii[7] = {-1, -1, -1, 1, -1, 3, 4};
        int bid = blk - LN1_BLK - CONV_BLK;
        int site = bid >> 2, ks = bid & 3;
        const float* W = wl + wi[site] * 16384;
#pragma unroll
        for (int rep = 0; rep < 2; ++rep) {
            int e = t * 2 + rep;
            int lane = e >> 3, j = e & 7;
            int n = lane & 15;
            int k = ks * 32 + (lane >> 4) * 8 + j;
            float v = 0.f;
            if (n < 4) {
                const float* a = (lod[site] ? a_dst : a_src) + loi[site] * 128;
#pragma unroll 8
                for (int d = 0; d < 32; ++d) v += W[k * 128 + n * 32 + d] * a[n * 32 + d];
            } else if (n < 8 && hii[site] >= 0) {
                const float* a = a_dst + hii[site] * 128;
                int hh = n - 4;
#pragma unroll 8
                for (int d = 0; d < 32; ++d) v += W[k * 128 + hh * 32 + d] * a[hh * 32 + d];
            }
            wq[((site * 4 + ks) * 64 + lane) * 8 + j] = f2bf(v);
        }
    }
}

// ---------------------------------------------------------------------------
// Paired GEMM: two sub-problems in one dispatch (runtime flags).
// Z output FP8 (u16 p -> cols (p, p+64)); optional logits via WQ MFMA.
// ---------------------------------------------------------------------------
struct G2 {
    const unsigned short *A0, *Wt0; const float* b0; unsigned short* Z0;
    const unsigned short* Q0; float *oa0, *ob0;
    const unsigned short *A1, *Wt1; const float* b1; unsigned short* Z1;
    const unsigned short* Q1; float *oa1, *ob1;
    int n0;
};

__global__ __launch_bounds__(256) void gemm_pair(G2 P)
{
    __shared__ unsigned short WL[16384];
    int t = threadIdx.x, w = t >> 6, l = t & 63;
    int l15 = l & 15, lq = l >> 4;
    int e = (blockIdx.x >= P.n0) ? 1 : 0;
    const unsigned short* A  = e ? P.A1 : P.A0;
    const unsigned short* Wt = e ? P.Wt1 : P.Wt0;
    const float* bias        = e ? P.b1 : P.b0;
    unsigned short* Zp       = e ? P.Z1 : P.Z0;
    const unsigned short* WQ = e ? P.Q1 : P.Q0;
    float* oa                = e ? P.oa1 : P.oa0;
    float* ob                = e ? P.ob1 : P.ob0;
    int lb = blockIdx.x - (e ? P.n0 : 0);
#pragma unroll
    for (int i = 0; i < 8; ++i)
        gll16(Wt + i * 2048 + t * 8, (char*)WL + i * 4096 + t * 16);
    size_t row0 = (size_t)lb * 128 + w * 32;
    f32x4 acc[2][8]; f32x4 accl[2];
#pragma unroll
    for (int r = 0; r < 2; ++r) {
        accl[r] = (f32x4){0.f, 0.f, 0.f, 0.f};
#pragma unroll
        for (int n = 0; n < 8; ++n) acc[r][n] = (f32x4){0.f, 0.f, 0.f, 0.f};
    }
    bool haslog = (WQ != nullptr);
    bf16x8 qf[4];
    if (haslog) {
#pragma unroll
        for (int ks = 0; ks < 4; ++ks) qf[ks] = *(const bf16x8*)(WQ + (ks * 64 + l) * 8);
    }
    __syncthreads();
#pragma unroll
    for (int ks = 0; ks < 4; ++ks) {
        int k0 = ks * 32 + lq * 8;
        bf16x8 a0 = *(const bf16x8*)(A + (row0 + l15) * 128 + k0);
        bf16x8 a1 = *(const bf16x8*)(A + (row0 + 16 + l15) * 128 + k0);
#pragma unroll
        for (int n = 0; n < 8; ++n) {
            bf16x8 bw = *(const bf16x8*)(WL + ((n * 4 + ks) * 64 + l) * 8);
            acc[0][n] = __builtin_amdgcn_mfma_f32_16x16x32_bf16(a0, bw, acc[0][n], 0, 0, 0);
            acc[1][n] = __builtin_amdgcn_mfma_f32_16x16x32_bf16(a1, bw, acc[1][n], 0, 0, 0);
        }
        if (haslog) {
            accl[0] = __builtin_amdgcn_mfma_f32_16x16x32_bf16(a0, qf[ks], accl[0], 0, 0, 0);
            accl[1] = __builtin_amdgcn_mfma_f32_16x16x32_bf16(a1, qf[ks], accl[1], 0, 0, 0);
        }
    }
    bool hasb = (bias != nullptr);
#pragma unroll
    for (int n = 0; n < 4; ++n) {
        float bl = hasb ? bias[n * 16 + l15] : 0.f;
        float bh = hasb ? bias[n * 16 + l15 + 64] : 0.f;
#pragma unroll
        for (int r = 0; r < 2; ++r)
#pragma unroll
            for (int reg = 0; reg < 4; ++reg) {
                size_t row = row0 + r * 16 + lq * 4 + reg;
                Zp[row * 64 + n * 16 + l15] = pkfp8(acc[r][n][reg] + bl, acc[r][n + 4][reg] + bh);
            }
    }
    if (haslog) {
#pragma unroll
        for (int r = 0; r < 2; ++r)
#pragma unroll
            for (int reg = 0; reg < 4; ++reg) {
                size_t row = row0 + r * 16 + lq * 4 + reg;
                if (oa && l15 < 4) oa[row * 4 + l15] = accl[r][reg];
                else if (ob && l15 >= 4 && l15 < 8) ob[row * 4 + (l15 - 4)] = accl[r][reg];
            }
    }
}

// ---------------------------------------------------------------------------
// CSR build, two-level bucket partition.
// ---------------------------------------------------------------------------
struct P8 { const int* a[8]; };
#define CHUNK 2048

__global__ __launch_bounds__(256) void bucket_count(P8 dsts, unsigned* __restrict__ bcnt)
{
    __shared__ unsigned lh[256];
    int blk = blockIdx.x, rel = blk >> 7, cb = blk & 127, t = threadIdx.x;
    lh[t] = 0; __syncthreads();
    const int* dp = dsts.a[rel] + cb * CHUNK;
#pragma unroll
    for (int it = 0; it < 8; ++it) atomicAdd(&lh[dp[it * 256 + t] >> 8], 1u);
    __syncthreads();
    atomicAdd(&bcnt[rel * 256 + t], lh[t]);
}

__global__ __launch_bounds__(256) void scanB(const unsigned* __restrict__ bcnt,
                                             unsigned* __restrict__ bbase,
                                             unsigned* __restrict__ bcur)
{
    __shared__ unsigned ts[256];
    int t = threadIdx.x;
    unsigned v[8]; unsigned run = 0;
#pragma unroll
    for (int i = 0; i < 8; ++i) { v[i] = bcnt[t * 8 + i]; run += v[i]; }
    ts[t] = run; __syncthreads();
    for (int off = 1; off < 256; off <<= 1) {
        unsigned x = (t >= off) ? ts[t - off] : 0u;
        __syncthreads(); ts[t] += x; __syncthreads();
    }
    unsigned base = ts[t] - run;
#pragma unroll
    for (int i = 0; i < 8; ++i) { bbase[t * 8 + i] = base; bcur[t * 8 + i] = base; base += v[i]; }
    if (t == 255) bbase[2048] = base;
}

__global__ __launch_bounds__(256) void bucket_fill(P8 dsts, P8 srcs,
                                                   unsigned* __restrict__ bcur,
                                                   unsigned long long* __restrict__ bb)
{
    __shared__ unsigned lh[256], lbase[256], lcur[256];
    int blk = blockIdx.x, rel = blk >> 7, cb = blk & 127, t = threadIdx.x;
    lh[t] = 0; lcur[t] = 0; __syncthreads();
    const int* dp = dsts.a[rel] + cb * CHUNK;
    const int* sp = srcs.a[rel] + cb * CHUNK;
    int dv[8];
#pragma unroll
    for (int it = 0; it < 8; ++it) { dv[it] = dp[it * 256 + t]; atomicAdd(&lh[dv[it] >> 8], 1u); }
    __syncthreads();
    lbase[t] = atomicAdd(&bcur[rel * 256 + t], lh[t]);
    __syncthreads();
#pragma unroll
    for (int it = 0; it < 8; ++it) {
        unsigned e = (unsigned)(cb * CHUNK + it * 256 + t);
        unsigned d = (unsigned)dv[it];
        unsigned s = (unsigned)sp[it * 256 + t];
        unsigned pos = atomicAdd(&lcur[d >> 8], 1u);
        bb[lbase[d >> 8] + pos] =
            (unsigned long long)s | ((unsigned long long)d << 16) | ((unsigned long long)e << 32);
    }
}

// fused bucket_hist + scan1 (hist buffer eliminated)
__global__ __launch_bounds__(256) void hist_scan(const unsigned long long* __restrict__ bb,
                                                 const unsigned* __restrict__ bbase,
                                                 unsigned* __restrict__ rowptr,
                                                 unsigned* __restrict__ blksum)
{
    __shared__ unsigned lh[256], s[256];
    int blk = blockIdx.x, rel = blk >> 8, b = blk & 255, t = threadIdx.x;
    lh[t] = 0; __syncthreads();
    unsigned s0 = bbase[blk], s1 = bbase[blk + 1];
    for (unsigned i = s0 + t; i < s1; i += 256)
        atomicAdd(&lh[(unsigned)(bb[i] >> 16) & 255u], 1u);
    __syncthreads();
    unsigned v = lh[t];
    s[t] = v; __syncthreads();
    for (int off = 1; off < 256; off <<= 1) {
        unsigned x = (t >= off) ? s[t - off] : 0u;
        __syncthreads();
        s[t] += x;
        __syncthreads();
    }
    rowptr[(size_t)rel * RPS + b * 256 + t] = s[t] - v;
    if (t == 255) blksum[rel * 256 + b] = s[255];
}

__global__ __launch_bounds__(256) void scan2(unsigned* __restrict__ blksum,
                                             unsigned* __restrict__ rowptr)
{
    __shared__ unsigned s[256];
    int rel = blockIdx.x, t = threadIdx.x;
    unsigned v = blksum[rel * 256 + t];
    s[t] = v; __syncthreads();
    for (int off = 1; off < 256; off <<= 1) {
        unsigned x = (t >= off) ? s[t - off] : 0u;
        __syncthreads();
        s[t] += x;
        __syncthreads();
    }
    blksum[rel * 256 + t] = s[t] - v;
    if (t == 255) rowptr[(size_t)rel * RPS + 65536] = s[255];
}

// fused scan3 + bucket_place
__global__ __launch_bounds__(256) void scan3_place(const unsigned long long* __restrict__ bb,
                                                   const unsigned* __restrict__ bbase,
                                                   unsigned* __restrict__ rowptr,
                                                   const unsigned* __restrict__ blksum,
                                                   int2* __restrict__ epair)
{
    __shared__ unsigned lrp[256], lcur[256];
    int blk = blockIdx.x, rel = blk >> 8, b = blk & 255, t = threadIdx.x;
    unsigned fin = rowptr[(size_t)rel * RPS + b * 256 + t] + blksum[rel * 256 + b];
    rowptr[(size_t)rel * RPS + b * 256 + t] = fin;
    lrp[t] = fin; lcur[t] = 0; __syncthreads();
    unsigned s0 = bbase[blk], s1 = bbase[blk + 1];
    for (unsigned i = s0 + t; i < s1; i += 256) {
        unsigned long long pk = bb[i];
        unsigned s = (unsigned)pk & 0xffffu;
        unsigned d8 = (unsigned)(pk >> 16) & 255u;
        unsigned e = (unsigned)(pk >> 32);
        unsigned pos = atomicAdd(&lcur[d8], 1u);
        epair[(size_t)rel * E2 + lrp[d8] + pos] = make_int2((int)s, (int)e);
    }
}

// ---------------------------------------------------------------------------
// Per-edge (ef @ M) EDGE-ORDERED, packed bf16x4.
// ---------------------------------------------------------------------------
__global__ __launch_bounds__(256) void ef4e_kernel(
    const float* __restrict__ efm, const float* __restrict__ efs,
    const float* __restrict__ efb, const float* __restrict__ eft,
    const float* __restrict__ we, const float* __restrict__ ae,
    uint2* __restrict__ ef4e)
{
    __shared__ float M[8][4];
    int b = blockIdx.x, t = threadIdx.x;
    int er = b >> 10;
    const float* ef = (er == 0) ? efm : (er == 1) ? efs : (er == 2) ? efb : eft;
    if (t < 32) {
        int f = t >> 2, hh = t & 3;
        float s = 0.f;
#pragma unroll 8
        for (int d = 0; d < 32; ++d) s += we[er * 1024 + f * 128 + hh * 32 + d] * ae[er * 128 + hh * 32 + d];
        M[f][hh] = s;
    }
    __syncthreads();
    int e = (b & 1023) * 256 + t;
    float4 a = *(const float4*)(ef + (size_t)e * 8);
    float4 c = *(const float4*)(ef + (size_t)e * 8 + 4);
    float o0 = a.x*M[0][0]+a.y*M[1][0]+a.z*M[2][0]+a.w*M[3][0]+c.x*M[4][0]+c.y*M[5][0]+c.z*M[6][0]+c.w*M[7][0];
    float o1 = a.x*M[0][1]+a.y*M[1][1]+a.z*M[2][1]+a.w*M[3][1]+c.x*M[4][1]+c.y*M[5][1]+c.z*M[6][1]+c.w*M[7][1];
    float o2 = a.x*M[0][2]+a.y*M[1][2]+a.z*M[2][2]+a.w*M[3][2]+c.x*M[4][2]+c.y*M[5][2]+c.z*M[6][2]+c.w*M[7][2];
    float o3 = a.x*M[0][3]+a.y*M[1][3]+a.z*M[2][3]+a.w*M[3][3]+c.x*M[4][3]+c.y*M[5][3]+c.z*M[6][3]+c.w*M[7][3];
    uint2 o; o.x = pk2(o0, o1); o.y = pk2(o2, o3);
    ef4e[(size_t)er * E2 + e] = o;
}

// ---------------------------------------------------------------------------
// Quarter-wave segment helpers (16 lanes/dst, fp8 Z, uint2/lane row cover).
// ---------------------------------------------------------------------------
__device__ __forceinline__ void phys_seg16(
    const unsigned* __restrict__ rowptr, const int2* __restrict__ epair,
    const unsigned short* __restrict__ Zp, int d, unsigned m,
    float rlo[4], float rhi[4])
{
    unsigned s0 = rowptr[d], s1 = rowptr[d + 1];
    float alo[4] = {0, 0, 0, 0}, ahi[4] = {0, 0, 0, 0};
    for (unsigned base = s0; base < s1; base += 4) {
        unsigned nb = s1 - base; if (nb > 4) nb = 4;
        int2 ep[4];
#pragma unroll
        for (int i = 0; i < 4; ++i)
            ep[i] = epair[base + ((unsigned)i < nb ? (unsigned)i : nb - 1)];
        uint2 zv[4];
#pragma unroll
        for (int i = 0; i < 4; ++i)
            zv[i] = ((const uint2*)(Zp + ((unsigned)ep[i].x << 6)))[m];
#pragma unroll
        for (int i = 0; i < 4; ++i) {
            if ((unsigned)i >= nb) break;
            f32x2 a0 = __builtin_amdgcn_cvt_pk_f32_fp8(zv[i].x, false);
            f32x2 a1 = __builtin_amdgcn_cvt_pk_f32_fp8(zv[i].x, true);
            f32x2 a2 = __builtin_amdgcn_cvt_pk_f32_fp8(zv[i].y, false);
            f32x2 a3 = __builtin_amdgcn_cvt_pk_f32_fp8(zv[i].y, true);
            alo[0] += a0.x; ahi[0] += a0.y;
            alo[1] += a1.x; ahi[1] += a1.y;
            alo[2] += a2.x; ahi[2] += a2.y;
            alo[3] += a3.x; ahi[3] += a3.y;
        }
    }
    int cnt = (int)(s1 - s0);
    float inv = 1.0f / (float)(cnt > 0 ? cnt : 1);
#pragma unroll
    for (int j = 0; j < 4; ++j) { rlo[j] += alo[j] * inv; rhi[j] += ahi[j] * inv; }
}

template <bool HAS_EF>
__device__ __forceinline__ void gat_seg16(
    const unsigned* __restrict__ rowptr, const int2* __restrict__ epair,
    const unsigned short* __restrict__ Zp, const float* __restrict__ ls,
    const float* __restrict__ ld, const uint2* __restrict__ ef4e,
    int d, unsigned m, int hs, float rlo[4], float rhi[4])
{
    float4 ldv4 = *(const float4*)(ld + ((unsigned)d << 2));
    float ldlo = hs ? ldv4.y : ldv4.x;
    float ldhi = hs ? ldv4.w : ldv4.z;
    unsigned s0 = rowptr[d], s1 = rowptr[d + 1];
    float nlo[4] = {0, 0, 0, 0}, nhi[4] = {0, 0, 0, 0};
    float dlo = 0.f, dhi = 0.f;
    for (unsigned base = s0; base < s1; base += 4) {
        unsigned nb = s1 - base; if (nb > 4) nb = 4;
        int2 ep[4];
#pragma unroll
        for (int i = 0; i < 4; ++i)
            ep[i] = epair[base + ((unsigned)i < nb ? (unsigned)i : nb - 1)];
        uint2 zv[4]; float4 lsv[4]; uint2 e4[4];
#pragma unroll
        for (int i = 0; i < 4; ++i) {
            zv[i] = ((const uint2*)(Zp + ((unsigned)ep[i].x << 6)))[m];
            lsv[i] = *(const float4*)(ls + ((unsigned)ep[i].x << 2));
            if (HAS_EF) e4[i] = ef4e[(unsigned)ep[i].y];
        }
#pragma unroll
        for (int i = 0; i < 4; ++i) {
            if ((unsigned)i >= nb) break;
            float glo = (hs ? lsv[i].y : lsv[i].x) + ldlo;
            float ghi = (hs ? lsv[i].w : lsv[i].z) + ldhi;
            if (HAS_EF) {
                glo += bf2f(hs ? (e4[i].x >> 16) : (e4[i].x & 0xffffu));
                ghi += bf2f(hs ? (e4[i].y >> 16) : (e4[i].y & 0xffffu));
            }
            glo = glo > 0.f ? glo : 0.2f * glo;
            ghi = ghi > 0.f ? ghi : 0.2f * ghi;
            float xlo = __expf(glo), xhi = __expf(ghi);
            f32x2 a0 = __builtin_amdgcn_cvt_pk_f32_fp8(zv[i].x, false);
            f32x2 a1 = __builtin_amdgcn_cvt_pk_f32_fp8(zv[i].x, true);
            f32x2 a2 = __builtin_amdgcn_cvt_pk_f32_fp8(zv[i].y, false);
            f32x2 a3 = __builtin_amdgcn_cvt_pk_f32_fp8(zv[i].y, true);
            nlo[0] += xlo * a0.x; nhi[0] += xhi * a0.y;
            nlo[1] += xlo * a1.x; nhi[1] += xhi * a1.y;
            nlo[2] += xlo * a2.x; nhi[2] += xhi * a2.y;
            nlo[3] += xlo * a3.x; nhi[3] += xhi * a3.y;
            dlo += xlo; dhi += xhi;
        }
    }
    float ilo = 1.0f / fmaxf(dlo, 1e-9f), ihi = 1.0f / fmaxf(dhi, 1e-9f);
#pragma unroll
    for (int j = 0; j < 4; ++j) { rlo[j] += nlo[j] * ilo; rhi[j] += nhi[j] * ihi; }
}

__device__ __forceinline__ void acc_write16(
    unsigned* __restrict__ accp, int d, unsigned m, bool acc,
    float rlo[4], float rhi[4])
{
    uint4* ap = (uint4*)(accp + ((unsigned)d << 6)) + m;
    if (acc) {
        uint4 o = *ap;
        rlo[0] += bf2f(o.x & 0xffffu); rhi[0] += bf2f(o.x >> 16);
        rlo[1] += bf2f(o.y & 0xffffu); rhi[1] += bf2f(o.y >> 16);
        rlo[2] += bf2f(o.z & 0xffffu); rhi[2] += bf2f(o.z >> 16);
        rlo[3] += bf2f(o.w & 0xffffu); rhi[3] += bf2f(o.w >> 16);
    }
    uint4 nv;
    nv.x = pk2(rlo[0], rhi[0]); nv.y = pk2(rlo[1], rhi[1]);
    nv.z = pk2(rlo[2], rhi[2]); nv.w = pk2(rlo[3], rhi[3]);
    *ap = nv;
}

template <bool ACC>
__global__ __launch_bounds__(256) void phys_gather(
    const unsigned* __restrict__ rowptr, const int2* __restrict__ epair,
    const unsigned short* __restrict__ Zp, unsigned* __restrict__ accp, int n_nodes)
{
    int t = threadIdx.x;
    unsigned m = (unsigned)(t & 15);
    int d = blockIdx.x * 16 + (t >> 4);
    if (d >= n_nodes) return;
    float rlo[4] = {0, 0, 0, 0}, rhi[4] = {0, 0, 0, 0};
    phys_seg16(rowptr, epair, Zp, d, m, rlo, rhi);
    acc_write16(accp, d, m, ACC, rlo, rhi);
}

template <bool ACC>
__global__ __launch_bounds__(256) void dual_phys(
    const unsigned* __restrict__ rpA, const int2* __restrict__ epA,
    const unsigned short* __restrict__ ZA,
    const unsigned* __restrict__ rpB, const int2* __restrict__ epB,
    const unsigned short* __restrict__ ZB,
    unsigned* __restrict__ accp, int n_nodes)
{
    int t = threadIdx.x;
    unsigned m = (unsigned)(t & 15);
    int d = blockIdx.x * 16 + (t >> 4);
    if (d >= n_nodes) return;
    float rlo[4] = {0, 0, 0, 0}, rhi[4] = {0, 0, 0, 0};
    phys_seg16(rpA, epA, ZA, d, m, rlo, rhi);
    phys_seg16(rpB, epB, ZB, d, m, rlo, rhi);
    acc_write16(accp, d, m, ACC, rlo, rhi);
}

template <bool EF, bool ACC>
__global__ __launch_bounds__(256) void gat_gather(
    const unsigned* __restrict__ rowptr, const int2* __restrict__ epair,
    const unsigned short* __restrict__ Zp, const float* __restrict__ ls,
    const float* __restrict__ ld, const uint2* __restrict__ ef4e,
    unsigned* __restrict__ accp, int n_nodes)
{
    int t = threadIdx.x;
    unsigned m = (unsigned)(t & 15);
    int d = blockIdx.x * 16 + (t >> 4);
    if (d >= n_nodes) return;
    int hs = (int)(m >> 3);
    float rlo[4] = {0, 0, 0, 0}, rhi[4] = {0, 0, 0, 0};
    gat_seg16<EF>(rowptr, epair, Zp, ls, ld, ef4e, d, m, hs, rlo, rhi);
    acc_write16(accp, d, m, ACC, rlo, rhi);
}

template <bool EFA, bool EFB, bool ACC>
__global__ __launch_bounds__(256) void dual_gat(
    const unsigned* __restrict__ rpA, const int2* __restrict__ epA,
    const unsigned short* __restrict__ ZA, const float* __restrict__ lsA,
    const float* __restrict__ ldA, const uint2* __restrict__ efA,
    const unsigned* __restrict__ rpB, const int2* __restrict__ epB,
    const unsigned short* __restrict__ ZB, const float* __restrict__ lsB,
    const float* __restrict__ ldB, const uint2* __restrict__ efB,
    unsigned* __restrict__ accp, int n_nodes)
{
    int t = threadIdx.x;
    unsigned m = (unsigned)(t & 15);
    int d = blockIdx.x * 16 + (t >> 4);
    if (d >= n_nodes) return;
    int hs = (int)(m >> 3);
    float rlo[4] = {0, 0, 0, 0}, rhi[4] = {0, 0, 0, 0};
    gat_seg16<EFA>(rpA, epA, ZA, lsA, ldA, efA, d, m, hs, rlo, rhi);
    gat_seg16<EFB>(rpB, epB, ZB, lsB, ldB, efB, d, m, hs, rlo, rhi);
    acc_write16(accp, d, m, ACC, rlo, rhi);
}

// ---------------------------------------------------------------------------
// Merged FFN over all 3 node types: block -> type by range; cheap GELU.
// 128 rows/block, double-buffered weight LDS (80 KB -> 2 blocks/CU).
// ---------------------------------------------------------------------------
struct FP {
    const float* h[3]; const unsigned* ac[3];
    const float* g[3]; const float* b[3];
    const unsigned short* w1[3]; const float* bb1[3];
    const unsigned short* w2[3]; const float* bb2[3];
    float* out[3]; float invC[3];
    int n1, n2;   // block range starts for type 1 and 2
};

__global__ __launch_bounds__(256, 2) void ffn_all(FP P)
{
    __shared__ unsigned short WB[2][16384];
    __shared__ float HW[4][1024];
    int blk = blockIdx.x;
    int ti = (blk >= P.n2) ? 2 : (blk >= P.n1) ? 1 : 0;
    int lb = blk - (ti == 2 ? P.n2 : ti == 1 ? P.n1 : 0);
    const float* h = P.h[ti];
    const unsigned* accp = P.ac[ti];
    const float* g = P.g[ti];
    const float* b = P.b[ti];
    const unsigned short* w1t = P.w1[ti];
    const float* b1 = P.bb1[ti];
    const unsigned short* w2t = P.w2[ti];
    const float* b2 = P.bb2[ti];
    float* out = P.out[ti];
    float invC = P.invC[ti];

    int t = threadIdx.x, w = t >> 6, l = t & 63;
    int l15 = l & 15, lq = l >> 4;
    size_t rw = (size_t)lb * 128 + w * 32;
    float* myHW = HW[w];

    bf16x8 af[2][4];
#pragma unroll
    for (int rf = 0; rf < 2; ++rf) {
        size_t myrow = rw + rf * 16 + l15;
        const unsigned* ap = accp + myrow * 64 + lq * 8;
        uint4 ua0 = *(const uint4*)(ap);
        uint4 ua1 = *(const uint4*)(ap + 4);
        uint4 ub0 = *(const uint4*)(ap + 32);
        uint4 ub1 = *(const uint4*)(ap + 36);
        const float* hp = h + myrow * 128 + lq * 8;
        float4 hf[4][2];
        hf[0][0] = *(const float4*)(hp);      hf[0][1] = *(const float4*)(hp + 4);
        hf[1][0] = *(const float4*)(hp + 32); hf[1][1] = *(const float4*)(hp + 36);
        hf[2][0] = *(const float4*)(hp + 64); hf[2][1] = *(const float4*)(hp + 68);
        hf[3][0] = *(const float4*)(hp + 96); hf[3][1] = *(const float4*)(hp + 100);
        unsigned ua[8] = {ua0.x, ua0.y, ua0.z, ua0.w, ua1.x, ua1.y, ua1.z, ua1.w};
        unsigned ub[8] = {ub0.x, ub0.y, ub0.z, ub0.w, ub1.x, ub1.y, ub1.z, ub1.w};
        float hv[4][8];
#pragma unroll
        for (int j = 0; j < 8; ++j) {
            hv[0][j] = ((const float*)hf[0])[j] + bf2f(ua[j] & 0xffffu) * invC;
            hv[1][j] = ((const float*)hf[1])[j] + bf2f(ub[j] & 0xffffu) * invC;
            hv[2][j] = ((const float*)hf[2])[j] + bf2f(ua[j] >> 16) * invC;
            hv[3][j] = ((const float*)hf[3])[j] + bf2f(ub[j] >> 16) * invC;
        }
        float s = 0.f;
#pragma unroll
        for (int ks = 0; ks < 4; ++ks)
#pragma unroll
            for (int j = 0; j < 8; ++j) s += hv[ks][j];
        s += __shfl_xor(s, 16); s += __shfl_xor(s, 32);
        float mean = s * (1.0f / 128.0f);
        float v = 0.f;
#pragma unroll
        for (int ks = 0; ks < 4; ++ks)
#pragma unroll
            for (int j = 0; j < 8; ++j) { float dd = hv[ks][j] - mean; v += dd * dd; }
        v += __shfl_xor(v, 16); v += __shfl_xor(v, 32);
        float rstd = rsqrtf(v * (1.0f / 128.0f) + 1e-5f);
#pragma unroll
        for (int ks = 0; ks < 4; ++ks) {
            int col0 = ks * 32 + lq * 8;
            float y[8];
#pragma unroll
            for (int j = 0; j < 8; ++j)
                y[j] = g[col0 + j] * (hv[ks][j] - mean) * rstd + b[col0 + j];
            af[rf][ks] = pack8(y);
        }
    }

#pragma unroll
    for (int i = 0; i < 4; ++i) {
        gll16(w1t + i * 2048 + t * 8, (char*)WB[0] + i * 4096 + t * 16);
        gll16(w2t + i * 2048 + t * 8, (char*)WB[0] + 16384 + i * 4096 + t * 16);
    }
    f32x4 facc[2][8];
#pragma unroll
    for (int rf = 0; rf < 2; ++rf)
#pragma unroll
        for (int n = 0; n < 8; ++n) facc[rf][n] = (f32x4){0.f, 0.f, 0.f, 0.f};
    __syncthreads();

    int buf = 0;
    int swR = (l15 & 7) << 2;
    for (int ch = 0; ch < 8; ++ch) {
        if (ch < 7) {
            const unsigned short* s1p = w1t + (ch + 1) * 8192;
            const unsigned short* s2p = w2t + (ch + 1) * 8192;
#pragma unroll
            for (int i = 0; i < 4; ++i) {
                gll16(s1p + i * 2048 + t * 8, (char*)WB[buf ^ 1] + i * 4096 + t * 16);
                gll16(s2p + i * 2048 + t * 8, (char*)WB[buf ^ 1] + 16384 + i * 4096 + t * 16);
            }
        }
        f32x4 acc1[2][4];
#pragma unroll
        for (int rf = 0; rf < 2; ++rf)
#pragma unroll
            for (int n = 0; n < 4; ++n) acc1[rf][n] = (f32x4){0.f, 0.f, 0.f, 0.f};
#pragma unroll
        for (int ks = 0; ks < 4; ++ks)
#pragma unroll
            for (int nf = 0; nf < 4; ++nf) {
                bf16x8 bw = *(const bf16x8*)(WB[buf] + ((nf * 4 + ks) * 64 + l) * 8);
                acc1[0][nf] = __builtin_amdgcn_mfma_f32_16x16x32_bf16(af[0][ks], bw, acc1[0][nf], 0, 0, 0);
                acc1[1][nf] = __builtin_amdgcn_mfma_f32_16x16x32_bf16(af[1][ks], bw, acc1[1][nf], 0, 0, 0);
            }
#pragma unroll
        for (int rf = 0; rf < 2; ++rf) {
#pragma unroll
            for (int nf = 0; nf < 4; ++nf) {
                float bv = b1[ch * 64 + nf * 16 + l15];
#pragma unroll
                for (int reg = 0; reg < 4; ++reg) {
                    int row = lq * 4 + reg;
                    float x = acc1[rf][nf][reg] + bv;
                    myHW[row * 64 + ((nf * 16 + l15) ^ ((row & 7) << 2))] = gelu(x);
                }
            }
#pragma unroll
            for (int ks2 = 0; ks2 < 2; ++ks2) {
                int cb = ks2 * 32 + lq * 8;
                f32x4 x0 = *(const f32x4*)(myHW + l15 * 64 + (cb ^ swR));
                f32x4 x1 = *(const f32x4*)(myHW + l15 * 64 + ((cb + 4) ^ swR));
                bf16x8 a2 = pack8v(x0, x1);
#pragma unroll
                for (int nf = 0; nf < 8; ++nf) {
                    bf16x8 bw = *(const bf16x8*)(WB[buf] + 8192 + ((ks2 * 8 + nf) * 64 + l) * 8);
                    facc[rf][nf] = __builtin_amdgcn_mfma_f32_16x16x32_bf16(a2, bw, facc[rf][nf], 0, 0, 0);
                }
            }
        }
        __syncthreads();
        buf ^= 1;
    }
#pragma unroll
    for (int rf = 0; rf < 2; ++rf)
#pragma unroll
        for (int nf = 0; nf < 8; ++nf) {
            int col = nf * 16 + l15;
            float bv = b2[col];
            int ci = col & 63;
            bool hi = col >= 64;
#pragma unroll
            for (int reg = 0; reg < 4; ++reg) {
                size_t row = rw + rf * 16 + lq * 4 + reg;
                unsigned pv = accp[row * 64 + ci];
                float av = bf2f(hi ? (pv >> 16) : (pv & 0xffffu));
                out[row * 128 + col] = h[row * 128 + col] + av * invC + facc[rf][nf][reg] + bv;
            }
        }
}

// ---------------------------------------------------------------------------
extern "C" void kernel_launch(void* const* d_in, const int* in_sizes, int n_in,
                              void* d_out, int out_size, void* d_ws, size_t ws_size,
                              hipStream_t stream)
{
    const float* h_enz  = (const float*)d_in[0];
    const float* h_met  = (const float*)d_in[1];
    const float* h_rxn  = (const float*)d_in[2];
    const float* ef_mod = (const float*)d_in[3];
    const float* ef_sig = (const float*)d_in[4];
    const float* ef_brg = (const float*)d_in[5];
    const float* ef_trn = (const float*)d_in[6];
    const float* ln1_g  = (const float*)d_in[7];
    const float* ln1_b  = (const float*)d_in[8];
    const float* ln2_g  = (const float*)d_in[9];
    const float* ln2_b  = (const float*)d_in[10];
    const float* wp     = (const float*)d_in[11];
    const float* bp     = (const float*)d_in[12];
    const float* wl     = (const float*)d_in[13];
    const float* a_src  = (const float*)d_in[14];
    const float* a_dst  = (const float*)d_in[15];
    const float* we     = (const float*)d_in[16];
    const float* a_edge = (const float*)d_in[17];
    const float* w1     = (const float*)d_in[18];
    const float* b1     = (const float*)d_in[19];
    const float* w2     = (const float*)d_in[20];
    const float* b2     = (const float*)d_in[21];
    const int* src_sub  = (const int*)d_in[22];
    const int* dst_sub  = (const int*)d_in[23];
    const int* src_prod = (const int*)d_in[24];
    const int* dst_prod = (const int*)d_in[25];
    const int* src_cat  = (const int*)d_in[26];
    const int* dst_cat  = (const int*)d_in[27];
    const int* src_mod  = (const int*)d_in[28];
    const int* dst_mod  = (const int*)d_in[29];
    const int* src_reg  = (const int*)d_in[30];
    const int* dst_reg  = (const int*)d_in[31];
    const int* src_sig  = (const int*)d_in[32];
    const int* dst_sig  = (const int*)d_in[33];
    const int* src_brg  = (const int*)d_in[34];
    const int* dst_brg  = (const int*)d_in[35];
    const int* src_trn  = (const int*)d_in[36];
    const int* dst_trn  = (const int*)d_in[37];
    float* out = (float*)d_out;

    // workspace (~90 MB; proven budget >= 116.6 MB)
    char* p = (char*)d_ws;
    unsigned* accp = (unsigned*)p;            p += (size_t)NTOT * 64 * 4;     // 37.75 MB
    unsigned short* ZpA = (unsigned short*)p; p += (size_t)NM * 64 * 2;       // 8.39 MB
    unsigned long long* bukbuf = (unsigned long long*)p;                      // alias:
    unsigned short* ZpB = (unsigned short*)p; p += (size_t)8 * E2 * 8;        // 16.78 MB
    int2* epair = (int2*)p;                   p += (size_t)8 * E2 * 8;        // 16.78 MB
    uint2* ef4e = (uint2*)p;                  p += (size_t)4 * E2 * 8;        // 8.39 MB
    float* ls3 = (float*)p;                   p += (size_t)NE * 4 * 4;
    float* ld3 = (float*)p;                   p += (size_t)NR * 4 * 4;
    float* ls4 = (float*)p;                   p += (size_t)NE * 4 * 4;
    float* ld4 = (float*)p;                   p += (size_t)NE * 4 * 4;
    float* ls5 = (float*)p;                   p += (size_t)NM * 4 * 4;
    float* ld5 = (float*)p;                   p += (size_t)NE * 4 * 4;
    float* ls6 = (float*)p;                   p += (size_t)NM * 4 * 4;
    float* ld6 = (float*)p;                   p += (size_t)NM * 4 * 4;
    float* ls7 = (float*)p;                   p += (size_t)NM * 4 * 4;
    float* ld7 = (float*)p;                   p += (size_t)NM * 4 * 4;
    unsigned short* wbf = (unsigned short*)p; p += (size_t)524288 * 2;
    unsigned short* wq  = (unsigned short*)p; p += (size_t)7 * 2048 * 2;
    unsigned* rowptr = (unsigned*)p;          p += (size_t)8 * RPS * 4;
    unsigned* bcnt = (unsigned*)p;            p += 2048 * 4;
    unsigned* bbase = (unsigned*)p;           p += 2049 * 4;
    unsigned* bcur = (unsigned*)p;            p += 2048 * 4;
    unsigned* blksum = (unsigned*)p;          p += (size_t)8 * 256 * 4;
    if (ws_size < (size_t)(p - (char*)d_ws)) return;

    unsigned* nrm32 = (unsigned*)d_out;
    const unsigned short* nbf_enz = (const unsigned short*)d_out;
    const unsigned short* nbf_met = nbf_enz + (size_t)NE * 128;
    const unsigned short* nbf_rxn = nbf_enz + (size_t)(NE + NM) * 128;
    unsigned* acc_enz = accp;
    unsigned* acc_met = accp + (size_t)NE * 64;
    unsigned* acc_rxn = accp + (size_t)(NE + NM) * 64;

    P8 dsts, srcs;
    dsts.a[0] = dst_sub;  srcs.a[0] = src_sub;
    dsts.a[1] = dst_prod; srcs.a[1] = src_prod;
    dsts.a[2] = dst_cat;  srcs.a[2] = src_cat;
    dsts.a[3] = dst_mod;  srcs.a[3] = src_mod;
    dsts.a[4] = dst_reg;  srcs.a[4] = src_reg;
    dsts.a[5] = dst_sig;  srcs.a[5] = src_sig;
    dsts.a[6] = dst_brg;  srcs.a[6] = src_brg;
    dsts.a[7] = dst_trn;  srcs.a[7] = src_trn;

    // ---- prep: LN1 + weights + WQ (one dispatch), bucketed CSR, ef.M
    hipMemsetAsync(bcnt, 0, 2048 * 4, stream);
    prep_all<<<LN1_BLK + CONV_BLK + 28, 256, 0, stream>>>(
        h_enz, h_met, h_rxn, ln1_g, ln1_b, nrm32,
        wp, wl, w1, w2, wbf, a_src, a_dst, wq);
    bucket_count<<<1024, 256, 0, stream>>>(dsts, bcnt);
    scanB<<<1, 256, 0, stream>>>(bcnt, bbase, bcur);
    bucket_fill<<<1024, 256, 0, stream>>>(dsts, srcs, bcur, bukbuf);
    hist_scan<<<2048, 256, 0, stream>>>(bukbuf, bbase, rowptr, blksum);
    scan2<<<8, 256, 0, stream>>>(blksum, rowptr);
    scan3_place<<<2048, 256, 0, stream>>>(bukbuf, bbase, rowptr, blksum, epair);
    ef4e_kernel<<<4096, 256, 0, stream>>>(ef_mod, ef_sig, ef_brg, ef_trn, we, a_edge, ef4e);

#define RP(r) (rowptr + (size_t)(r) * RPS)
#define EP(r) (epair + (size_t)(r) * E2)
#define WQS(s) (wq + (size_t)(s) * 2048)
#define EF4(er) (ef4e + (size_t)(er) * E2)

    // ---- pair A: rel0 (met->rxn phys, ZpA) + rel2 (enz->rxn phys + ld5, ZpB)
    {
        G2 P = {nbf_met, wbf + 0 * 16384, bp + 0,   ZpA, nullptr, nullptr, nullptr,
                nbf_enz, wbf + 2 * 16384, bp + 256, ZpB, WQS(1),  ld5,     nullptr,
                NM / 128};
        gemm_pair<<<NM / 128 + NE / 128, 256, 0, stream>>>(P);
    }
    dual_phys<false><<<NR / 16, 256, 0, stream>>>(RP(0), EP(0), ZpA, RP(2), EP(2), ZpB,
                                                  acc_rxn, NR);
    // ---- pair B: rel1 (rxn->met phys + ld3, ZpA) + rel3 (enz->rxn gat ls3, ZpB)
    {
        G2 P = {nbf_rxn, wbf + 1 * 16384, bp + 128, ZpA, WQS(0), ld3, nullptr,
                nbf_enz, wbf + 3 * 16384, nullptr,  ZpB, WQS(2), ls3, nullptr,
                NR / 128};
        gemm_pair<<<NR / 128 + NE / 128, 256, 0, stream>>>(P);
    }
    phys_gather<false><<<NM / 16, 256, 0, stream>>>(RP(1), EP(1), ZpA, acc_met, NM);
    gat_gather<true, true><<<NR / 16, 256, 0, stream>>>(RP(3), EP(3), ZpB, ls3, ld3, EF4(0),
                                                        acc_rxn, NR);
    // ---- pair C: rel4 (enz->enz, ls4/ld4, ZpA) + rel5 (met->enz, ls5, ZpB)
    {
        G2 P = {nbf_enz, wbf + 4 * 16384, nullptr, ZpA, WQS(3), ls4, ld4,
                nbf_met, wbf + 5 * 16384, nullptr, ZpB, WQS(4), ls5, nullptr,
                NE / 128};
        gemm_pair<<<NE / 128 + NM / 128, 256, 0, stream>>>(P);
    }
    dual_gat<false, true, false><<<NE / 16, 256, 0, stream>>>(
        RP(4), EP(4), ZpA, ls4, ld4, nullptr,
        RP(5), EP(5), ZpB, ls5, ld5, EF4(1), acc_enz, NE);
    // ---- pair D: rel6 (met->met, ls6/ld6, ZpA) + rel7 (met->met, ls7/ld7, ZpB)
    {
        G2 P = {nbf_met, wbf + 6 * 16384, nullptr, ZpA, WQS(5), ls6, ld6,
                nbf_met, wbf + 7 * 16384, nullptr, ZpB, WQS(6), ls7, ld7,
                NM / 128};
        gemm_pair<<<NM / 128 + NM / 128, 256, 0, stream>>>(P);
    }
    dual_gat<true, true, true><<<NM / 16, 256, 0, stream>>>(
        RP(6), EP(6), ZpA, ls6, ld6, EF4(2),
        RP(7), EP(7), ZpB, ls7, ld7, EF4(3), acc_met, NM);

    // ---- merged FFN over all three node types
    {
        FP P;
        P.h[0] = h_enz; P.h[1] = h_met; P.h[2] = h_rxn;
        P.ac[0] = acc_enz; P.ac[1] = acc_met; P.ac[2] = acc_rxn;
        P.g[0] = ln2_g; P.g[1] = ln2_g + 128; P.g[2] = ln2_g + 256;
        P.b[0] = ln2_b; P.b[1] = ln2_b + 128; P.b[2] = ln2_b + 256;
        P.w1[0] = wbf + W1T_OFF; P.w1[1] = wbf + W1T_OFF + 65536; P.w1[2] = wbf + W1T_OFF + 2 * 65536;
        P.bb1[0] = b1; P.bb1[1] = b1 + 512; P.bb1[2] = b1 + 1024;
        P.w2[0] = wbf + W2T_OFF; P.w2[1] = wbf + W2T_OFF + 65536; P.w2[2] = wbf + W2T_OFF + 2 * 65536;
        P.bb2[0] = b2; P.bb2[1] = b2 + 128; P.bb2[2] = b2 + 256;
        P.out[0] = out; P.out[1] = out + (size_t)NE * 128; P.out[2] = out + (size_t)(NE + NM) * 128;
        P.invC[0] = 0.5f; P.invC[1] = 1.0f / 3.0f; P.invC[2] = 1.0f / 3.0f;
        P.n1 = NE / 128; P.n2 = NE / 128 + NM / 128;
        ffn_all<<<NE / 128 + NM / 128 + NR / 128, 256, 0, stream>>>(P);
    }
#undef RP
#undef EP
#undef WQS
#undef EF4
}

// Round 10
// 439.866 us; speedup vs baseline: 1.4354x; 1.0091x over previous
//
#include <hip/hip_runtime.h>
#include <cstddef>

#define NE 32768
#define NM 65536
#define NR 49152
#define NTOT 147456
#define E2 262144
#define RPS 65537
#define W1T_OFF 131072
#define W2T_OFF 327680
#define LN1_BLK 36864
#define CONV_BLK 2048

typedef __attribute__((ext_vector_type(8))) short bf16x8;
typedef __attribute__((ext_vector_type(4))) float f32x4;
typedef __attribute__((ext_vector_type(2))) float f32x2;

__device__ __forceinline__ unsigned short f2bf(float x) {
    unsigned u = __float_as_uint(x);
    return (unsigned short)((u + 0x7FFFu + ((u >> 16) & 1u)) >> 16);
}
__device__ __forceinline__ float bf2f(unsigned s) { return __uint_as_float(s << 16); }
__device__ __forceinline__ unsigned pk2(float a, float b) {
    return (unsigned)f2bf(a) | ((unsigned)f2bf(b) << 16);
}
__device__ __forceinline__ bf16x8 pack8(const float* v) {
    union { bf16x8 b; unsigned u[4]; } r;
#pragma unroll
    for (int i = 0; i < 4; ++i) r.u[i] = pk2(v[2 * i], v[2 * i + 1]);
    return r.b;
}
__device__ __forceinline__ bf16x8 pack8v(f32x4 a, f32x4 b) {
    union { bf16x8 v; unsigned u[4]; } r;
    r.u[0] = pk2(a[0], a[1]); r.u[1] = pk2(a[2], a[3]);
    r.u[2] = pk2(b[0], b[1]); r.u[3] = pk2(b[2], b[3]);
    return r.v;
}
__device__ __forceinline__ unsigned short pkfp8(float a, float b) {
    return (unsigned short)__builtin_amdgcn_cvt_pk_fp8_f32(a, b, 0u, false);
}
__device__ __forceinline__ void gll16(const void* g, void* l) {
    __builtin_amdgcn_global_load_lds(
        (const __attribute__((address_space(1))) void*)g,
        (__attribute__((address_space(3))) void*)l, 16, 0, 0);
}
// sigmoid-form GELU: x * sigma(1.702 x); |err| <= ~1e-2 at |x|~2, ~5e-3 typical
__device__ __forceinline__ float gelu(float x) {
    float e = __expf(-1.702f * x);
    return x * __builtin_amdgcn_rcpf(1.0f + e);
}

// ---------------------------------------------------------------------------
// prep_all = ln1 (blocks [0,36864)) + convw ([36864,38912)) + wqk (last 28).
// ---------------------------------------------------------------------------
__global__ __launch_bounds__(256) void prep_all(
    const float* __restrict__ he, const float* __restrict__ hm, const float* __restrict__ hr,
    const float* __restrict__ g1, const float* __restrict__ b1g, unsigned* __restrict__ nout,
    const float* __restrict__ wp, const float* __restrict__ wl,
    const float* __restrict__ w1, const float* __restrict__ w2,
    unsigned short* __restrict__ wbf,
    const float* __restrict__ a_src, const float* __restrict__ a_dst,
    unsigned short* __restrict__ wq)
{
    int blk = blockIdx.x, t = threadIdx.x;
    if (blk < LN1_BLK) {
        int row  = blk * 4 + (t >> 6);
        int lane = t & 63;
        const float* src; int ti; int lr;
        if (row < NE)           { src = he; ti = 0; lr = row; }
        else if (row < NE + NM) { src = hm; ti = 1; lr = row - NE; }
        else                    { src = hr; ti = 2; lr = row - NE - NM; }
        float2 x = *(const float2*)(src + (size_t)lr * 128 + lane * 2);
        float s = x.x + x.y;
#pragma unroll
        for (int o = 32; o; o >>= 1) s += __shfl_xor(s, o);
        float mean = s * (1.0f / 128.0f);
        float dx = x.x - mean, dy = x.y - mean;
        float v = dx * dx + dy * dy;
#pragma unroll
        for (int o = 32; o; o >>= 1) v += __shfl_xor(v, o);
        float rstd = rsqrtf(v * (1.0f / 128.0f) + 1e-5f);
        int c = lane * 2;
        float y0 = g1[ti * 128 + c]     * dx * rstd + b1g[ti * 128 + c];
        float y1 = g1[ti * 128 + c + 1] * dy * rstd + b1g[ti * 128 + c + 1];
        nout[(size_t)row * 64 + lane] = pk2(y0, y1);
    } else if (blk < LN1_BLK + CONV_BLK) {
        int i = (blk - LN1_BLK) * 256 + t;
        float v;
        if (i < 131072) {
            int mat = i >> 14, r = i & 16383;
            int frag = r >> 9, lane = (r >> 3) & 63, j = r & 7;
            int nf = frag >> 2, ks = frag & 3;
            int n = nf * 16 + (lane & 15);
            int k = ks * 32 + (lane >> 4) * 8 + j;
            const float* src = (mat < 3) ? (wp + mat * 16384) : (wl + (mat - 3) * 16384);
            v = src[k * 128 + n];
        } else if (i < 327680) {
            int ii = i - 131072; int mat = ii >> 16, r = ii & 65535;
            int frag = r >> 9, lane = (r >> 3) & 63, j = r & 7;
            int nf = frag >> 2, ks = frag & 3;
            int n = nf * 16 + (lane & 15);
            int k = ks * 32 + (lane >> 4) * 8 + j;
            v = w1[mat * 65536 + k * 512 + n];
        } else {
            int ii = i - 327680; int mat = ii >> 16, r = ii & 65535;
            int frag = r >> 9, lane = (r >> 3) & 63, j = r & 7;
            int ks = frag >> 3, nf = frag & 7;
            int n = nf * 16 + (lane & 15);
            int k = ks * 32 + (lane >> 4) * 8 + j;
            v = w2[mat * 65536 + k * 128 + n];
        }
        wbf[i] = f2bf(v);
    } else {
        const int wi[7]  = {0, 2, 0, 1, 2, 3, 4};
        const int loi[7] = {0, 2, 0, 1, 2, 3, 4};
        const int lod[7] = {1, 1, 0, 0, 0, 0, 0};
        const int hii[7] = {-1, -1, -1, 1, -1, 3, 4};
        int bid = blk - LN1_BLK - CONV_BLK;
        int site = bid >> 2, ks = bid & 3;
        const float* W = wl + wi[site] * 16384;
#pragma unroll
        for (int rep = 0; rep < 2; ++rep) {
            int e = t * 2 + rep;
            int lane = e >> 3, j = e & 7;
            int n = lane & 15;
            int k = ks * 32 + (lane >> 4) * 8 + j;
            float v = 0.f;
            if (n < 4) {
                const float* a = (lod[site] ? a_dst : a_src) + loi[site] * 128;
#pragma unroll 8
                for (int d = 0; d < 32; ++d) v += W[k * 128 + n * 32 + d] * a[n * 32 + d];
            } else if (n < 8 && hii[site] >= 0) {
                const float* a = a_dst + hii[site] * 128;
                int hh = n - 4;
#pragma unroll 8
                for (int d = 0; d < 32; ++d) v += W[k * 128 + hh * 32 + d] * a[hh * 32 + d];
            }
            wq[((site * 4 + ks) * 64 + lane) * 8 + j] = f2bf(v);
        }
    }
}

// ---------------------------------------------------------------------------
// Paired GEMM: two sub-problems in one dispatch (runtime flags).
// Z output FP8 (u16 p -> cols (p, p+64)); optional logits via WQ MFMA.
// ---------------------------------------------------------------------------
struct G2 {
    const unsigned short *A0, *Wt0; const float* b0; unsigned short* Z0;
    const unsigned short* Q0; float *oa0, *ob0;
    const unsigned short *A1, *Wt1; const float* b1; unsigned short* Z1;
    const unsigned short* Q1; float *oa1, *ob1;
    int n0;
};

__global__ __launch_bounds__(256) void gemm_pair(G2 P)
{
    __shared__ unsigned short WL[16384];
    int t = threadIdx.x, w = t >> 6, l = t & 63;
    int l15 = l & 15, lq = l >> 4;
    int e = (blockIdx.x >= P.n0) ? 1 : 0;
    const unsigned short* A  = e ? P.A1 : P.A0;
    const unsigned short* Wt = e ? P.Wt1 : P.Wt0;
    const float* bias        = e ? P.b1 : P.b0;
    unsigned short* Zp       = e ? P.Z1 : P.Z0;
    const unsigned short* WQ = e ? P.Q1 : P.Q0;
    float* oa                = e ? P.oa1 : P.oa0;
    float* ob                = e ? P.ob1 : P.ob0;
    int lb = blockIdx.x - (e ? P.n0 : 0);
#pragma unroll
    for (int i = 0; i < 8; ++i)
        gll16(Wt + i * 2048 + t * 8, (char*)WL + i * 4096 + t * 16);
    size_t row0 = (size_t)lb * 128 + w * 32;
    f32x4 acc[2][8]; f32x4 accl[2];
#pragma unroll
    for (int r = 0; r < 2; ++r) {
        accl[r] = (f32x4){0.f, 0.f, 0.f, 0.f};
#pragma unroll
        for (int n = 0; n < 8; ++n) acc[r][n] = (f32x4){0.f, 0.f, 0.f, 0.f};
    }
    bool haslog = (WQ != nullptr);
    bf16x8 qf[4];
    if (haslog) {
#pragma unroll
        for (int ks = 0; ks < 4; ++ks) qf[ks] = *(const bf16x8*)(WQ + (ks * 64 + l) * 8);
    }
    __syncthreads();
#pragma unroll
    for (int ks = 0; ks < 4; ++ks) {
        int k0 = ks * 32 + lq * 8;
        bf16x8 a0 = *(const bf16x8*)(A + (row0 + l15) * 128 + k0);
        bf16x8 a1 = *(const bf16x8*)(A + (row0 + 16 + l15) * 128 + k0);
#pragma unroll
        for (int n = 0; n < 8; ++n) {
            bf16x8 bw = *(const bf16x8*)(WL + ((n * 4 + ks) * 64 + l) * 8);
            acc[0][n] = __builtin_amdgcn_mfma_f32_16x16x32_bf16(a0, bw, acc[0][n], 0, 0, 0);
            acc[1][n] = __builtin_amdgcn_mfma_f32_16x16x32_bf16(a1, bw, acc[1][n], 0, 0, 0);
        }
        if (haslog) {
            accl[0] = __builtin_amdgcn_mfma_f32_16x16x32_bf16(a0, qf[ks], accl[0], 0, 0, 0);
            accl[1] = __builtin_amdgcn_mfma_f32_16x16x32_bf16(a1, qf[ks], accl[1], 0, 0, 0);
        }
    }
    bool hasb = (bias != nullptr);
#pragma unroll
    for (int n = 0; n < 4; ++n) {
        float bl = hasb ? bias[n * 16 + l15] : 0.f;
        float bh = hasb ? bias[n * 16 + l15 + 64] : 0.f;
#pragma unroll
        for (int r = 0; r < 2; ++r)
#pragma unroll
            for (int reg = 0; reg < 4; ++reg) {
                size_t row = row0 + r * 16 + lq * 4 + reg;
                Zp[row * 64 + n * 16 + l15] = pkfp8(acc[r][n][reg] + bl, acc[r][n + 4][reg] + bh);
            }
    }
    if (haslog) {
#pragma unroll
        for (int r = 0; r < 2; ++r)
#pragma unroll
            for (int reg = 0; reg < 4; ++reg) {
                size_t row = row0 + r * 16 + lq * 4 + reg;
                if (oa && l15 < 4) oa[row * 4 + l15] = accl[r][reg];
                else if (ob && l15 >= 4 && l15 < 8) ob[row * 4 + (l15 - 4)] = accl[r][reg];
            }
    }
}

// ---------------------------------------------------------------------------
// CSR build, two-level bucket partition.
// ---------------------------------------------------------------------------
struct P8 { const int* a[8]; };
#define CHUNK 2048

__global__ __launch_bounds__(256) void bucket_count(P8 dsts, unsigned* __restrict__ bcnt)
{
    __shared__ unsigned lh[256];
    int blk = blockIdx.x, rel = blk >> 7, cb = blk & 127, t = threadIdx.x;
    lh[t] = 0; __syncthreads();
    const int* dp = dsts.a[rel] + cb * CHUNK;
#pragma unroll
    for (int it = 0; it < 8; ++it) atomicAdd(&lh[dp[it * 256 + t] >> 8], 1u);
    __syncthreads();
    atomicAdd(&bcnt[rel * 256 + t], lh[t]);
}

__global__ __launch_bounds__(256) void scanB(const unsigned* __restrict__ bcnt,
                                             unsigned* __restrict__ bbase,
                                             unsigned* __restrict__ bcur)
{
    __shared__ unsigned ts[256];
    int t = threadIdx.x;
    unsigned v[8]; unsigned run = 0;
#pragma unroll
    for (int i = 0; i < 8; ++i) { v[i] = bcnt[t * 8 + i]; run += v[i]; }
    ts[t] = run; __syncthreads();
    for (int off = 1; off < 256; off <<= 1) {
        unsigned x = (t >= off) ? ts[t - off] : 0u;
        __syncthreads(); ts[t] += x; __syncthreads();
    }
    unsigned base = ts[t] - run;
#pragma unroll
    for (int i = 0; i < 8; ++i) { bbase[t * 8 + i] = base; bcur[t * 8 + i] = base; base += v[i]; }
    if (t == 255) bbase[2048] = base;
}

__global__ __launch_bounds__(256) void bucket_fill(P8 dsts, P8 srcs,
                                                   unsigned* __restrict__ bcur,
                                                   unsigned long long* __restrict__ bb)
{
    __shared__ unsigned lh[256], lbase[256], lcur[256];
    int blk = blockIdx.x, rel = blk >> 7, cb = blk & 127, t = threadIdx.x;
    lh[t] = 0; lcur[t] = 0; __syncthreads();
    const int* dp = dsts.a[rel] + cb * CHUNK;
    const int* sp = srcs.a[rel] + cb * CHUNK;
    int dv[8];
#pragma unroll
    for (int it = 0; it < 8; ++it) { dv[it] = dp[it * 256 + t]; atomicAdd(&lh[dv[it] >> 8], 1u); }
    __syncthreads();
    lbase[t] = atomicAdd(&bcur[rel * 256 + t], lh[t]);
    __syncthreads();
#pragma unroll
    for (int it = 0; it < 8; ++it) {
        unsigned e = (unsigned)(cb * CHUNK + it * 256 + t);
        unsigned d = (unsigned)dv[it];
        unsigned s = (unsigned)sp[it * 256 + t];
        unsigned pos = atomicAdd(&lcur[d >> 8], 1u);
        bb[lbase[d >> 8] + pos] =
            (unsigned long long)s | ((unsigned long long)d << 16) | ((unsigned long long)e << 32);
    }
}

// fused bucket_hist + scan1
__global__ __launch_bounds__(256) void hist_scan(const unsigned long long* __restrict__ bb,
                                                 const unsigned* __restrict__ bbase,
                                                 unsigned* __restrict__ rowptr,
                                                 unsigned* __restrict__ blksum)
{
    __shared__ unsigned lh[256], s[256];
    int blk = blockIdx.x, rel = blk >> 8, b = blk & 255, t = threadIdx.x;
    lh[t] = 0; __syncthreads();
    unsigned s0 = bbase[blk], s1 = bbase[blk + 1];
    for (unsigned i = s0 + t; i < s1; i += 256)
        atomicAdd(&lh[(unsigned)(bb[i] >> 16) & 255u], 1u);
    __syncthreads();
    unsigned v = lh[t];
    s[t] = v; __syncthreads();
    for (int off = 1; off < 256; off <<= 1) {
        unsigned x = (t >= off) ? s[t - off] : 0u;
        __syncthreads();
        s[t] += x;
        __syncthreads();
    }
    rowptr[(size_t)rel * RPS + b * 256 + t] = s[t] - v;
    if (t == 255) blksum[rel * 256 + b] = s[255];
}

__global__ __launch_bounds__(256) void scan2(unsigned* __restrict__ blksum,
                                             unsigned* __restrict__ rowptr)
{
    __shared__ unsigned s[256];
    int rel = blockIdx.x, t = threadIdx.x;
    unsigned v = blksum[rel * 256 + t];
    s[t] = v; __syncthreads();
    for (int off = 1; off < 256; off <<= 1) {
        unsigned x = (t >= off) ? s[t - off] : 0u;
        __syncthreads();
        s[t] += x;
        __syncthreads();
    }
    blksum[rel * 256 + t] = s[t] - v;
    if (t == 255) rowptr[(size_t)rel * RPS + 65536] = s[255];
}

// fused scan3 + bucket_place
__global__ __launch_bounds__(256) void scan3_place(const unsigned long long* __restrict__ bb,
                                                   const unsigned* __restrict__ bbase,
                                                   unsigned* __restrict__ rowptr,
                                                   const unsigned* __restrict__ blksum,
                                                   int2* __restrict__ epair)
{
    __shared__ unsigned lrp[256], lcur[256];
    int blk = blockIdx.x, rel = blk >> 8, b = blk & 255, t = threadIdx.x;
    unsigned fin = rowptr[(size_t)rel * RPS + b * 256 + t] + blksum[rel * 256 + b];
    rowptr[(size_t)rel * RPS + b * 256 + t] = fin;
    lrp[t] = fin; lcur[t] = 0; __syncthreads();
    unsigned s0 = bbase[blk], s1 = bbase[blk + 1];
    for (unsigned i = s0 + t; i < s1; i += 256) {
        unsigned long long pk = bb[i];
        unsigned s = (unsigned)pk & 0xffffu;
        unsigned d8 = (unsigned)(pk >> 16) & 255u;
        unsigned e = (unsigned)(pk >> 32);
        unsigned pos = atomicAdd(&lcur[d8], 1u);
        epair[(size_t)rel * E2 + lrp[d8] + pos] = make_int2((int)s, (int)e);
    }
}

// ---------------------------------------------------------------------------
// Per-edge (ef @ M) EDGE-ORDERED, packed bf16x4.
// ---------------------------------------------------------------------------
__global__ __launch_bounds__(256) void ef4e_kernel(
    const float* __restrict__ efm, const float* __restrict__ efs,
    const float* __restrict__ efb, const float* __restrict__ eft,
    const float* __restrict__ we, const float* __restrict__ ae,
    uint2* __restrict__ ef4e)
{
    __shared__ float M[8][4];
    int b = blockIdx.x, t = threadIdx.x;
    int er = b >> 10;
    const float* ef = (er == 0) ? efm : (er == 1) ? efs : (er == 2) ? efb : eft;
    if (t < 32) {
        int f = t >> 2, hh = t & 3;
        float s = 0.f;
#pragma unroll 8
        for (int d = 0; d < 32; ++d) s += we[er * 1024 + f * 128 + hh * 32 + d] * ae[er * 128 + hh * 32 + d];
        M[f][hh] = s;
    }
    __syncthreads();
    int e = (b & 1023) * 256 + t;
    float4 a = *(const float4*)(ef + (size_t)e * 8);
    float4 c = *(const float4*)(ef + (size_t)e * 8 + 4);
    float o0 = a.x*M[0][0]+a.y*M[1][0]+a.z*M[2][0]+a.w*M[3][0]+c.x*M[4][0]+c.y*M[5][0]+c.z*M[6][0]+c.w*M[7][0];
    float o1 = a.x*M[0][1]+a.y*M[1][1]+a.z*M[2][1]+a.w*M[3][1]+c.x*M[4][1]+c.y*M[5][1]+c.z*M[6][1]+c.w*M[7][1];
    float o2 = a.x*M[0][2]+a.y*M[1][2]+a.z*M[2][2]+a.w*M[3][2]+c.x*M[4][2]+c.y*M[5][2]+c.z*M[6][2]+c.w*M[7][2];
    float o3 = a.x*M[0][3]+a.y*M[1][3]+a.z*M[2][3]+a.w*M[3][3]+c.x*M[4][3]+c.y*M[5][3]+c.z*M[6][3]+c.w*M[7][3];
    uint2 o; o.x = pk2(o0, o1); o.y = pk2(o2, o3);
    ef4e[(size_t)er * E2 + e] = o;
}

// ---------------------------------------------------------------------------
// Quarter-wave segment helpers (16 lanes/dst, fp8 Z, uint2/lane row cover).
// ---------------------------------------------------------------------------
__device__ __forceinline__ void phys_seg16(
    const unsigned* __restrict__ rowptr, const int2* __restrict__ epair,
    const unsigned short* __restrict__ Zp, int d, unsigned m,
    float rlo[4], float rhi[4])
{
    unsigned s0 = rowptr[d], s1 = rowptr[d + 1];
    float alo[4] = {0, 0, 0, 0}, ahi[4] = {0, 0, 0, 0};
    for (unsigned base = s0; base < s1; base += 4) {
        unsigned nb = s1 - base; if (nb > 4) nb = 4;
        int2 ep[4];
#pragma unroll
        for (int i = 0; i < 4; ++i)
            ep[i] = epair[base + ((unsigned)i < nb ? (unsigned)i : nb - 1)];
        uint2 zv[4];
#pragma unroll
        for (int i = 0; i < 4; ++i)
            zv[i] = ((const uint2*)(Zp + ((unsigned)ep[i].x << 6)))[m];
#pragma unroll
        for (int i = 0; i < 4; ++i) {
            if ((unsigned)i >= nb) break;
            f32x2 a0 = __builtin_amdgcn_cvt_pk_f32_fp8(zv[i].x, false);
            f32x2 a1 = __builtin_amdgcn_cvt_pk_f32_fp8(zv[i].x, true);
            f32x2 a2 = __builtin_amdgcn_cvt_pk_f32_fp8(zv[i].y, false);
            f32x2 a3 = __builtin_amdgcn_cvt_pk_f32_fp8(zv[i].y, true);
            alo[0] += a0.x; ahi[0] += a0.y;
            alo[1] += a1.x; ahi[1] += a1.y;
            alo[2] += a2.x; ahi[2] += a2.y;
            alo[3] += a3.x; ahi[3] += a3.y;
        }
    }
    int cnt = (int)(s1 - s0);
    float inv = 1.0f / (float)(cnt > 0 ? cnt : 1);
#pragma unroll
    for (int j = 0; j < 4; ++j) { rlo[j] += alo[j] * inv; rhi[j] += ahi[j] * inv; }
}

template <bool HAS_EF>
__device__ __forceinline__ void gat_seg16(
    const unsigned* __restrict__ rowptr, const int2* __restrict__ epair,
    const unsigned short* __restrict__ Zp, const float* __restrict__ ls,
    const float* __restrict__ ld, const uint2* __restrict__ ef4e,
    int d, unsigned m, int hs, float rlo[4], float rhi[4])
{
    float4 ldv4 = *(const float4*)(ld + ((unsigned)d << 2));
    float ldlo = hs ? ldv4.y : ldv4.x;
    float ldhi = hs ? ldv4.w : ldv4.z;
    unsigned s0 = rowptr[d], s1 = rowptr[d + 1];
    float nlo[4] = {0, 0, 0, 0}, nhi[4] = {0, 0, 0, 0};
    float dlo = 0.f, dhi = 0.f;
    for (unsigned base = s0; base < s1; base += 4) {
        unsigned nb = s1 - base; if (nb > 4) nb = 4;
        int2 ep[4];
#pragma unroll
        for (int i = 0; i < 4; ++i)
            ep[i] = epair[base + ((unsigned)i < nb ? (unsigned)i : nb - 1)];
        uint2 zv[4]; float4 lsv[4]; uint2 e4[4];
#pragma unroll
        for (int i = 0; i < 4; ++i) {
            zv[i] = ((const uint2*)(Zp + ((unsigned)ep[i].x << 6)))[m];
            lsv[i] = *(const float4*)(ls + ((unsigned)ep[i].x << 2));
            if (HAS_EF) e4[i] = ef4e[(unsigned)ep[i].y];
        }
#pragma unroll
        for (int i = 0; i < 4; ++i) {
            if ((unsigned)i >= nb) break;
            float glo = (hs ? lsv[i].y : lsv[i].x) + ldlo;
            float ghi = (hs ? lsv[i].w : lsv[i].z) + ldhi;
            if (HAS_EF) {
                glo += bf2f(hs ? (e4[i].x >> 16) : (e4[i].x & 0xffffu));
                ghi += bf2f(hs ? (e4[i].y >> 16) : (e4[i].y & 0xffffu));
            }
            glo = glo > 0.f ? glo : 0.2f * glo;
            ghi = ghi > 0.f ? ghi : 0.2f * ghi;
            float xlo = __expf(glo), xhi = __expf(ghi);
            f32x2 a0 = __builtin_amdgcn_cvt_pk_f32_fp8(zv[i].x, false);
            f32x2 a1 = __builtin_amdgcn_cvt_pk_f32_fp8(zv[i].x, true);
            f32x2 a2 = __builtin_amdgcn_cvt_pk_f32_fp8(zv[i].y, false);
            f32x2 a3 = __builtin_amdgcn_cvt_pk_f32_fp8(zv[i].y, true);
            nlo[0] += xlo * a0.x; nhi[0] += xhi * a0.y;
            nlo[1] += xlo * a1.x; nhi[1] += xhi * a1.y;
            nlo[2] += xlo * a2.x; nhi[2] += xhi * a2.y;
            nlo[3] += xlo * a3.x; nhi[3] += xhi * a3.y;
            dlo += xlo; dhi += xhi;
        }
    }
    float ilo = 1.0f / fmaxf(dlo, 1e-9f), ihi = 1.0f / fmaxf(dhi, 1e-9f);
#pragma unroll
    for (int j = 0; j < 4; ++j) { rlo[j] += nlo[j] * ilo; rhi[j] += nhi[j] * ihi; }
}

__device__ __forceinline__ void acc_write16(
    unsigned* __restrict__ accp, int d, unsigned m, bool acc,
    float rlo[4], float rhi[4])
{
    uint4* ap = (uint4*)(accp + ((unsigned)d << 6)) + m;
    if (acc) {
        uint4 o = *ap;
        rlo[0] += bf2f(o.x & 0xffffu); rhi[0] += bf2f(o.x >> 16);
        rlo[1] += bf2f(o.y & 0xffffu); rhi[1] += bf2f(o.y >> 16);
        rlo[2] += bf2f(o.z & 0xffffu); rhi[2] += bf2f(o.z >> 16);
        rlo[3] += bf2f(o.w & 0xffffu); rhi[3] += bf2f(o.w >> 16);
    }
    uint4 nv;
    nv.x = pk2(rlo[0], rhi[0]); nv.y = pk2(rlo[1], rhi[1]);
    nv.z = pk2(rlo[2], rhi[2]); nv.w = pk2(rlo[3], rhi[3]);
    *ap = nv;
}

template <bool ACC>
__global__ __launch_bounds__(256) void phys_gather(
    const unsigned* __restrict__ rowptr, const int2* __restrict__ epair,
    const unsigned short* __restrict__ Zp, unsigned* __restrict__ accp, int n_nodes)
{
    int t = threadIdx.x;
    unsigned m = (unsigned)(t & 15);
    int d = blockIdx.x * 16 + (t >> 4);
    if (d >= n_nodes) return;
    float rlo[4] = {0, 0, 0, 0}, rhi[4] = {0, 0, 0, 0};
    phys_seg16(rowptr, epair, Zp, d, m, rlo, rhi);
    acc_write16(accp, d, m, ACC, rlo, rhi);
}

template <bool ACC>
__global__ __launch_bounds__(256) void dual_phys(
    const unsigned* __restrict__ rpA, const int2* __restrict__ epA,
    const unsigned short* __restrict__ ZA,
    const unsigned* __restrict__ rpB, const int2* __restrict__ epB,
    const unsigned short* __restrict__ ZB,
    unsigned* __restrict__ accp, int n_nodes)
{
    int t = threadIdx.x;
    unsigned m = (unsigned)(t & 15);
    int d = blockIdx.x * 16 + (t >> 4);
    if (d >= n_nodes) return;
    float rlo[4] = {0, 0, 0, 0}, rhi[4] = {0, 0, 0, 0};
    phys_seg16(rpA, epA, ZA, d, m, rlo, rhi);
    phys_seg16(rpB, epB, ZB, d, m, rlo, rhi);
    acc_write16(accp, d, m, ACC, rlo, rhi);
}

template <bool EF, bool ACC>
__global__ __launch_bounds__(256) void gat_gather(
    const unsigned* __restrict__ rowptr, const int2* __restrict__ epair,
    const unsigned short* __restrict__ Zp, const float* __restrict__ ls,
    const float* __restrict__ ld, const uint2* __restrict__ ef4e,
    unsigned* __restrict__ accp, int n_nodes)
{
    int t = threadIdx.x;
    unsigned m = (unsigned)(t & 15);
    int d = blockIdx.x * 16 + (t >> 4);
    if (d >= n_nodes) return;
    int hs = (int)(m >> 3);
    float rlo[4] = {0, 0, 0, 0}, rhi[4] = {0, 0, 0, 0};
    gat_seg16<EF>(rowptr, epair, Zp, ls, ld, ef4e, d, m, hs, rlo, rhi);
    acc_write16(accp, d, m, ACC, rlo, rhi);
}

template <bool EFA, bool EFB, bool ACC>
__global__ __launch_bounds__(256) void dual_gat(
    const unsigned* __restrict__ rpA, const int2* __restrict__ epA,
    const unsigned short* __restrict__ ZA, const float* __restrict__ lsA,
    const float* __restrict__ ldA, const uint2* __restrict__ efA,
    const unsigned* __restrict__ rpB, const int2* __restrict__ epB,
    const unsigned short* __restrict__ ZB, const float* __restrict__ lsB,
    const float* __restrict__ ldB, const uint2* __restrict__ efB,
    unsigned* __restrict__ accp, int n_nodes)
{
    int t = threadIdx.x;
    unsigned m = (unsigned)(t & 15);
    int d = blockIdx.x * 16 + (t >> 4);
    if (d >= n_nodes) return;
    int hs = (int)(m >> 3);
    float rlo[4] = {0, 0, 0, 0}, rhi[4] = {0, 0, 0, 0};
    gat_seg16<EFA>(rpA, epA, ZA, lsA, ldA, efA, d, m, hs, rlo, rhi);
    gat_seg16<EFB>(rpB, epB, ZB, lsB, ldB, efB, d, m, hs, rlo, rhi);
    acc_write16(accp, d, m, ACC, rlo, rhi);
}

// ---------------------------------------------------------------------------
// Merged FFN v2: 32-col chunks, 40 KB LDS -> 4 blocks/CU; dbuf retained.
// WB[b] layout (u16): [0,4096) w1-chunk (frags nfL*4+ks), [4096,8192) w2-chunk
// (frags nf2, ksLocal=0).  HW: per-wave 16x32 f32 swizzled transpose.
// ---------------------------------------------------------------------------
struct FP {
    const float* h[3]; const unsigned* ac[3];
    const float* g[3]; const float* b[3];
    const unsigned short* w1[3]; const float* bb1[3];
    const unsigned short* w2[3]; const float* bb2[3];
    float* out[3]; float invC[3];
    int n1, n2;
};

__global__ __launch_bounds__(256, 3) void ffn_all(FP P)
{
    __shared__ unsigned short WB[2][8192];   // 2 x 16 KB
    __shared__ float HW[4][512];             // 8 KB
    int blk = blockIdx.x;
    int ti = (blk >= P.n2) ? 2 : (blk >= P.n1) ? 1 : 0;
    int lb = blk - (ti == 2 ? P.n2 : ti == 1 ? P.n1 : 0);
    const float* h = P.h[ti];
    const unsigned* accp = P.ac[ti];
    const float* g = P.g[ti];
    const float* b = P.b[ti];
    const unsigned short* w1t = P.w1[ti];
    const float* b1 = P.bb1[ti];
    const unsigned short* w2t = P.w2[ti];
    const float* b2 = P.bb2[ti];
    float* out = P.out[ti];
    float invC = P.invC[ti];

    int t = threadIdx.x, w = t >> 6, l = t & 63;
    int l15 = l & 15, lq = l >> 4;
    size_t rw = (size_t)lb * 128 + w * 32;
    float* myHW = HW[w];

    // ---- LN + A-frag pack for both 16-row frags
    bf16x8 af[2][4];
#pragma unroll
    for (int rf = 0; rf < 2; ++rf) {
        size_t myrow = rw + rf * 16 + l15;
        const unsigned* ap = accp + myrow * 64 + lq * 8;
        uint4 ua0 = *(const uint4*)(ap);
        uint4 ua1 = *(const uint4*)(ap + 4);
        uint4 ub0 = *(const uint4*)(ap + 32);
        uint4 ub1 = *(const uint4*)(ap + 36);
        const float* hp = h + myrow * 128 + lq * 8;
        float4 hf[4][2];
        hf[0][0] = *(const float4*)(hp);      hf[0][1] = *(const float4*)(hp + 4);
        hf[1][0] = *(const float4*)(hp + 32); hf[1][1] = *(const float4*)(hp + 36);
        hf[2][0] = *(const float4*)(hp + 64); hf[2][1] = *(const float4*)(hp + 68);
        hf[3][0] = *(const float4*)(hp + 96); hf[3][1] = *(const float4*)(hp + 100);
        unsigned ua[8] = {ua0.x, ua0.y, ua0.z, ua0.w, ua1.x, ua1.y, ua1.z, ua1.w};
        unsigned ub[8] = {ub0.x, ub0.y, ub0.z, ub0.w, ub1.x, ub1.y, ub1.z, ub1.w};
        float hv[4][8];
#pragma unroll
        for (int j = 0; j < 8; ++j) {
            hv[0][j] = ((const float*)hf[0])[j] + bf2f(ua[j] & 0xffffu) * invC;
            hv[1][j] = ((const float*)hf[1])[j] + bf2f(ub[j] & 0xffffu) * invC;
            hv[2][j] = ((const float*)hf[2])[j] + bf2f(ua[j] >> 16) * invC;
            hv[3][j] = ((const float*)hf[3])[j] + bf2f(ub[j] >> 16) * invC;
        }
        float s = 0.f;
#pragma unroll
        for (int ks = 0; ks < 4; ++ks)
#pragma unroll
            for (int j = 0; j < 8; ++j) s += hv[ks][j];
        s += __shfl_xor(s, 16); s += __shfl_xor(s, 32);
        float mean = s * (1.0f / 128.0f);
        float v = 0.f;
#pragma unroll
        for (int ks = 0; ks < 4; ++ks)
#pragma unroll
            for (int j = 0; j < 8; ++j) { float dd = hv[ks][j] - mean; v += dd * dd; }
        v += __shfl_xor(v, 16); v += __shfl_xor(v, 32);
        float rstd = rsqrtf(v * (1.0f / 128.0f) + 1e-5f);
#pragma unroll
        for (int ks = 0; ks < 4; ++ks) {
            int col0 = ks * 32 + lq * 8;
            float y[8];
#pragma unroll
            for (int j = 0; j < 8; ++j)
                y[j] = g[col0 + j] * (hv[ks][j] - mean) * rstd + b[col0 + j];
            af[rf][ks] = pack8(y);
        }
    }

    // ---- stage chunk 0 (16 KB: 8 KB w1 + 8 KB w2)
#pragma unroll
    for (int i = 0; i < 2; ++i) {
        gll16(w1t + i * 2048 + t * 8, (char*)WB[0] + i * 4096 + t * 16);
        gll16(w2t + i * 2048 + t * 8, (char*)WB[0] + 8192 + i * 4096 + t * 16);
    }
    f32x4 facc[2][8];
#pragma unroll
    for (int rf = 0; rf < 2; ++rf)
#pragma unroll
        for (int n = 0; n < 8; ++n) facc[rf][n] = (f32x4){0.f, 0.f, 0.f, 0.f};
    __syncthreads();

    int buf = 0;
    int swR = (l15 & 7) << 2;
    for (int ch = 0; ch < 16; ++ch) {
        if (ch < 15) {
            const unsigned short* s1p = w1t + (ch + 1) * 4096;
            const unsigned short* s2p = w2t + (ch + 1) * 4096;
#pragma unroll
            for (int i = 0; i < 2; ++i) {
                gll16(s1p + i * 2048 + t * 8, (char*)WB[buf ^ 1] + i * 4096 + t * 16);
                gll16(s2p + i * 2048 + t * 8, (char*)WB[buf ^ 1] + 8192 + i * 4096 + t * 16);
            }
        }
        // gemm1: 32 rows x 32 hidden cols
        f32x4 acc1[2][2];
#pragma unroll
        for (int rf = 0; rf < 2; ++rf)
#pragma unroll
            for (int n = 0; n < 2; ++n) acc1[rf][n] = (f32x4){0.f, 0.f, 0.f, 0.f};
#pragma unroll
        for (int ks = 0; ks < 4; ++ks)
#pragma unroll
            for (int nfL = 0; nfL < 2; ++nfL) {
                bf16x8 bw = *(const bf16x8*)(WB[buf] + ((nfL * 4 + ks) * 64 + l) * 8);
                acc1[0][nfL] = __builtin_amdgcn_mfma_f32_16x16x32_bf16(af[0][ks], bw, acc1[0][nfL], 0, 0, 0);
                acc1[1][nfL] = __builtin_amdgcn_mfma_f32_16x16x32_bf16(af[1][ks], bw, acc1[1][nfL], 0, 0, 0);
            }
        // GELU + transpose + gemm2, per row-frag through the 2 KB wave LDS
#pragma unroll
        for (int rf = 0; rf < 2; ++rf) {
#pragma unroll
            for (int nfL = 0; nfL < 2; ++nfL) {
                float bv = b1[ch * 32 + nfL * 16 + l15];
#pragma unroll
                for (int reg = 0; reg < 4; ++reg) {
                    int row = lq * 4 + reg;
                    float x = acc1[rf][nfL][reg] + bv;
                    myHW[row * 32 + ((nfL * 16 + l15) ^ ((row & 7) << 2))] = gelu(x);
                }
            }
            {
                int cb = lq * 8;
                f32x4 x0 = *(const f32x4*)(myHW + l15 * 32 + (cb ^ swR));
                f32x4 x1 = *(const f32x4*)(myHW + l15 * 32 + ((cb + 4) ^ swR));
                bf16x8 a2 = pack8v(x0, x1);
#pragma unroll
                for (int nf2 = 0; nf2 < 8; ++nf2) {
                    bf16x8 bw = *(const bf16x8*)(WB[buf] + 4096 + (nf2 * 64 + l) * 8);
                    facc[rf][nf2] = __builtin_amdgcn_mfma_f32_16x16x32_bf16(a2, bw, facc[rf][nf2], 0, 0, 0);
                }
            }
        }
        __syncthreads();
        buf ^= 1;
    }
    // ---- epilogue: out = h + acc*invC + ffn + b2 (D layout)
#pragma unroll
    for (int rf = 0; rf < 2; ++rf)
#pragma unroll
        for (int nf = 0; nf < 8; ++nf) {
            int col = nf * 16 + l15;
            float bv = b2[col];
            int ci = col & 63;
            bool hi = col >= 64;
#pragma unroll
            for (int reg = 0; reg < 4; ++reg) {
                size_t row = rw + rf * 16 + lq * 4 + reg;
                unsigned pv = accp[row * 64 + ci];
                float av = bf2f(hi ? (pv >> 16) : (pv & 0xffffu));
                out[row * 128 + col] = h[row * 128 + col] + av * invC + facc[rf][nf][reg] + bv;
            }
        }
}

// ---------------------------------------------------------------------------
extern "C" void kernel_launch(void* const* d_in, const int* in_sizes, int n_in,
                              void* d_out, int out_size, void* d_ws, size_t ws_size,
                              hipStream_t stream)
{
    const float* h_enz  = (const float*)d_in[0];
    const float* h_met  = (const float*)d_in[1];
    const float* h_rxn  = (const float*)d_in[2];
    const float* ef_mod = (const float*)d_in[3];
    const float* ef_sig = (const float*)d_in[4];
    const float* ef_brg = (const float*)d_in[5];
    const float* ef_trn = (const float*)d_in[6];
    const float* ln1_g  = (const float*)d_in[7];
    const float* ln1_b  = (const float*)d_in[8];
    const float* ln2_g  = (const float*)d_in[9];
    const float* ln2_b  = (const float*)d_in[10];
    const float* wp     = (const float*)d_in[11];
    const float* bp     = (const float*)d_in[12];
    const float* wl     = (const float*)d_in[13];
    const float* a_src  = (const float*)d_in[14];
    const float* a_dst  = (const float*)d_in[15];
    const float* we     = (const float*)d_in[16];
    const float* a_edge = (const float*)d_in[17];
    const float* w1     = (const float*)d_in[18];
    const float* b1     = (const float*)d_in[19];
    const float* w2     = (const float*)d_in[20];
    const float* b2     = (const float*)d_in[21];
    const int* src_sub  = (const int*)d_in[22];
    const int* dst_sub  = (const int*)d_in[23];
    const int* src_prod = (const int*)d_in[24];
    const int* dst_prod = (const int*)d_in[25];
    const int* src_cat  = (const int*)d_in[26];
    const int* dst_cat  = (const int*)d_in[27];
    const int* src_mod  = (const int*)d_in[28];
    const int* dst_mod  = (const int*)d_in[29];
    const int* src_reg  = (const int*)d_in[30];
    const int* dst_reg  = (const int*)d_in[31];
    const int* src_sig  = (const int*)d_in[32];
    const int* dst_sig  = (const int*)d_in[33];
    const int* src_brg  = (const int*)d_in[34];
    const int* dst_brg  = (const int*)d_in[35];
    const int* src_trn  = (const int*)d_in[36];
    const int* dst_trn  = (const int*)d_in[37];
    float* out = (float*)d_out;

    // workspace (~90 MB; proven budget >= 116.6 MB)
    char* p = (char*)d_ws;
    unsigned* accp = (unsigned*)p;            p += (size_t)NTOT * 64 * 4;
    unsigned short* ZpA = (unsigned short*)p; p += (size_t)NM * 64 * 2;
    unsigned long long* bukbuf = (unsigned long long*)p;                      // alias:
    unsigned short* ZpB = (unsigned short*)p; p += (size_t)8 * E2 * 8;
    int2* epair = (int2*)p;                   p += (size_t)8 * E2 * 8;
    uint2* ef4e = (uint2*)p;                  p += (size_t)4 * E2 * 8;
    float* ls3 = (float*)p;                   p += (size_t)NE * 4 * 4;
    float* ld3 = (float*)p;                   p += (size_t)NR * 4 * 4;
    float* ls4 = (float*)p;                   p += (size_t)NE * 4 * 4;
    float* ld4 = (float*)p;                   p += (size_t)NE * 4 * 4;
    float* ls5 = (float*)p;                   p += (size_t)NM * 4 * 4;
    float* ld5 = (float*)p;                   p += (size_t)NE * 4 * 4;
    float* ls6 = (float*)p;                   p += (size_t)NM * 4 * 4;
    float* ld6 = (float*)p;                   p += (size_t)NM * 4 * 4;
    float* ls7 = (float*)p;                   p += (size_t)NM * 4 * 4;
    float* ld7 = (float*)p;                   p += (size_t)NM * 4 * 4;
    unsigned short* wbf = (unsigned short*)p; p += (size_t)524288 * 2;
    unsigned short* wq  = (unsigned short*)p; p += (size_t)7 * 2048 * 2;
    unsigned* rowptr = (unsigned*)p;          p += (size_t)8 * RPS * 4;
    unsigned* bcnt = (unsigned*)p;            p += 2048 * 4;
    unsigned* bbase = (unsigned*)p;           p += 2049 * 4;
    unsigned* bcur = (unsigned*)p;            p += 2048 * 4;
    unsigned* blksum = (unsigned*)p;          p += (size_t)8 * 256 * 4;
    if (ws_size < (size_t)(p - (char*)d_ws)) return;

    unsigned* nrm32 = (unsigned*)d_out;
    const unsigned short* nbf_enz = (const unsigned short*)d_out;
    const unsigned short* nbf_met = nbf_enz + (size_t)NE * 128;
    const unsigned short* nbf_rxn = nbf_enz + (size_t)(NE + NM) * 128;
    unsigned* acc_enz = accp;
    unsigned* acc_met = accp + (size_t)NE * 64;
    unsigned* acc_rxn = accp + (size_t)(NE + NM) * 64;

    P8 dsts, srcs;
    dsts.a[0] = dst_sub;  srcs.a[0] = src_sub;
    dsts.a[1] = dst_prod; srcs.a[1] = src_prod;
    dsts.a[2] = dst_cat;  srcs.a[2] = src_cat;
    dsts.a[3] = dst_mod;  srcs.a[3] = src_mod;
    dsts.a[4] = dst_reg;  srcs.a[4] = src_reg;
    dsts.a[5] = dst_sig;  srcs.a[5] = src_sig;
    dsts.a[6] = dst_brg;  srcs.a[6] = src_brg;
    dsts.a[7] = dst_trn;  srcs.a[7] = src_trn;

    // ---- prep: LN1 + weights + WQ (one dispatch), bucketed CSR, ef.M
    hipMemsetAsync(bcnt, 0, 2048 * 4, stream);
    prep_all<<<LN1_BLK + CONV_BLK + 28, 256, 0, stream>>>(
        h_enz, h_met, h_rxn, ln1_g, ln1_b, nrm32,
        wp, wl, w1, w2, wbf, a_src, a_dst, wq);
    bucket_count<<<1024, 256, 0, stream>>>(dsts, bcnt);
    scanB<<<1, 256, 0, stream>>>(bcnt, bbase, bcur);
    bucket_fill<<<1024, 256, 0, stream>>>(dsts, srcs, bcur, bukbuf);
    hist_scan<<<2048, 256, 0, stream>>>(bukbuf, bbase, rowptr, blksum);
    scan2<<<8, 256, 0, stream>>>(blksum, rowptr);
    scan3_place<<<2048, 256, 0, stream>>>(bukbuf, bbase, rowptr, blksum, epair);
    ef4e_kernel<<<4096, 256, 0, stream>>>(ef_mod, ef_sig, ef_brg, ef_trn, we, a_edge, ef4e);

#define RP(r) (rowptr + (size_t)(r) * RPS)
#define EP(r) (epair + (size_t)(r) * E2)
#define WQS(s) (wq + (size_t)(s) * 2048)
#define EF4(er) (ef4e + (size_t)(er) * E2)

    // ---- pair A: rel0 (met->rxn phys, ZpA) + rel2 (enz->rxn phys + ld5, ZpB)
    {
        G2 P = {nbf_met, wbf + 0 * 16384, bp + 0,   ZpA, nullptr, nullptr, nullptr,
                nbf_enz, wbf + 2 * 16384, bp + 256, ZpB, WQS(1),  ld5,     nullptr,
                NM / 128};
        gemm_pair<<<NM / 128 + NE / 128, 256, 0, stream>>>(P);
    }
    dual_phys<false><<<NR / 16, 256, 0, stream>>>(RP(0), EP(0), ZpA, RP(2), EP(2), ZpB,
                                                  acc_rxn, NR);
    // ---- pair B: rel1 (rxn->met phys + ld3, ZpA) + rel3 (enz->rxn gat ls3, ZpB)
    {
        G2 P = {nbf_rxn, wbf + 1 * 16384, bp + 128, ZpA, WQS(0), ld3, nullptr,
                nbf_enz, wbf + 3 * 16384, nullptr,  ZpB, WQS(2), ls3, nullptr,
                NR / 128};
        gemm_pair<<<NR / 128 + NE / 128, 256, 0, stream>>>(P);
    }
    phys_gather<false><<<NM / 16, 256, 0, stream>>>(RP(1), EP(1), ZpA, acc_met, NM);
    gat_gather<true, true><<<NR / 16, 256, 0, stream>>>(RP(3), EP(3), ZpB, ls3, ld3, EF4(0),
                                                        acc_rxn, NR);
    // ---- pair C: rel4 (enz->enz, ls4/ld4, ZpA) + rel5 (met->enz, ls5, ZpB)
    {
        G2 P = {nbf_enz, wbf + 4 * 16384, nullptr, ZpA, WQS(3), ls4, ld4,
                nbf_met, wbf + 5 * 16384, nullptr, ZpB, WQS(4), ls5, nullptr,
                NE / 128};
        gemm_pair<<<NE / 128 + NM / 128, 256, 0, stream>>>(P);
    }
    dual_gat<false, true, false><<<NE / 16, 256, 0, stream>>>(
        RP(4), EP(4), ZpA, ls4, ld4, nullptr,
        RP(5), EP(5), ZpB, ls5, ld5, EF4(1), acc_enz, NE);
    // ---- pair D: rel6 (met->met, ls6/ld6, ZpA) + rel7 (met->met, ls7/ld7, ZpB)
    {
        G2 P = {nbf_met, wbf + 6 * 16384, nullptr, ZpA, WQS(5), ls6, ld6,
                nbf_met, wbf + 7 * 16384, nullptr, ZpB, WQS(6), ls7, ld7,
                NM / 128};
        gemm_pair<<<NM / 128 + NM / 128, 256, 0, stream>>>(P);
    }
    dual_gat<true, true, true><<<NM / 16, 256, 0, stream>>>(
        RP(6), EP(6), ZpA, ls6, ld6, EF4(2),
        RP(7), EP(7), ZpB, ls7, ld7, EF4(3), acc_met, NM);

    // ---- merged FFN over all three node types
    {
        FP P;
        P.h[0] = h_enz; P.h[1] = h_met; P.h[2] = h_rxn;
        P.ac[0] = acc_enz; P.ac[1] = acc_met; P.ac[2] = acc_rxn;
        P.g[0] = ln2_g; P.g[1] = ln2_g + 128; P.g[2] = ln2_g + 256;
        P.b[0] = ln2_b; P.b[1] = ln2_b + 128; P.b[2] = ln2_b + 256;
        P.w1[0] = wbf + W1T_OFF; P.w1[1] = wbf + W1T_OFF + 65536; P.w1[2] = wbf + W1T_OFF + 2 * 65536;
        P.bb1[0] = b1; P.bb1[1] = b1 + 512; P.bb1[2] = b1 + 1024;
        P.w2[0] = wbf + W2T_OFF; P.w2[1] = wbf + W2T_OFF + 65536; P.w2[2] = wbf + W2T_OFF + 2 * 65536;
        P.bb2[0] = b2; P.bb2[1] = b2 + 128; P.bb2[2] = b2 + 256;
        P.out[0] = out; P.out[1] = out + (size_t)NE * 128; P.out[2] = out + (size_t)(NE + NM) * 128;
        P.invC[0] = 0.5f; P.invC[1] = 1.0f / 3.0f; P.invC[2] = 1.0f / 3.0f;
        P.n1 = NE / 128; P.n2 = NE / 128 + NM / 128;
        ffn_all<<<NE / 128 + NM / 128 + NR / 128, 256, 0, stream>>>(P);
    }
#undef RP
#undef EP
#undef WQS
#undef EF4
}

// Round 11
// 438.816 us; speedup vs baseline: 1.4389x; 1.0024x over previous
//
#include <hip/hip_runtime.h>
#include <cstddef>

#define NE 32768
#define NM 65536
#define NR 49152
#define NTOT 147456
#define E2 262144
#define RPS 65537
#define LN1_BLK 36864
#define SQ_BLK 512
#define F8_BLK 1536

typedef __attribute__((ext_vector_type(8))) short bf16x8;
typedef __attribute__((ext_vector_type(4))) float f32x4;
typedef __attribute__((ext_vector_type(2))) float f32x2;

__device__ __forceinline__ unsigned short f2bf(float x) {
    unsigned u = __float_as_uint(x);
    return (unsigned short)((u + 0x7FFFu + ((u >> 16) & 1u)) >> 16);
}
__device__ __forceinline__ float bf2f(unsigned s) { return __uint_as_float(s << 16); }
__device__ __forceinline__ unsigned pk2(float a, float b) {
    return (unsigned)f2bf(a) | ((unsigned)f2bf(b) << 16);
}
__device__ __forceinline__ bf16x8 pack8(const float* v) {
    union { bf16x8 b; unsigned u[4]; } r;
#pragma unroll
    for (int i = 0; i < 4; ++i) r.u[i] = pk2(v[2 * i], v[2 * i + 1]);
    return r.b;
}
__device__ __forceinline__ unsigned short pkfp8(float a, float b) {
    return (unsigned short)__builtin_amdgcn_cvt_pk_fp8_f32(a, b, 0u, false);
}
__device__ __forceinline__ long pk8f8(const float* y) {
    unsigned long long p0 = pkfp8(y[0], y[1]);
    unsigned long long p1 = pkfp8(y[2], y[3]);
    unsigned long long p2 = pkfp8(y[4], y[5]);
    unsigned long long p3 = pkfp8(y[6], y[7]);
    return (long)(p0 | (p1 << 16) | (p2 << 32) | (p3 << 48));
}
__device__ __forceinline__ long pk8f8v(f32x4 a, f32x4 b) {
    float y[8] = {a[0], a[1], a[2], a[3], b[0], b[1], b[2], b[3]};
    return pk8f8(y);
}
__device__ __forceinline__ void gll16(const void* g, void* l) {
    __builtin_amdgcn_global_load_lds(
        (const __attribute__((address_space(1))) void*)g,
        (__attribute__((address_space(3))) void*)l, 16, 0, 0);
}
// sigmoid-form GELU: x * sigma(1.702 x)
__device__ __forceinline__ float gelu(float x) {
    float e = __expf(-1.702f * x);
    return x * __builtin_amdgcn_rcpf(1.0f + e);
}

// ---------------------------------------------------------------------------
// prep_all = ln1 + square-mat bf16 frag-pack + w1/w2 FP8 frag-pack + wqk.
// fp8 layout: w1 (N=512,K=128) nf-major frags (frag=nf*4+ks, 512B each);
//             w2 (N=128,K=512) ks-major (frag=ks*8+nf2).  Chunk ch (32 cols /
//             32 ks) = bytes [ch*4096, +4096) in each.
// ---------------------------------------------------------------------------
__global__ __launch_bounds__(256) void prep_all(
    const float* __restrict__ he, const float* __restrict__ hm, const float* __restrict__ hr,
    const float* __restrict__ g1, const float* __restrict__ b1g, unsigned* __restrict__ nout,
    const float* __restrict__ wp, const float* __restrict__ wl,
    const float* __restrict__ w1, const float* __restrict__ w2,
    unsigned short* __restrict__ wbf, unsigned char* __restrict__ wbf8,
    const float* __restrict__ a_src, const float* __restrict__ a_dst,
    unsigned short* __restrict__ wq)
{
    int blk = blockIdx.x, t = threadIdx.x;
    if (blk < LN1_BLK) {
        int row  = blk * 4 + (t >> 6);
        int lane = t & 63;
        const float* src; int ti; int lr;
        if (row < NE)           { src = he; ti = 0; lr = row; }
        else if (row < NE + NM) { src = hm; ti = 1; lr = row - NE; }
        else                    { src = hr; ti = 2; lr = row - NE - NM; }
        float2 x = *(const float2*)(src + (size_t)lr * 128 + lane * 2);
        float s = x.x + x.y;
#pragma unroll
        for (int o = 32; o; o >>= 1) s += __shfl_xor(s, o);
        float mean = s * (1.0f / 128.0f);
        float dx = x.x - mean, dy = x.y - mean;
        float v = dx * dx + dy * dy;
#pragma unroll
        for (int o = 32; o; o >>= 1) v += __shfl_xor(v, o);
        float rstd = rsqrtf(v * (1.0f / 128.0f) + 1e-5f);
        int c = lane * 2;
        float y0 = g1[ti * 128 + c]     * dx * rstd + b1g[ti * 128 + c];
        float y1 = g1[ti * 128 + c + 1] * dy * rstd + b1g[ti * 128 + c + 1];
        nout[(size_t)row * 64 + lane] = pk2(y0, y1);
    } else if (blk < LN1_BLK + SQ_BLK) {
        int i = (blk - LN1_BLK) * 256 + t;          // [0, 131072)
        int mat = i >> 14, r = i & 16383;
        int frag = r >> 9, lane = (r >> 3) & 63, j = r & 7;
        int nf = frag >> 2, ks = frag & 3;
        int n = nf * 16 + (lane & 15);
        int k = ks * 32 + (lane >> 4) * 8 + j;
        const float* src = (mat < 3) ? (wp + mat * 16384) : (wl + (mat - 3) * 16384);
        wbf[i] = f2bf(src[k * 128 + n]);
    } else if (blk < LN1_BLK + SQ_BLK + F8_BLK) {
        int i = (blk - LN1_BLK - SQ_BLK) * 256 + t; // [0, 393216)
        float v;
        if (i < 196608) {                           // w1 fp8
            int mat = i >> 16, r = i & 65535;
            int frag = r >> 9, lane = (r >> 3) & 63, j = r & 7;
            int nf = frag >> 2, ks = frag & 3;
            int n = nf * 16 + (lane & 15);
            int k = ks * 32 + (lane >> 4) * 8 + j;
            v = w1[mat * 65536 + k * 512 + n];
        } else {                                    // w2 fp8
            int ii = i - 196608;
            int mat = ii >> 16, r = ii & 65535;
            int frag = r >> 9, lane = (r >> 3) & 63, j = r & 7;
            int ks = frag >> 3, nf = frag & 7;
            int n = nf * 16 + (lane & 15);
            int k = ks * 32 + (lane >> 4) * 8 + j;
            v = w2[mat * 65536 + k * 128 + n];
        }
        wbf8[i] = (unsigned char)(__builtin_amdgcn_cvt_pk_fp8_f32(v, 0.f, 0u, false) & 0xffu);
    } else {
        const int wi[7]  = {0, 2, 0, 1, 2, 3, 4};
        const int loi[7] = {0, 2, 0, 1, 2, 3, 4};
        const int lod[7] = {1, 1, 0, 0, 0, 0, 0};
        const int hii[7] = {-1, -1, -1, 1, -1, 3, 4};
        int bid = blk - LN1_BLK - SQ_BLK - F8_BLK;
        int site = bid >> 2, ks = bid & 3;
        const float* W = wl + wi[site] * 16384;
#pragma unroll
        for (int rep = 0; rep < 2; ++rep) {
            int e = t * 2 + rep;
            int lane = e >> 3, j = e & 7;
            int n = lane & 15;
            int k = ks * 32 + (lane >> 4) * 8 + j;
            float v = 0.f;
            if (n < 4) {
                const float* a = (lod[site] ? a_dst : a_src) + loi[site] * 128;
#pragma unroll 8
                for (int d = 0; d < 32; ++d) v += W[k * 128 + n * 32 + d] * a[n * 32 + d];
            } else if (n < 8 && hii[site] >= 0) {
                const float* a = a_dst + hii[site] * 128;
                int hh = n - 4;
#pragma unroll 8
                for (int d = 0; d < 32; ++d) v += W[k * 128 + hh * 32 + d] * a[hh * 32 + d];
            }
            wq[((site * 4 + ks) * 64 + lane) * 8 + j] = f2bf(v);
        }
    }
}

// ---------------------------------------------------------------------------
// Paired GEMM (unchanged from round 10).
// ---------------------------------------------------------------------------
struct G2 {
    const unsigned short *A0, *Wt0; const float* b0; unsigned short* Z0;
    const unsigned short* Q0; float *oa0, *ob0;
    const unsigned short *A1, *Wt1; const float* b1; unsigned short* Z1;
    const unsigned short* Q1; float *oa1, *ob1;
    int n0;
};

__global__ __launch_bounds__(256) void gemm_pair(G2 P)
{
    __shared__ unsigned short WL[16384];
    int t = threadIdx.x, w = t >> 6, l = t & 63;
    int l15 = l & 15, lq = l >> 4;
    int e = (blockIdx.x >= P.n0) ? 1 : 0;
    const unsigned short* A  = e ? P.A1 : P.A0;
    const unsigned short* Wt = e ? P.Wt1 : P.Wt0;
    const float* bias        = e ? P.b1 : P.b0;
    unsigned short* Zp       = e ? P.Z1 : P.Z0;
    const unsigned short* WQ = e ? P.Q1 : P.Q0;
    float* oa                = e ? P.oa1 : P.oa0;
    float* ob                = e ? P.ob1 : P.ob0;
    int lb = blockIdx.x - (e ? P.n0 : 0);
#pragma unroll
    for (int i = 0; i < 8; ++i)
        gll16(Wt + i * 2048 + t * 8, (char*)WL + i * 4096 + t * 16);
    size_t row0 = (size_t)lb * 128 + w * 32;
    f32x4 acc[2][8]; f32x4 accl[2];
#pragma unroll
    for (int r = 0; r < 2; ++r) {
        accl[r] = (f32x4){0.f, 0.f, 0.f, 0.f};
#pragma unroll
        for (int n = 0; n < 8; ++n) acc[r][n] = (f32x4){0.f, 0.f, 0.f, 0.f};
    }
    bool haslog = (WQ != nullptr);
    bf16x8 qf[4];
    if (haslog) {
#pragma unroll
        for (int ks = 0; ks < 4; ++ks) qf[ks] = *(const bf16x8*)(WQ + (ks * 64 + l) * 8);
    }
    __syncthreads();
#pragma unroll
    for (int ks = 0; ks < 4; ++ks) {
        int k0 = ks * 32 + lq * 8;
        bf16x8 a0 = *(const bf16x8*)(A + (row0 + l15) * 128 + k0);
        bf16x8 a1 = *(const bf16x8*)(A + (row0 + 16 + l15) * 128 + k0);
#pragma unroll
        for (int n = 0; n < 8; ++n) {
            bf16x8 bw = *(const bf16x8*)(WL + ((n * 4 + ks) * 64 + l) * 8);
            acc[0][n] = __builtin_amdgcn_mfma_f32_16x16x32_bf16(a0, bw, acc[0][n], 0, 0, 0);
            acc[1][n] = __builtin_amdgcn_mfma_f32_16x16x32_bf16(a1, bw, acc[1][n], 0, 0, 0);
        }
        if (haslog) {
            accl[0] = __builtin_amdgcn_mfma_f32_16x16x32_bf16(a0, qf[ks], accl[0], 0, 0, 0);
            accl[1] = __builtin_amdgcn_mfma_f32_16x16x32_bf16(a1, qf[ks], accl[1], 0, 0, 0);
        }
    }
    bool hasb = (bias != nullptr);
#pragma unroll
    for (int n = 0; n < 4; ++n) {
        float bl = hasb ? bias[n * 16 + l15] : 0.f;
        float bh = hasb ? bias[n * 16 + l15 + 64] : 0.f;
#pragma unroll
        for (int r = 0; r < 2; ++r)
#pragma unroll
            for (int reg = 0; reg < 4; ++reg) {
                size_t row = row0 + r * 16 + lq * 4 + reg;
                Zp[row * 64 + n * 16 + l15] = pkfp8(acc[r][n][reg] + bl, acc[r][n + 4][reg] + bh);
            }
    }
    if (haslog) {
#pragma unroll
        for (int r = 0; r < 2; ++r)
#pragma unroll
            for (int reg = 0; reg < 4; ++reg) {
                size_t row = row0 + r * 16 + lq * 4 + reg;
                if (oa && l15 < 4) oa[row * 4 + l15] = accl[r][reg];
                else if (ob && l15 >= 4 && l15 < 8) ob[row * 4 + (l15 - 4)] = accl[r][reg];
            }
    }
}

// ---------------------------------------------------------------------------
// CSR build, two-level bucket partition (unchanged).
// ---------------------------------------------------------------------------
struct P8 { const int* a[8]; };
#define CHUNK 2048

__global__ __launch_bounds__(256) void bucket_count(P8 dsts, unsigned* __restrict__ bcnt)
{
    __shared__ unsigned lh[256];
    int blk = blockIdx.x, rel = blk >> 7, cb = blk & 127, t = threadIdx.x;
    lh[t] = 0; __syncthreads();
    const int* dp = dsts.a[rel] + cb * CHUNK;
#pragma unroll
    for (int it = 0; it < 8; ++it) atomicAdd(&lh[dp[it * 256 + t] >> 8], 1u);
    __syncthreads();
    atomicAdd(&bcnt[rel * 256 + t], lh[t]);
}

__global__ __launch_bounds__(256) void scanB(const unsigned* __restrict__ bcnt,
                                             unsigned* __restrict__ bbase,
                                             unsigned* __restrict__ bcur)
{
    __shared__ unsigned ts[256];
    int t = threadIdx.x;
    unsigned v[8]; unsigned run = 0;
#pragma unroll
    for (int i = 0; i < 8; ++i) { v[i] = bcnt[t * 8 + i]; run += v[i]; }
    ts[t] = run; __syncthreads();
    for (int off = 1; off < 256; off <<= 1) {
        unsigned x = (t >= off) ? ts[t - off] : 0u;
        __syncthreads(); ts[t] += x; __syncthreads();
    }
    unsigned base = ts[t] - run;
#pragma unroll
    for (int i = 0; i < 8; ++i) { bbase[t * 8 + i] = base; bcur[t * 8 + i] = base; base += v[i]; }
    if (t == 255) bbase[2048] = base;
}

__global__ __launch_bounds__(256) void bucket_fill(P8 dsts, P8 srcs,
                                                   unsigned* __restrict__ bcur,
                                                   unsigned long long* __restrict__ bb)
{
    __shared__ unsigned lh[256], lbase[256], lcur[256];
    int blk = blockIdx.x, rel = blk >> 7, cb = blk & 127, t = threadIdx.x;
    lh[t] = 0; lcur[t] = 0; __syncthreads();
    const int* dp = dsts.a[rel] + cb * CHUNK;
    const int* sp = srcs.a[rel] + cb * CHUNK;
    int dv[8];
#pragma unroll
    for (int it = 0; it < 8; ++it) { dv[it] = dp[it * 256 + t]; atomicAdd(&lh[dv[it] >> 8], 1u); }
    __syncthreads();
    lbase[t] = atomicAdd(&bcur[rel * 256 + t], lh[t]);
    __syncthreads();
#pragma unroll
    for (int it = 0; it < 8; ++it) {
        unsigned e = (unsigned)(cb * CHUNK + it * 256 + t);
        unsigned d = (unsigned)dv[it];
        unsigned s = (unsigned)sp[it * 256 + t];
        unsigned pos = atomicAdd(&lcur[d >> 8], 1u);
        bb[lbase[d >> 8] + pos] =
            (unsigned long long)s | ((unsigned long long)d << 16) | ((unsigned long long)e << 32);
    }
}

// fused bucket_hist + scan1
__global__ __launch_bounds__(256) void hist_scan(const unsigned long long* __restrict__ bb,
                                                 const unsigned* __restrict__ bbase,
                                                 unsigned* __restrict__ rowptr,
                                                 unsigned* __restrict__ blksum)
{
    __shared__ unsigned lh[256], s[256];
    int blk = blockIdx.x, rel = blk >> 8, b = blk & 255, t = threadIdx.x;
    lh[t] = 0; __syncthreads();
    unsigned s0 = bbase[blk], s1 = bbase[blk + 1];
    for (unsigned i = s0 + t; i < s1; i += 256)
        atomicAdd(&lh[(unsigned)(bb[i] >> 16) & 255u], 1u);
    __syncthreads();
    unsigned v = lh[t];
    s[t] = v; __syncthreads();
    for (int off = 1; off < 256; off <<= 1) {
        unsigned x = (t >= off) ? s[t - off] : 0u;
        __syncthreads();
        s[t] += x;
        __syncthreads();
    }
    rowptr[(size_t)rel * RPS + b * 256 + t] = s[t] - v;
    if (t == 255) blksum[rel * 256 + b] = s[255];
}

__global__ __launch_bounds__(256) void scan2(unsigned* __restrict__ blksum,
                                             unsigned* __restrict__ rowptr)
{
    __shared__ unsigned s[256];
    int rel = blockIdx.x, t = threadIdx.x;
    unsigned v = blksum[rel * 256 + t];
    s[t] = v; __syncthreads();
    for (int off = 1; off < 256; off <<= 1) {
        unsigned x = (t >= off) ? s[t - off] : 0u;
        __syncthreads();
        s[t] += x;
        __syncthreads();
    }
    blksum[rel * 256 + t] = s[t] - v;
    if (t == 255) rowptr[(size_t)rel * RPS + 65536] = s[255];
}

// fused scan3 + bucket_place
__global__ __launch_bounds__(256) void scan3_place(const unsigned long long* __restrict__ bb,
                                                   const unsigned* __restrict__ bbase,
                                                   unsigned* __restrict__ rowptr,
                                                   const unsigned* __restrict__ blksum,
                                                   int2* __restrict__ epair)
{
    __shared__ unsigned lrp[256], lcur[256];
    int blk = blockIdx.x, rel = blk >> 8, b = blk & 255, t = threadIdx.x;
    unsigned fin = rowptr[(size_t)rel * RPS + b * 256 + t] + blksum[rel * 256 + b];
    rowptr[(size_t)rel * RPS + b * 256 + t] = fin;
    lrp[t] = fin; lcur[t] = 0; __syncthreads();
    unsigned s0 = bbase[blk], s1 = bbase[blk + 1];
    for (unsigned i = s0 + t; i < s1; i += 256) {
        unsigned long long pk = bb[i];
        unsigned s = (unsigned)pk & 0xffffu;
        unsigned d8 = (unsigned)(pk >> 16) & 255u;
        unsigned e = (unsigned)(pk >> 32);
        unsigned pos = atomicAdd(&lcur[d8], 1u);
        epair[(size_t)rel * E2 + lrp[d8] + pos] = make_int2((int)s, (int)e);
    }
}

// ---------------------------------------------------------------------------
// Per-edge (ef @ M) EDGE-ORDERED, packed bf16x4.
// ---------------------------------------------------------------------------
__global__ __launch_bounds__(256) void ef4e_kernel(
    const float* __restrict__ efm, const float* __restrict__ efs,
    const float* __restrict__ efb, const float* __restrict__ eft,
    const float* __restrict__ we, const float* __restrict__ ae,
    uint2* __restrict__ ef4e)
{
    __shared__ float M[8][4];
    int b = blockIdx.x, t = threadIdx.x;
    int er = b >> 10;
    const float* ef = (er == 0) ? efm : (er == 1) ? efs : (er == 2) ? efb : eft;
    if (t < 32) {
        int f = t >> 2, hh = t & 3;
        float s = 0.f;
#pragma unroll 8
        for (int d = 0; d < 32; ++d) s += we[er * 1024 + f * 128 + hh * 32 + d] * ae[er * 128 + hh * 32 + d];
        M[f][hh] = s;
    }
    __syncthreads();
    int e = (b & 1023) * 256 + t;
    float4 a = *(const float4*)(ef + (size_t)e * 8);
    float4 c = *(const float4*)(ef + (size_t)e * 8 + 4);
    float o0 = a.x*M[0][0]+a.y*M[1][0]+a.z*M[2][0]+a.w*M[3][0]+c.x*M[4][0]+c.y*M[5][0]+c.z*M[6][0]+c.w*M[7][0];
    float o1 = a.x*M[0][1]+a.y*M[1][1]+a.z*M[2][1]+a.w*M[3][1]+c.x*M[4][1]+c.y*M[5][1]+c.z*M[6][1]+c.w*M[7][1];
    float o2 = a.x*M[0][2]+a.y*M[1][2]+a.z*M[2][2]+a.w*M[3][2]+c.x*M[4][2]+c.y*M[5][2]+c.z*M[6][2]+c.w*M[7][2];
    float o3 = a.x*M[0][3]+a.y*M[1][3]+a.z*M[2][3]+a.w*M[3][3]+c.x*M[4][3]+c.y*M[5][3]+c.z*M[6][3]+c.w*M[7][3];
    uint2 o; o.x = pk2(o0, o1); o.y = pk2(o2, o3);
    ef4e[(size_t)er * E2 + e] = o;
}

// ---------------------------------------------------------------------------
// Quarter-wave segment helpers (unchanged).
// ---------------------------------------------------------------------------
__device__ __forceinline__ void phys_seg16(
    const unsigned* __restrict__ rowptr, const int2* __restrict__ epair,
    const unsigned short* __restrict__ Zp, int d, unsigned m,
    float rlo[4], float rhi[4])
{
    unsigned s0 = rowptr[d], s1 = rowptr[d + 1];
    float alo[4] = {0, 0, 0, 0}, ahi[4] = {0, 0, 0, 0};
    for (unsigned base = s0; base < s1; base += 4) {
        unsigned nb = s1 - base; if (nb > 4) nb = 4;
        int2 ep[4];
#pragma unroll
        for (int i = 0; i < 4; ++i)
            ep[i] = epair[base + ((unsigned)i < nb ? (unsigned)i : nb - 1)];
        uint2 zv[4];
#pragma unroll
        for (int i = 0; i < 4; ++i)
            zv[i] = ((const uint2*)(Zp + ((unsigned)ep[i].x << 6)))[m];
#pragma unroll
        for (int i = 0; i < 4; ++i) {
            if ((unsigned)i >= nb) break;
            f32x2 a0 = __builtin_amdgcn_cvt_pk_f32_fp8(zv[i].x, false);
            f32x2 a1 = __builtin_amdgcn_cvt_pk_f32_fp8(zv[i].x, true);
            f32x2 a2 = __builtin_amdgcn_cvt_pk_f32_fp8(zv[i].y, false);
            f32x2 a3 = __builtin_amdgcn_cvt_pk_f32_fp8(zv[i].y, true);
            alo[0] += a0.x; ahi[0] += a0.y;
            alo[1] += a1.x; ahi[1] += a1.y;
            alo[2] += a2.x; ahi[2] += a2.y;
            alo[3] += a3.x; ahi[3] += a3.y;
        }
    }
    int cnt = (int)(s1 - s0);
    float inv = 1.0f / (float)(cnt > 0 ? cnt : 1);
#pragma unroll
    for (int j = 0; j < 4; ++j) { rlo[j] += alo[j] * inv; rhi[j] += ahi[j] * inv; }
}

template <bool HAS_EF>
__device__ __forceinline__ void gat_seg16(
    const unsigned* __restrict__ rowptr, const int2* __restrict__ epair,
    const unsigned short* __restrict__ Zp, const float* __restrict__ ls,
    const float* __restrict__ ld, const uint2* __restrict__ ef4e,
    int d, unsigned m, int hs, float rlo[4], float rhi[4])
{
    float4 ldv4 = *(const float4*)(ld + ((unsigned)d << 2));
    float ldlo = hs ? ldv4.y : ldv4.x;
    float ldhi = hs ? ldv4.w : ldv4.z;
    unsigned s0 = rowptr[d], s1 = rowptr[d + 1];
    float nlo[4] = {0, 0, 0, 0}, nhi[4] = {0, 0, 0, 0};
    float dlo = 0.f, dhi = 0.f;
    for (unsigned base = s0; base < s1; base += 4) {
        unsigned nb = s1 - base; if (nb > 4) nb = 4;
        int2 ep[4];
#pragma unroll
        for (int i = 0; i < 4; ++i)
            ep[i] = epair[base + ((unsigned)i < nb ? (unsigned)i : nb - 1)];
        uint2 zv[4]; float4 lsv[4]; uint2 e4[4];
#pragma unroll
        for (int i = 0; i < 4; ++i) {
            zv[i] = ((const uint2*)(Zp + ((unsigned)ep[i].x << 6)))[m];
            lsv[i] = *(const float4*)(ls + ((unsigned)ep[i].x << 2));
            if (HAS_EF) e4[i] = ef4e[(unsigned)ep[i].y];
        }
#pragma unroll
        for (int i = 0; i < 4; ++i) {
            if ((unsigned)i >= nb) break;
            float glo = (hs ? lsv[i].y : lsv[i].x) + ldlo;
            float ghi = (hs ? lsv[i].w : lsv[i].z) + ldhi;
            if (HAS_EF) {
                glo += bf2f(hs ? (e4[i].x >> 16) : (e4[i].x & 0xffffu));
                ghi += bf2f(hs ? (e4[i].y >> 16) : (e4[i].y & 0xffffu));
            }
            glo = glo > 0.f ? glo : 0.2f * glo;
            ghi = ghi > 0.f ? ghi : 0.2f * ghi;
            float xlo = __expf(glo), xhi = __expf(ghi);
            f32x2 a0 = __builtin_amdgcn_cvt_pk_f32_fp8(zv[i].x, false);
            f32x2 a1 = __builtin_amdgcn_cvt_pk_f32_fp8(zv[i].x, true);
            f32x2 a2 = __builtin_amdgcn_cvt_pk_f32_fp8(zv[i].y, false);
            f32x2 a3 = __builtin_amdgcn_cvt_pk_f32_fp8(zv[i].y, true);
            nlo[0] += xlo * a0.x; nhi[0] += xhi * a0.y;
            nlo[1] += xlo * a1.x; nhi[1] += xhi * a1.y;
            nlo[2] += xlo * a2.x; nhi[2] += xhi * a2.y;
            nlo[3] += xlo * a3.x; nhi[3] += xhi * a3.y;
            dlo += xlo; dhi += xhi;
        }
    }
    float ilo = 1.0f / fmaxf(dlo, 1e-9f), ihi = 1.0f / fmaxf(dhi, 1e-9f);
#pragma unroll
    for (int j = 0; j < 4; ++j) { rlo[j] += nlo[j] * ilo; rhi[j] += nhi[j] * ihi; }
}

__device__ __forceinline__ void acc_write16(
    unsigned* __restrict__ accp, int d, unsigned m, bool acc,
    float rlo[4], float rhi[4])
{
    uint4* ap = (uint4*)(accp + ((unsigned)d << 6)) + m;
    if (acc) {
        uint4 o = *ap;
        rlo[0] += bf2f(o.x & 0xffffu); rhi[0] += bf2f(o.x >> 16);
        rlo[1] += bf2f(o.y & 0xffffu); rhi[1] += bf2f(o.y >> 16);
        rlo[2] += bf2f(o.z & 0xffffu); rhi[2] += bf2f(o.z >> 16);
        rlo[3] += bf2f(o.w & 0xffffu); rhi[3] += bf2f(o.w >> 16);
    }
    uint4 nv;
    nv.x = pk2(rlo[0], rhi[0]); nv.y = pk2(rlo[1], rhi[1]);
    nv.z = pk2(rlo[2], rhi[2]); nv.w = pk2(rlo[3], rhi[3]);
    *ap = nv;
}

template <bool ACC>
__global__ __launch_bounds__(256) void phys_gather(
    const unsigned* __restrict__ rowptr, const int2* __restrict__ epair,
    const unsigned short* __restrict__ Zp, unsigned* __restrict__ accp, int n_nodes)
{
    int t = threadIdx.x;
    unsigned m = (unsigned)(t & 15);
    int d = blockIdx.x * 16 + (t >> 4);
    if (d >= n_nodes) return;
    float rlo[4] = {0, 0, 0, 0}, rhi[4] = {0, 0, 0, 0};
    phys_seg16(rowptr, epair, Zp, d, m, rlo, rhi);
    acc_write16(accp, d, m, ACC, rlo, rhi);
}

template <bool ACC>
__global__ __launch_bounds__(256) void dual_phys(
    const unsigned* __restrict__ rpA, const int2* __restrict__ epA,
    const unsigned short* __restrict__ ZA,
    const unsigned* __restrict__ rpB, const int2* __restrict__ epB,
    const unsigned short* __restrict__ ZB,
    unsigned* __restrict__ accp, int n_nodes)
{
    int t = threadIdx.x;
    unsigned m = (unsigned)(t & 15);
    int d = blockIdx.x * 16 + (t >> 4);
    if (d >= n_nodes) return;
    float rlo[4] = {0, 0, 0, 0}, rhi[4] = {0, 0, 0, 0};
    phys_seg16(rpA, epA, ZA, d, m, rlo, rhi);
    phys_seg16(rpB, epB, ZB, d, m, rlo, rhi);
    acc_write16(accp, d, m, ACC, rlo, rhi);
}

template <bool EF, bool ACC>
__global__ __launch_bounds__(256) void gat_gather(
    const unsigned* __restrict__ rowptr, const int2* __restrict__ epair,
    const unsigned short* __restrict__ Zp, const float* __restrict__ ls,
    const float* __restrict__ ld, const uint2* __restrict__ ef4e,
    unsigned* __restrict__ accp, int n_nodes)
{
    int t = threadIdx.x;
    unsigned m = (unsigned)(t & 15);
    int d = blockIdx.x * 16 + (t >> 4);
    if (d >= n_nodes) return;
    int hs = (int)(m >> 3);
    float rlo[4] = {0, 0, 0, 0}, rhi[4] = {0, 0, 0, 0};
    gat_seg16<EF>(rowptr, epair, Zp, ls, ld, ef4e, d, m, hs, rlo, rhi);
    acc_write16(accp, d, m, ACC, rlo, rhi);
}

template <bool EFA, bool EFB, bool ACC>
__global__ __launch_bounds__(256) void dual_gat(
    const unsigned* __restrict__ rpA, const int2* __restrict__ epA,
    const unsigned short* __restrict__ ZA, const float* __restrict__ lsA,
    const float* __restrict__ ldA, const uint2* __restrict__ efA,
    const unsigned* __restrict__ rpB, const int2* __restrict__ epB,
    const unsigned short* __restrict__ ZB, const float* __restrict__ lsB,
    const float* __restrict__ ldB, const uint2* __restrict__ efB,
    unsigned* __restrict__ accp, int n_nodes)
{
    int t = threadIdx.x;
    unsigned m = (unsigned)(t & 15);
    int d = blockIdx.x * 16 + (t >> 4);
    if (d >= n_nodes) return;
    int hs = (int)(m >> 3);
    float rlo[4] = {0, 0, 0, 0}, rhi[4] = {0, 0, 0, 0};
    gat_seg16<EFA>(rpA, epA, ZA, lsA, ldA, efA, d, m, hs, rlo, rhi);
    gat_seg16<EFB>(rpB, epB, ZB, lsB, ldB, efB, d, m, hs, rlo, rhi);
    acc_write16(accp, d, m, ACC, rlo, rhi);
}

// ---------------------------------------------------------------------------
// Merged FFN v3: FP8 weights + fp8 MFMA.  32-col chunks; WB 2x8KB + HW 8KB =
// 24 KB LDS -> 6 blocks/CU.  A-operands packed to fp8 in-register.
// ---------------------------------------------------------------------------
struct FP {
    const float* h[3]; const unsigned* ac[3];
    const float* g[3]; const float* b[3];
    const unsigned char* w1[3]; const float* bb1[3];
    const unsigned char* w2[3]; const float* bb2[3];
    float* out[3]; float invC[3];
    int n1, n2;
};

__global__ __launch_bounds__(256, 4) void ffn_all(FP P)
{
    __shared__ unsigned char WB[2][8192];   // 2 x (4KB w1-chunk + 4KB w2-chunk)
    __shared__ float HW[4][512];            // per-wave 16x32 f32, swizzled
    int blk = blockIdx.x;
    int ti = (blk >= P.n2) ? 2 : (blk >= P.n1) ? 1 : 0;
    int lb = blk - (ti == 2 ? P.n2 : ti == 1 ? P.n1 : 0);
    const float* h = P.h[ti];
    const unsigned* accp = P.ac[ti];
    const float* g = P.g[ti];
    const float* b = P.b[ti];
    const unsigned char* w1p = P.w1[ti];
    const float* b1 = P.bb1[ti];
    const unsigned char* w2p = P.w2[ti];
    const float* b2 = P.bb2[ti];
    float* out = P.out[ti];
    float invC = P.invC[ti];

    int t = threadIdx.x, w = t >> 6, l = t & 63;
    int l15 = l & 15, lq = l >> 4;
    size_t rw = (size_t)lb * 128 + w * 32;
    float* myHW = HW[w];

    // ---- LN + A-frag pack (fp8) for both 16-row frags
    long afq[2][4];
#pragma unroll
    for (int rf = 0; rf < 2; ++rf) {
        size_t myrow = rw + rf * 16 + l15;
        const unsigned* ap = accp + myrow * 64 + lq * 8;
        uint4 ua0 = *(const uint4*)(ap);
        uint4 ua1 = *(const uint4*)(ap + 4);
        uint4 ub0 = *(const uint4*)(ap + 32);
        uint4 ub1 = *(const uint4*)(ap + 36);
        const float* hp = h + myrow * 128 + lq * 8;
        float4 hf[4][2];
        hf[0][0] = *(const float4*)(hp);      hf[0][1] = *(const float4*)(hp + 4);
        hf[1][0] = *(const float4*)(hp + 32); hf[1][1] = *(const float4*)(hp + 36);
        hf[2][0] = *(const float4*)(hp + 64); hf[2][1] = *(const float4*)(hp + 68);
        hf[3][0] = *(const float4*)(hp + 96); hf[3][1] = *(const float4*)(hp + 100);
        unsigned ua[8] = {ua0.x, ua0.y, ua0.z, ua0.w, ua1.x, ua1.y, ua1.z, ua1.w};
        unsigned ub[8] = {ub0.x, ub0.y, ub0.z, ub0.w, ub1.x, ub1.y, ub1.z, ub1.w};
        float hv[4][8];
#pragma unroll
        for (int j = 0; j < 8; ++j) {
            hv[0][j] = ((const float*)hf[0])[j] + bf2f(ua[j] & 0xffffu) * invC;
            hv[1][j] = ((const float*)hf[1])[j] + bf2f(ub[j] & 0xffffu) * invC;
            hv[2][j] = ((const float*)hf[2])[j] + bf2f(ua[j] >> 16) * invC;
            hv[3][j] = ((const float*)hf[3])[j] + bf2f(ub[j] >> 16) * invC;
        }
        float s = 0.f;
#pragma unroll
        for (int ks = 0; ks < 4; ++ks)
#pragma unroll
            for (int j = 0; j < 8; ++j) s += hv[ks][j];
        s += __shfl_xor(s, 16); s += __shfl_xor(s, 32);
        float mean = s * (1.0f / 128.0f);
        float v = 0.f;
#pragma unroll
        for (int ks = 0; ks < 4; ++ks)
#pragma unroll
            for (int j = 0; j < 8; ++j) { float dd = hv[ks][j] - mean; v += dd * dd; }
        v += __shfl_xor(v, 16); v += __shfl_xor(v, 32);
        float rstd = rsqrtf(v * (1.0f / 128.0f) + 1e-5f);
#pragma unroll
        for (int ks = 0; ks < 4; ++ks) {
            int col0 = ks * 32 + lq * 8;
            float y[8];
#pragma unroll
            for (int j = 0; j < 8; ++j)
                y[j] = g[col0 + j] * (hv[ks][j] - mean) * rstd + b[col0 + j];
            afq[rf][ks] = pk8f8(y);
        }
    }

    // ---- stage chunk 0 (8 KB: 4 KB w1 + 4 KB w2)
    gll16(w1p + t * 16, (char*)WB[0] + t * 16);
    gll16(w2p + t * 16, (char*)WB[0] + 4096 + t * 16);
    f32x4 facc[2][8];
#pragma unroll
    for (int rf = 0; rf < 2; ++rf)
#pragma unroll
        for (int n = 0; n < 8; ++n) facc[rf][n] = (f32x4){0.f, 0.f, 0.f, 0.f};
    __syncthreads();

    int buf = 0;
    int swR = (l15 & 7) << 2;
    for (int ch = 0; ch < 16; ++ch) {
        if (ch < 15) {
            gll16(w1p + (ch + 1) * 4096 + t * 16, (char*)WB[buf ^ 1] + t * 16);
            gll16(w2p + (ch + 1) * 4096 + t * 16, (char*)WB[buf ^ 1] + 4096 + t * 16);
        }
        // gemm1: 32 rows x 32 hidden cols (fp8 x fp8)
        f32x4 acc1[2][2];
#pragma unroll
        for (int rf = 0; rf < 2; ++rf)
#pragma unroll
            for (int n = 0; n < 2; ++n) acc1[rf][n] = (f32x4){0.f, 0.f, 0.f, 0.f};
#pragma unroll
        for (int ks = 0; ks < 4; ++ks)
#pragma unroll
            for (int nfL = 0; nfL < 2; ++nfL) {
                long bw = *(const long*)(WB[buf] + ((nfL * 4 + ks) * 64 + l) * 8);
                acc1[0][nfL] = __builtin_amdgcn_mfma_f32_16x16x32_fp8_fp8(afq[0][ks], bw, acc1[0][nfL], 0, 0, 0);
                acc1[1][nfL] = __builtin_amdgcn_mfma_f32_16x16x32_fp8_fp8(afq[1][ks], bw, acc1[1][nfL], 0, 0, 0);
            }
        // GELU + transpose + gemm2, per row-frag through the 2 KB wave LDS
#pragma unroll
        for (int rf = 0; rf < 2; ++rf) {
#pragma unroll
            for (int nfL = 0; nfL < 2; ++nfL) {
                float bv = b1[ch * 32 + nfL * 16 + l15];
#pragma unroll
                for (int reg = 0; reg < 4; ++reg) {
                    int row = lq * 4 + reg;
                    float x = acc1[rf][nfL][reg] + bv;
                    myHW[row * 32 + ((nfL * 16 + l15) ^ ((row & 7) << 2))] = gelu(x);
                }
            }
            {
                int cb = lq * 8;
                f32x4 x0 = *(const f32x4*)(myHW + l15 * 32 + (cb ^ swR));
                f32x4 x1 = *(const f32x4*)(myHW + l15 * 32 + ((cb + 4) ^ swR));
                long a2 = pk8f8v(x0, x1);
#pragma unroll
                for (int nf2 = 0; nf2 < 8; ++nf2) {
                    long bw = *(const long*)(WB[buf] + 4096 + (nf2 * 64 + l) * 8);
                    facc[rf][nf2] = __builtin_amdgcn_mfma_f32_16x16x32_fp8_fp8(a2, bw, facc[rf][nf2], 0, 0, 0);
                }
            }
        }
        __syncthreads();
        buf ^= 1;
    }
    // ---- epilogue: out = h + acc*invC + ffn + b2 (D layout)
#pragma unroll
    for (int rf = 0; rf < 2; ++rf)
#pragma unroll
        for (int nf = 0; nf < 8; ++nf) {
            int col = nf * 16 + l15;
            float bv = b2[col];
            int ci = col & 63;
            bool hi = col >= 64;
#pragma unroll
            for (int reg = 0; reg < 4; ++reg) {
                size_t row = rw + rf * 16 + lq * 4 + reg;
                unsigned pv = accp[row * 64 + ci];
                float av = bf2f(hi ? (pv >> 16) : (pv & 0xffffu));
                out[row * 128 + col] = h[row * 128 + col] + av * invC + facc[rf][nf][reg] + bv;
            }
        }
}

// ---------------------------------------------------------------------------
extern "C" void kernel_launch(void* const* d_in, const int* in_sizes, int n_in,
                              void* d_out, int out_size, void* d_ws, size_t ws_size,
                              hipStream_t stream)
{
    const float* h_enz  = (const float*)d_in[0];
    const float* h_met  = (const float*)d_in[1];
    const float* h_rxn  = (const float*)d_in[2];
    const float* ef_mod = (const float*)d_in[3];
    const float* ef_sig = (const float*)d_in[4];
    const float* ef_brg = (const float*)d_in[5];
    const float* ef_trn = (const float*)d_in[6];
    const float* ln1_g  = (const float*)d_in[7];
    const float* ln1_b  = (const float*)d_in[8];
    const float* ln2_g  = (const float*)d_in[9];
    const float* ln2_b  = (const float*)d_in[10];
    const float* wp     = (const float*)d_in[11];
    const float* bp     = (const float*)d_in[12];
    const float* wl     = (const float*)d_in[13];
    const float* a_src  = (const float*)d_in[14];
    const float* a_dst  = (const float*)d_in[15];
    const float* we     = (const float*)d_in[16];
    const float* a_edge = (const float*)d_in[17];
    const float* w1     = (const float*)d_in[18];
    const float* b1     = (const float*)d_in[19];
    const float* w2     = (const float*)d_in[20];
    const float* b2     = (const float*)d_in[21];
    const int* src_sub  = (const int*)d_in[22];
    const int* dst_sub  = (const int*)d_in[23];
    const int* src_prod = (const int*)d_in[24];
    const int* dst_prod = (const int*)d_in[25];
    const int* src_cat  = (const int*)d_in[26];
    const int* dst_cat  = (const int*)d_in[27];
    const int* src_mod  = (const int*)d_in[28];
    const int* dst_mod  = (const int*)d_in[29];
    const int* src_reg  = (const int*)d_in[30];
    const int* dst_reg  = (const int*)d_in[31];
    const int* src_sig  = (const int*)d_in[32];
    const int* dst_sig  = (const int*)d_in[33];
    const int* src_brg  = (const int*)d_in[34];
    const int* dst_brg  = (const int*)d_in[35];
    const int* src_trn  = (const int*)d_in[36];
    const int* dst_trn  = (const int*)d_in[37];
    float* out = (float*)d_out;

    // workspace (~90 MB; proven budget >= 116.6 MB)
    char* p = (char*)d_ws;
    unsigned* accp = (unsigned*)p;            p += (size_t)NTOT * 64 * 4;
    unsigned short* ZpA = (unsigned short*)p; p += (size_t)NM * 64 * 2;
    unsigned long long* bukbuf = (unsigned long long*)p;                      // alias:
    unsigned short* ZpB = (unsigned short*)p; p += (size_t)8 * E2 * 8;
    int2* epair = (int2*)p;                   p += (size_t)8 * E2 * 8;
    uint2* ef4e = (uint2*)p;                  p += (size_t)4 * E2 * 8;
    float* ls3 = (float*)p;                   p += (size_t)NE * 4 * 4;
    float* ld3 = (float*)p;                   p += (size_t)NR * 4 * 4;
    float* ls4 = (float*)p;                   p += (size_t)NE * 4 * 4;
    float* ld4 = (float*)p;                   p += (size_t)NE * 4 * 4;
    float* ls5 = (float*)p;                   p += (size_t)NM * 4 * 4;
    float* ld5 = (float*)p;                   p += (size_t)NE * 4 * 4;
    float* ls6 = (float*)p;                   p += (size_t)NM * 4 * 4;
    float* ld6 = (float*)p;                   p += (size_t)NM * 4 * 4;
    float* ls7 = (float*)p;                   p += (size_t)NM * 4 * 4;
    float* ld7 = (float*)p;                   p += (size_t)NM * 4 * 4;
    unsigned short* wbf = (unsigned short*)p; p += (size_t)131072 * 2;   // square mats bf16
    unsigned char* wbf8 = (unsigned char*)p;  p += (size_t)393216;       // w1/w2 fp8
    unsigned short* wq  = (unsigned short*)p; p += (size_t)7 * 2048 * 2;
    unsigned* rowptr = (unsigned*)p;          p += (size_t)8 * RPS * 4;
    unsigned* bcnt = (unsigned*)p;            p += 2048 * 4;
    unsigned* bbase = (unsigned*)p;           p += 2049 * 4;
    unsigned* bcur = (unsigned*)p;            p += 2048 * 4;
    unsigned* blksum = (unsigned*)p;          p += (size_t)8 * 256 * 4;
    if (ws_size < (size_t)(p - (char*)d_ws)) return;

    unsigned* nrm32 = (unsigned*)d_out;
    const unsigned short* nbf_enz = (const unsigned short*)d_out;
    const unsigned short* nbf_met = nbf_enz + (size_t)NE * 128;
    const unsigned short* nbf_rxn = nbf_enz + (size_t)(NE + NM) * 128;
    unsigned* acc_enz = accp;
    unsigned* acc_met = accp + (size_t)NE * 64;
    unsigned* acc_rxn = accp + (size_t)(NE + NM) * 64;

    P8 dsts, srcs;
    dsts.a[0] = dst_sub;  srcs.a[0] = src_sub;
    dsts.a[1] = dst_prod; srcs.a[1] = src_prod;
    dsts.a[2] = dst_cat;  srcs.a[2] = src_cat;
    dsts.a[3] = dst_mod;  srcs.a[3] = src_mod;
    dsts.a[4] = dst_reg;  srcs.a[4] = src_reg;
    dsts.a[5] = dst_sig;  srcs.a[5] = src_sig;
    dsts.a[6] = dst_brg;  srcs.a[6] = src_brg;
    dsts.a[7] = dst_trn;  srcs.a[7] = src_trn;

    // ---- prep: LN1 + weights (bf16 square + fp8 ffn) + WQ, bucketed CSR, ef.M
    hipMemsetAsync(bcnt, 0, 2048 * 4, stream);
    prep_all<<<LN1_BLK + SQ_BLK + F8_BLK + 28, 256, 0, stream>>>(
        h_enz, h_met, h_rxn, ln1_g, ln1_b, nrm32,
        wp, wl, w1, w2, wbf, wbf8, a_src, a_dst, wq);
    bucket_count<<<1024, 256, 0, stream>>>(dsts, bcnt);
    scanB<<<1, 256, 0, stream>>>(bcnt, bbase, bcur);
    bucket_fill<<<1024, 256, 0, stream>>>(dsts, srcs, bcur, bukbuf);
    hist_scan<<<2048, 256, 0, stream>>>(bukbuf, bbase, rowptr, blksum);
    scan2<<<8, 256, 0, stream>>>(blksum, rowptr);
    scan3_place<<<2048, 256, 0, stream>>>(bukbuf, bbase, rowptr, blksum, epair);
    ef4e_kernel<<<4096, 256, 0, stream>>>(ef_mod, ef_sig, ef_brg, ef_trn, we, a_edge, ef4e);

#define RP(r) (rowptr + (size_t)(r) * RPS)
#define EP(r) (epair + (size_t)(r) * E2)
#define WQS(s) (wq + (size_t)(s) * 2048)
#define EF4(er) (ef4e + (size_t)(er) * E2)

    // ---- pair A: rel0 (met->rxn phys, ZpA) + rel2 (enz->rxn phys + ld5, ZpB)
    {
        G2 P = {nbf_met, wbf + 0 * 16384, bp + 0,   ZpA, nullptr, nullptr, nullptr,
                nbf_enz, wbf + 2 * 16384, bp + 256, ZpB, WQS(1),  ld5,     nullptr,
                NM / 128};
        gemm_pair<<<NM / 128 + NE / 128, 256, 0, stream>>>(P);
    }
    dual_phys<false><<<NR / 16, 256, 0, stream>>>(RP(0), EP(0), ZpA, RP(2), EP(2), ZpB,
                                                  acc_rxn, NR);
    // ---- pair B: rel1 (rxn->met phys + ld3, ZpA) + rel3 (enz->rxn gat ls3, ZpB)
    {
        G2 P = {nbf_rxn, wbf + 1 * 16384, bp + 128, ZpA, WQS(0), ld3, nullptr,
                nbf_enz, wbf + 3 * 16384, nullptr,  ZpB, WQS(2), ls3, nullptr,
                NR / 128};
        gemm_pair<<<NR / 128 + NE / 128, 256, 0, stream>>>(P);
    }
    phys_gather<false><<<NM / 16, 256, 0, stream>>>(RP(1), EP(1), ZpA, acc_met, NM);
    gat_gather<true, true><<<NR / 16, 256, 0, stream>>>(RP(3), EP(3), ZpB, ls3, ld3, EF4(0),
                                                        acc_rxn, NR);
    // ---- pair C: rel4 (enz->enz, ls4/ld4, ZpA) + rel5 (met->enz, ls5, ZpB)
    {
        G2 P = {nbf_enz, wbf + 4 * 16384, nullptr, ZpA, WQS(3), ls4, ld4,
                nbf_met, wbf + 5 * 16384, nullptr, ZpB, WQS(4), ls5, nullptr,
                NE / 128};
        gemm_pair<<<NE / 128 + NM / 128, 256, 0, stream>>>(P);
    }
    dual_gat<false, true, false><<<NE / 16, 256, 0, stream>>>(
        RP(4), EP(4), ZpA, ls4, ld4, nullptr,
        RP(5), EP(5), ZpB, ls5, ld5, EF4(1), acc_enz, NE);
    // ---- pair D: rel6 (met->met, ls6/ld6, ZpA) + rel7 (met->met, ls7/ld7, ZpB)
    {
        G2 P = {nbf_met, wbf + 6 * 16384, nullptr, ZpA, WQS(5), ls6, ld6,
                nbf_met, wbf + 7 * 16384, nullptr, ZpB, WQS(6), ls7, ld7,
                NM / 128};
        gemm_pair<<<NM / 128 + NM / 128, 256, 0, stream>>>(P);
    }
    dual_gat<true, true, true><<<NM / 16, 256, 0, stream>>>(
        RP(6), EP(6), ZpA, ls6, ld6, EF4(2),
        RP(7), EP(7), ZpB, ls7, ld7, EF4(3), acc_met, NM);

    // ---- merged FFN (fp8 weights) over all three node types
    {
        FP P;
        P.h[0] = h_enz; P.h[1] = h_met; P.h[2] = h_rxn;
        P.ac[0] = acc_enz; P.ac[1] = acc_met; P.ac[2] = acc_rxn;
        P.g[0] = ln2_g; P.g[1] = ln2_g + 128; P.g[2] = ln2_g + 256;
        P.b[0] = ln2_b; P.b[1] = ln2_b + 128; P.b[2] = ln2_b + 256;
        P.w1[0] = wbf8; P.w1[1] = wbf8 + 65536; P.w1[2] = wbf8 + 2 * 65536;
        P.bb1[0] = b1; P.bb1[1] = b1 + 512; P.bb1[2] = b1 + 1024;
        P.w2[0] = wbf8 + 196608; P.w2[1] = wbf8 + 196608 + 65536; P.w2[2] = wbf8 + 196608 + 2 * 65536;
        P.bb2[0] = b2; P.bb2[1] = b2 + 128; P.bb2[2] = b2 + 256;
        P.out[0] = out; P.out[1] = out + (size_t)NE * 128; P.out[2] = out + (size_t)(NE + NM) * 128;
        P.invC[0] = 0.5f; P.invC[1] = 1.0f / 3.0f; P.invC[2] = 1.0f / 3.0f;
        P.n1 = NE / 128; P.n2 = NE / 128 + NM / 128;
        ffn_all<<<NE / 128 + NM / 128 + NR / 128, 256, 0, stream>>>(P);
    }
#undef RP
#undef EP
#undef WQS
#undef EF4
}

// Round 12
// 393.296 us; speedup vs baseline: 1.6054x; 1.1157x over previous
//
#include <hip/hip_runtime.h>
#include <cstddef>

#define NE 32768
#define NM 65536
#define NR 49152
#define NTOT 147456
#define E2 262144
#define RPS 65537
#define LN1_BLK 36864
#define SQ_BLK 512
#define F8_BLK 1536

typedef __attribute__((ext_vector_type(8))) short bf16x8;
typedef __attribute__((ext_vector_type(4))) float f32x4;
typedef __attribute__((ext_vector_type(2))) float f32x2;

__device__ __forceinline__ unsigned short f2bf(float x) {
    unsigned u = __float_as_uint(x);
    return (unsigned short)((u + 0x7FFFu + ((u >> 16) & 1u)) >> 16);
}
__device__ __forceinline__ float bf2f(unsigned s) { return __uint_as_float(s << 16); }
__device__ __forceinline__ unsigned pk2(float a, float b) {
    return (unsigned)f2bf(a) | ((unsigned)f2bf(b) << 16);
}
__device__ __forceinline__ bf16x8 pack8(const float* v) {
    union { bf16x8 b; unsigned u[4]; } r;
#pragma unroll
    for (int i = 0; i < 4; ++i) r.u[i] = pk2(v[2 * i], v[2 * i + 1]);
    return r.b;
}
__device__ __forceinline__ unsigned short pkfp8(float a, float b) {
    return (unsigned short)__builtin_amdgcn_cvt_pk_fp8_f32(a, b, 0u, false);
}
__device__ __forceinline__ long pk8f8(const float* y) {
    unsigned long long p0 = pkfp8(y[0], y[1]);
    unsigned long long p1 = pkfp8(y[2], y[3]);
    unsigned long long p2 = pkfp8(y[4], y[5]);
    unsigned long long p3 = pkfp8(y[6], y[7]);
    return (long)(p0 | (p1 << 16) | (p2 << 32) | (p3 << 48));
}
__device__ __forceinline__ long pk8f8v(f32x4 a, f32x4 b) {
    float y[8] = {a[0], a[1], a[2], a[3], b[0], b[1], b[2], b[3]};
    return pk8f8(y);
}
__device__ __forceinline__ void gll16(const void* g, void* l) {
    __builtin_amdgcn_global_load_lds(
        (const __attribute__((address_space(1))) void*)g,
        (__attribute__((address_space(3))) void*)l, 16, 0, 0);
}
// sigmoid-form GELU: x * sigma(1.702 x)
__device__ __forceinline__ float gelu(float x) {
    float e = __expf(-1.702f * x);
    return x * __builtin_amdgcn_rcpf(1.0f + e);
}

// ---------------------------------------------------------------------------
// prep_all = ln1 + square-mat bf16 frag-pack + w1/w2 FP8 frag-pack + wqk.
// ---------------------------------------------------------------------------
__global__ __launch_bounds__(256) void prep_all(
    const float* __restrict__ he, const float* __restrict__ hm, const float* __restrict__ hr,
    const float* __restrict__ g1, const float* __restrict__ b1g, unsigned* __restrict__ nout,
    const float* __restrict__ wp, const float* __restrict__ wl,
    const float* __restrict__ w1, const float* __restrict__ w2,
    unsigned short* __restrict__ wbf, unsigned char* __restrict__ wbf8,
    const float* __restrict__ a_src, const float* __restrict__ a_dst,
    unsigned short* __restrict__ wq)
{
    int blk = blockIdx.x, t = threadIdx.x;
    if (blk < LN1_BLK) {
        int row  = blk * 4 + (t >> 6);
        int lane = t & 63;
        const float* src; int ti; int lr;
        if (row < NE)           { src = he; ti = 0; lr = row; }
        else if (row < NE + NM) { src = hm; ti = 1; lr = row - NE; }
        else                    { src = hr; ti = 2; lr = row - NE - NM; }
        float2 x = *(const float2*)(src + (size_t)lr * 128 + lane * 2);
        float s = x.x + x.y;
#pragma unroll
        for (int o = 32; o; o >>= 1) s += __shfl_xor(s, o);
        float mean = s * (1.0f / 128.0f);
        float dx = x.x - mean, dy = x.y - mean;
        float v = dx * dx + dy * dy;
#pragma unroll
        for (int o = 32; o; o >>= 1) v += __shfl_xor(v, o);
        float rstd = rsqrtf(v * (1.0f / 128.0f) + 1e-5f);
        int c = lane * 2;
        float y0 = g1[ti * 128 + c]     * dx * rstd + b1g[ti * 128 + c];
        float y1 = g1[ti * 128 + c + 1] * dy * rstd + b1g[ti * 128 + c + 1];
        nout[(size_t)row * 64 + lane] = pk2(y0, y1);
    } else if (blk < LN1_BLK + SQ_BLK) {
        int i = (blk - LN1_BLK) * 256 + t;          // [0, 131072)
        int mat = i >> 14, r = i & 16383;
        int frag = r >> 9, lane = (r >> 3) & 63, j = r & 7;
        int nf = frag >> 2, ks = frag & 3;
        int n = nf * 16 + (lane & 15);
        int k = ks * 32 + (lane >> 4) * 8 + j;
        const float* src = (mat < 3) ? (wp + mat * 16384) : (wl + (mat - 3) * 16384);
        wbf[i] = f2bf(src[k * 128 + n]);
    } else if (blk < LN1_BLK + SQ_BLK + F8_BLK) {
        int i = (blk - LN1_BLK - SQ_BLK) * 256 + t; // [0, 393216)
        float v;
        if (i < 196608) {                           // w1 fp8
            int mat = i >> 16, r = i & 65535;
            int frag = r >> 9, lane = (r >> 3) & 63, j = r & 7;
            int nf = frag >> 2, ks = frag & 3;
            int n = nf * 16 + (lane & 15);
            int k = ks * 32 + (lane >> 4) * 8 + j;
            v = w1[mat * 65536 + k * 512 + n];
        } else {                                    // w2 fp8
            int ii = i - 196608;
            int mat = ii >> 16, r = ii & 65535;
            int frag = r >> 9, lane = (r >> 3) & 63, j = r & 7;
            int ks = frag >> 3, nf = frag & 7;
            int n = nf * 16 + (lane & 15);
            int k = ks * 32 + (lane >> 4) * 8 + j;
            v = w2[mat * 65536 + k * 128 + n];
        }
        wbf8[i] = (unsigned char)(__builtin_amdgcn_cvt_pk_fp8_f32(v, 0.f, 0u, false) & 0xffu);
    } else {
        const int wi[7]  = {0, 2, 0, 1, 2, 3, 4};
        const int loi[7] = {0, 2, 0, 1, 2, 3, 4};
        const int lod[7] = {1, 1, 0, 0, 0, 0, 0};
        const int hii[7] = {-1, -1, -1, 1, -1, 3, 4};
        int bid = blk - LN1_BLK - SQ_BLK - F8_BLK;
        int site = bid >> 2, ks = bid & 3;
        const float* W = wl + wi[site] * 16384;
#pragma unroll
        for (int rep = 0; rep < 2; ++rep) {
            int e = t * 2 + rep;
            int lane = e >> 3, j = e & 7;
            int n = lane & 15;
            int k = ks * 32 + (lane >> 4) * 8 + j;
            float v = 0.f;
            if (n < 4) {
                const float* a = (lod[site] ? a_dst : a_src) + loi[site] * 128;
#pragma unroll 8
                for (int d = 0; d < 32; ++d) v += W[k * 128 + n * 32 + d] * a[n * 32 + d];
            } else if (n < 8 && hii[site] >= 0) {
                const float* a = a_dst + hii[site] * 128;
                int hh = n - 4;
#pragma unroll 8
                for (int d = 0; d < 32; ++d) v += W[k * 128 + hh * 32 + d] * a[hh * 32 + d];
            }
            wq[((site * 4 + ks) * 64 + lane) * 8 + j] = f2bf(v);
        }
    }
}

// ---------------------------------------------------------------------------
// Paired GEMM (unchanged).
// ---------------------------------------------------------------------------
struct G2 {
    const unsigned short *A0, *Wt0; const float* b0; unsigned short* Z0;
    const unsigned short* Q0; float *oa0, *ob0;
    const unsigned short *A1, *Wt1; const float* b1; unsigned short* Z1;
    const unsigned short* Q1; float *oa1, *ob1;
    int n0;
};

__global__ __launch_bounds__(256) void gemm_pair(G2 P)
{
    __shared__ unsigned short WL[16384];
    int t = threadIdx.x, w = t >> 6, l = t & 63;
    int l15 = l & 15, lq = l >> 4;
    int e = (blockIdx.x >= P.n0) ? 1 : 0;
    const unsigned short* A  = e ? P.A1 : P.A0;
    const unsigned short* Wt = e ? P.Wt1 : P.Wt0;
    const float* bias        = e ? P.b1 : P.b0;
    unsigned short* Zp       = e ? P.Z1 : P.Z0;
    const unsigned short* WQ = e ? P.Q1 : P.Q0;
    float* oa                = e ? P.oa1 : P.oa0;
    float* ob                = e ? P.ob1 : P.ob0;
    int lb = blockIdx.x - (e ? P.n0 : 0);
#pragma unroll
    for (int i = 0; i < 8; ++i)
        gll16(Wt + i * 2048 + t * 8, (char*)WL + i * 4096 + t * 16);
    size_t row0 = (size_t)lb * 128 + w * 32;
    f32x4 acc[2][8]; f32x4 accl[2];
#pragma unroll
    for (int r = 0; r < 2; ++r) {
        accl[r] = (f32x4){0.f, 0.f, 0.f, 0.f};
#pragma unroll
        for (int n = 0; n < 8; ++n) acc[r][n] = (f32x4){0.f, 0.f, 0.f, 0.f};
    }
    bool haslog = (WQ != nullptr);
    bf16x8 qf[4];
    if (haslog) {
#pragma unroll
        for (int ks = 0; ks < 4; ++ks) qf[ks] = *(const bf16x8*)(WQ + (ks * 64 + l) * 8);
    }
    __syncthreads();
#pragma unroll
    for (int ks = 0; ks < 4; ++ks) {
        int k0 = ks * 32 + lq * 8;
        bf16x8 a0 = *(const bf16x8*)(A + (row0 + l15) * 128 + k0);
        bf16x8 a1 = *(const bf16x8*)(A + (row0 + 16 + l15) * 128 + k0);
#pragma unroll
        for (int n = 0; n < 8; ++n) {
            bf16x8 bw = *(const bf16x8*)(WL + ((n * 4 + ks) * 64 + l) * 8);
            acc[0][n] = __builtin_amdgcn_mfma_f32_16x16x32_bf16(a0, bw, acc[0][n], 0, 0, 0);
            acc[1][n] = __builtin_amdgcn_mfma_f32_16x16x32_bf16(a1, bw, acc[1][n], 0, 0, 0);
        }
        if (haslog) {
            accl[0] = __builtin_amdgcn_mfma_f32_16x16x32_bf16(a0, qf[ks], accl[0], 0, 0, 0);
            accl[1] = __builtin_amdgcn_mfma_f32_16x16x32_bf16(a1, qf[ks], accl[1], 0, 0, 0);
        }
    }
    bool hasb = (bias != nullptr);
#pragma unroll
    for (int n = 0; n < 4; ++n) {
        float bl = hasb ? bias[n * 16 + l15] : 0.f;
        float bh = hasb ? bias[n * 16 + l15 + 64] : 0.f;
#pragma unroll
        for (int r = 0; r < 2; ++r)
#pragma unroll
            for (int reg = 0; reg < 4; ++reg) {
                size_t row = row0 + r * 16 + lq * 4 + reg;
                Zp[row * 64 + n * 16 + l15] = pkfp8(acc[r][n][reg] + bl, acc[r][n + 4][reg] + bh);
            }
    }
    if (haslog) {
#pragma unroll
        for (int r = 0; r < 2; ++r)
#pragma unroll
            for (int reg = 0; reg < 4; ++reg) {
                size_t row = row0 + r * 16 + lq * 4 + reg;
                if (oa && l15 < 4) oa[row * 4 + l15] = accl[r][reg];
                else if (ob && l15 >= 4 && l15 < 8) ob[row * 4 + (l15 - 4)] = accl[r][reg];
            }
    }
}

// ---------------------------------------------------------------------------
// CSR build, two-level bucket partition (unchanged).
// ---------------------------------------------------------------------------
struct P8 { const int* a[8]; };
#define CHUNK 2048

__global__ __launch_bounds__(256) void bucket_count(P8 dsts, unsigned* __restrict__ bcnt)
{
    __shared__ unsigned lh[256];
    int blk = blockIdx.x, rel = blk >> 7, cb = blk & 127, t = threadIdx.x;
    lh[t] = 0; __syncthreads();
    const int* dp = dsts.a[rel] + cb * CHUNK;
#pragma unroll
    for (int it = 0; it < 8; ++it) atomicAdd(&lh[dp[it * 256 + t] >> 8], 1u);
    __syncthreads();
    atomicAdd(&bcnt[rel * 256 + t], lh[t]);
}

__global__ __launch_bounds__(256) void scanB(const unsigned* __restrict__ bcnt,
                                             unsigned* __restrict__ bbase,
                                             unsigned* __restrict__ bcur)
{
    __shared__ unsigned ts[256];
    int t = threadIdx.x;
    unsigned v[8]; unsigned run = 0;
#pragma unroll
    for (int i = 0; i < 8; ++i) { v[i] = bcnt[t * 8 + i]; run += v[i]; }
    ts[t] = run; __syncthreads();
    for (int off = 1; off < 256; off <<= 1) {
        unsigned x = (t >= off) ? ts[t - off] : 0u;
        __syncthreads(); ts[t] += x; __syncthreads();
    }
    unsigned base = ts[t] - run;
#pragma unroll
    for (int i = 0; i < 8; ++i) { bbase[t * 8 + i] = base; bcur[t * 8 + i] = base; base += v[i]; }
    if (t == 255) bbase[2048] = base;
}

__global__ __launch_bounds__(256) void bucket_fill(P8 dsts, P8 srcs,
                                                   unsigned* __restrict__ bcur,
                                                   unsigned long long* __restrict__ bb)
{
    __shared__ unsigned lh[256], lbase[256], lcur[256];
    int blk = blockIdx.x, rel = blk >> 7, cb = blk & 127, t = threadIdx.x;
    lh[t] = 0; lcur[t] = 0; __syncthreads();
    const int* dp = dsts.a[rel] + cb * CHUNK;
    const int* sp = srcs.a[rel] + cb * CHUNK;
    int dv[8];
#pragma unroll
    for (int it = 0; it < 8; ++it) { dv[it] = dp[it * 256 + t]; atomicAdd(&lh[dv[it] >> 8], 1u); }
    __syncthreads();
    lbase[t] = atomicAdd(&bcur[rel * 256 + t], lh[t]);
    __syncthreads();
#pragma unroll
    for (int it = 0; it < 8; ++it) {
        unsigned e = (unsigned)(cb * CHUNK + it * 256 + t);
        unsigned d = (unsigned)dv[it];
        unsigned s = (unsigned)sp[it * 256 + t];
        unsigned pos = atomicAdd(&lcur[d >> 8], 1u);
        bb[lbase[d >> 8] + pos] =
            (unsigned long long)s | ((unsigned long long)d << 16) | ((unsigned long long)e << 32);
    }
}

// fused bucket_hist + scan1
__global__ __launch_bounds__(256) void hist_scan(const unsigned long long* __restrict__ bb,
                                                 const unsigned* __restrict__ bbase,
                                                 unsigned* __restrict__ rowptr,
                                                 unsigned* __restrict__ blksum)
{
    __shared__ unsigned lh[256], s[256];
    int blk = blockIdx.x, rel = blk >> 8, b = blk & 255, t = threadIdx.x;
    lh[t] = 0; __syncthreads();
    unsigned s0 = bbase[blk], s1 = bbase[blk + 1];
    for (unsigned i = s0 + t; i < s1; i += 256)
        atomicAdd(&lh[(unsigned)(bb[i] >> 16) & 255u], 1u);
    __syncthreads();
    unsigned v = lh[t];
    s[t] = v; __syncthreads();
    for (int off = 1; off < 256; off <<= 1) {
        unsigned x = (t >= off) ? s[t - off] : 0u;
        __syncthreads();
        s[t] += x;
        __syncthreads();
    }
    rowptr[(size_t)rel * RPS + b * 256 + t] = s[t] - v;
    if (t == 255) blksum[rel * 256 + b] = s[255];
}

__global__ __launch_bounds__(256) void scan2(unsigned* __restrict__ blksum,
                                             unsigned* __restrict__ rowptr)
{
    __shared__ unsigned s[256];
    int rel = blockIdx.x, t = threadIdx.x;
    unsigned v = blksum[rel * 256 + t];
    s[t] = v; __syncthreads();
    for (int off = 1; off < 256; off <<= 1) {
        unsigned x = (t >= off) ? s[t - off] : 0u;
        __syncthreads();
        s[t] += x;
        __syncthreads();
    }
    blksum[rel * 256 + t] = s[t] - v;
    if (t == 255) rowptr[(size_t)rel * RPS + 65536] = s[255];
}

// fused scan3 + bucket_place
__global__ __launch_bounds__(256) void scan3_place(const unsigned long long* __restrict__ bb,
                                                   const unsigned* __restrict__ bbase,
                                                   unsigned* __restrict__ rowptr,
                                                   const unsigned* __restrict__ blksum,
                                                   int2* __restrict__ epair)
{
    __shared__ unsigned lrp[256], lcur[256];
    int blk = blockIdx.x, rel = blk >> 8, b = blk & 255, t = threadIdx.x;
    unsigned fin = rowptr[(size_t)rel * RPS + b * 256 + t] + blksum[rel * 256 + b];
    rowptr[(size_t)rel * RPS + b * 256 + t] = fin;
    lrp[t] = fin; lcur[t] = 0; __syncthreads();
    unsigned s0 = bbase[blk], s1 = bbase[blk + 1];
    for (unsigned i = s0 + t; i < s1; i += 256) {
        unsigned long long pk = bb[i];
        unsigned s = (unsigned)pk & 0xffffu;
        unsigned d8 = (unsigned)(pk >> 16) & 255u;
        unsigned e = (unsigned)(pk >> 32);
        unsigned pos = atomicAdd(&lcur[d8], 1u);
        epair[(size_t)rel * E2 + lrp[d8] + pos] = make_int2((int)s, (int)e);
    }
}

// ---------------------------------------------------------------------------
// Per-edge (ef @ M) EDGE-ORDERED, packed bf16x4.
// ---------------------------------------------------------------------------
__global__ __launch_bounds__(256) void ef4e_kernel(
    const float* __restrict__ efm, const float* __restrict__ efs,
    const float* __restrict__ efb, const float* __restrict__ eft,
    const float* __restrict__ we, const float* __restrict__ ae,
    uint2* __restrict__ ef4e)
{
    __shared__ float M[8][4];
    int b = blockIdx.x, t = threadIdx.x;
    int er = b >> 10;
    const float* ef = (er == 0) ? efm : (er == 1) ? efs : (er == 2) ? efb : eft;
    if (t < 32) {
        int f = t >> 2, hh = t & 3;
        float s = 0.f;
#pragma unroll 8
        for (int d = 0; d < 32; ++d) s += we[er * 1024 + f * 128 + hh * 32 + d] * ae[er * 128 + hh * 32 + d];
        M[f][hh] = s;
    }
    __syncthreads();
    int e = (b & 1023) * 256 + t;
    float4 a = *(const float4*)(ef + (size_t)e * 8);
    float4 c = *(const float4*)(ef + (size_t)e * 8 + 4);
    float o0 = a.x*M[0][0]+a.y*M[1][0]+a.z*M[2][0]+a.w*M[3][0]+c.x*M[4][0]+c.y*M[5][0]+c.z*M[6][0]+c.w*M[7][0];
    float o1 = a.x*M[0][1]+a.y*M[1][1]+a.z*M[2][1]+a.w*M[3][1]+c.x*M[4][1]+c.y*M[5][1]+c.z*M[6][1]+c.w*M[7][1];
    float o2 = a.x*M[0][2]+a.y*M[1][2]+a.z*M[2][2]+a.w*M[3][2]+c.x*M[4][2]+c.y*M[5][2]+c.z*M[6][2]+c.w*M[7][2];
    float o3 = a.x*M[0][3]+a.y*M[1][3]+a.z*M[2][3]+a.w*M[3][3]+c.x*M[4][3]+c.y*M[5][3]+c.z*M[6][3]+c.w*M[7][3];
    uint2 o; o.x = pk2(o0, o1); o.y = pk2(o2, o3);
    ef4e[(size_t)er * E2 + e] = o;
}

// ---------------------------------------------------------------------------
// Quarter-wave segment helpers (unchanged).
// ---------------------------------------------------------------------------
__device__ __forceinline__ void phys_seg16(
    const unsigned* __restrict__ rowptr, const int2* __restrict__ epair,
    const unsigned short* __restrict__ Zp, int d, unsigned m,
    float rlo[4], float rhi[4])
{
    unsigned s0 = rowptr[d], s1 = rowptr[d + 1];
    float alo[4] = {0, 0, 0, 0}, ahi[4] = {0, 0, 0, 0};
    for (unsigned base = s0; base < s1; base += 4) {
        unsigned nb = s1 - base; if (nb > 4) nb = 4;
        int2 ep[4];
#pragma unroll
        for (int i = 0; i < 4; ++i)
            ep[i] = epair[base + ((unsigned)i < nb ? (unsigned)i : nb - 1)];
        uint2 zv[4];
#pragma unroll
        for (int i = 0; i < 4; ++i)
            zv[i] = ((const uint2*)(Zp + ((unsigned)ep[i].x << 6)))[m];
#pragma unroll
        for (int i = 0; i < 4; ++i) {
            if ((unsigned)i >= nb) break;
            f32x2 a0 = __builtin_amdgcn_cvt_pk_f32_fp8(zv[i].x, false);
            f32x2 a1 = __builtin_amdgcn_cvt_pk_f32_fp8(zv[i].x, true);
            f32x2 a2 = __builtin_amdgcn_cvt_pk_f32_fp8(zv[i].y, false);
            f32x2 a3 = __builtin_amdgcn_cvt_pk_f32_fp8(zv[i].y, true);
            alo[0] += a0.x; ahi[0] += a0.y;
            alo[1] += a1.x; ahi[1] += a1.y;
            alo[2] += a2.x; ahi[2] += a2.y;
            alo[3] += a3.x; ahi[3] += a3.y;
        }
    }
    int cnt = (int)(s1 - s0);
    float inv = 1.0f / (float)(cnt > 0 ? cnt : 1);
#pragma unroll
    for (int j = 0; j < 4; ++j) { rlo[j] += alo[j] * inv; rhi[j] += ahi[j] * inv; }
}

template <bool HAS_EF>
__device__ __forceinline__ void gat_seg16(
    const unsigned* __restrict__ rowptr, const int2* __restrict__ epair,
    const unsigned short* __restrict__ Zp, const float* __restrict__ ls,
    const float* __restrict__ ld, const uint2* __restrict__ ef4e,
    int d, unsigned m, int hs, float rlo[4], float rhi[4])
{
    float4 ldv4 = *(const float4*)(ld + ((unsigned)d << 2));
    float ldlo = hs ? ldv4.y : ldv4.x;
    float ldhi = hs ? ldv4.w : ldv4.z;
    unsigned s0 = rowptr[d], s1 = rowptr[d + 1];
    float nlo[4] = {0, 0, 0, 0}, nhi[4] = {0, 0, 0, 0};
    float dlo = 0.f, dhi = 0.f;
    for (unsigned base = s0; base < s1; base += 4) {
        unsigned nb = s1 - base; if (nb > 4) nb = 4;
        int2 ep[4];
#pragma unroll
        for (int i = 0; i < 4; ++i)
            ep[i] = epair[base + ((unsigned)i < nb ? (unsigned)i : nb - 1)];
        uint2 zv[4]; float4 lsv[4]; uint2 e4[4];
#pragma unroll
        for (int i = 0; i < 4; ++i) {
            zv[i] = ((const uint2*)(Zp + ((unsigned)ep[i].x << 6)))[m];
            lsv[i] = *(const float4*)(ls + ((unsigned)ep[i].x << 2));
            if (HAS_EF) e4[i] = ef4e[(unsigned)ep[i].y];
        }
#pragma unroll
        for (int i = 0; i < 4; ++i) {
            if ((unsigned)i >= nb) break;
            float glo = (hs ? lsv[i].y : lsv[i].x) + ldlo;
            float ghi = (hs ? lsv[i].w : lsv[i].z) + ldhi;
            if (HAS_EF) {
                glo += bf2f(hs ? (e4[i].x >> 16) : (e4[i].x & 0xffffu));
                ghi += bf2f(hs ? (e4[i].y >> 16) : (e4[i].y & 0xffffu));
            }
            glo = glo > 0.f ? glo : 0.2f * glo;
            ghi = ghi > 0.f ? ghi : 0.2f * ghi;
            float xlo = __expf(glo), xhi = __expf(ghi);
            f32x2 a0 = __builtin_amdgcn_cvt_pk_f32_fp8(zv[i].x, false);
            f32x2 a1 = __builtin_amdgcn_cvt_pk_f32_fp8(zv[i].x, true);
            f32x2 a2 = __builtin_amdgcn_cvt_pk_f32_fp8(zv[i].y, false);
            f32x2 a3 = __builtin_amdgcn_cvt_pk_f32_fp8(zv[i].y, true);
            nlo[0] += xlo * a0.x; nhi[0] += xhi * a0.y;
            nlo[1] += xlo * a1.x; nhi[1] += xhi * a1.y;
            nlo[2] += xlo * a2.x; nhi[2] += xhi * a2.y;
            nlo[3] += xlo * a3.x; nhi[3] += xhi * a3.y;
            dlo += xlo; dhi += xhi;
        }
    }
    float ilo = 1.0f / fmaxf(dlo, 1e-9f), ihi = 1.0f / fmaxf(dhi, 1e-9f);
#pragma unroll
    for (int j = 0; j < 4; ++j) { rlo[j] += nlo[j] * ilo; rhi[j] += nhi[j] * ihi; }
}

__device__ __forceinline__ void acc_write16(
    unsigned* __restrict__ accp, int d, unsigned m, bool acc,
    float rlo[4], float rhi[4])
{
    uint4* ap = (uint4*)(accp + ((unsigned)d << 6)) + m;
    if (acc) {
        uint4 o = *ap;
        rlo[0] += bf2f(o.x & 0xffffu); rhi[0] += bf2f(o.x >> 16);
        rlo[1] += bf2f(o.y & 0xffffu); rhi[1] += bf2f(o.y >> 16);
        rlo[2] += bf2f(o.z & 0xffffu); rhi[2] += bf2f(o.z >> 16);
        rlo[3] += bf2f(o.w & 0xffffu); rhi[3] += bf2f(o.w >> 16);
    }
    uint4 nv;
    nv.x = pk2(rlo[0], rhi[0]); nv.y = pk2(rlo[1], rhi[1]);
    nv.z = pk2(rlo[2], rhi[2]); nv.w = pk2(rlo[3], rhi[3]);
    *ap = nv;
}

template <bool ACC>
__global__ __launch_bounds__(256) void phys_gather(
    const unsigned* __restrict__ rowptr, const int2* __restrict__ epair,
    const unsigned short* __restrict__ Zp, unsigned* __restrict__ accp, int n_nodes)
{
    int t = threadIdx.x;
    unsigned m = (unsigned)(t & 15);
    int d = blockIdx.x * 16 + (t >> 4);
    if (d >= n_nodes) return;
    float rlo[4] = {0, 0, 0, 0}, rhi[4] = {0, 0, 0, 0};
    phys_seg16(rowptr, epair, Zp, d, m, rlo, rhi);
    acc_write16(accp, d, m, ACC, rlo, rhi);
}

template <bool ACC>
__global__ __launch_bounds__(256) void dual_phys(
    const unsigned* __restrict__ rpA, const int2* __restrict__ epA,
    const unsigned short* __restrict__ ZA,
    const unsigned* __restrict__ rpB, const int2* __restrict__ epB,
    const unsigned short* __restrict__ ZB,
    unsigned* __restrict__ accp, int n_nodes)
{
    int t = threadIdx.x;
    unsigned m = (unsigned)(t & 15);
    int d = blockIdx.x * 16 + (t >> 4);
    if (d >= n_nodes) return;
    float rlo[4] = {0, 0, 0, 0}, rhi[4] = {0, 0, 0, 0};
    phys_seg16(rpA, epA, ZA, d, m, rlo, rhi);
    phys_seg16(rpB, epB, ZB, d, m, rlo, rhi);
    acc_write16(accp, d, m, ACC, rlo, rhi);
}

template <bool EF, bool ACC>
__global__ __launch_bounds__(256) void gat_gather(
    const unsigned* __restrict__ rowptr, const int2* __restrict__ epair,
    const unsigned short* __restrict__ Zp, const float* __restrict__ ls,
    const float* __restrict__ ld, const uint2* __restrict__ ef4e,
    unsigned* __restrict__ accp, int n_nodes)
{
    int t = threadIdx.x;
    unsigned m = (unsigned)(t & 15);
    int d = blockIdx.x * 16 + (t >> 4);
    if (d >= n_nodes) return;
    int hs = (int)(m >> 3);
    float rlo[4] = {0, 0, 0, 0}, rhi[4] = {0, 0, 0, 0};
    gat_seg16<EF>(rowptr, epair, Zp, ls, ld, ef4e, d, m, hs, rlo, rhi);
    acc_write16(accp, d, m, ACC, rlo, rhi);
}

template <bool EFA, bool EFB, bool ACC>
__global__ __launch_bounds__(256) void dual_gat(
    const unsigned* __restrict__ rpA, const int2* __restrict__ epA,
    const unsigned short* __restrict__ ZA, const float* __restrict__ lsA,
    const float* __restrict__ ldA, const uint2* __restrict__ efA,
    const unsigned* __restrict__ rpB, const int2* __restrict__ epB,
    const unsigned short* __restrict__ ZB, const float* __restrict__ lsB,
    const float* __restrict__ ldB, const uint2* __restrict__ efB,
    unsigned* __restrict__ accp, int n_nodes)
{
    int t = threadIdx.x;
    unsigned m = (unsigned)(t & 15);
    int d = blockIdx.x * 16 + (t >> 4);
    if (d >= n_nodes) return;
    int hs = (int)(m >> 3);
    float rlo[4] = {0, 0, 0, 0}, rhi[4] = {0, 0, 0, 0};
    gat_seg16<EFA>(rpA, epA, ZA, lsA, ldA, efA, d, m, hs, rlo, rhi);
    gat_seg16<EFB>(rpB, epB, ZB, lsB, ldB, efB, d, m, hs, rlo, rhi);
    acc_write16(accp, d, m, ACC, rlo, rhi);
}

// ---------------------------------------------------------------------------
// Merged FFN v4: FP8 weights/MFMA, 64 rows/block (1 row-frag/wave), grid 2304
// -> ~9 blocks/CU queued, 6 resident (24 KB LDS).  Same chunk/stage structure.
// ---------------------------------------------------------------------------
struct FP {
    const float* h[3]; const unsigned* ac[3];
    const float* g[3]; const float* b[3];
    const unsigned char* w1[3]; const float* bb1[3];
    const unsigned char* w2[3]; const float* bb2[3];
    float* out[3]; float invC[3];
    int n1, n2;
};

__global__ __launch_bounds__(256, 4) void ffn_all(FP P)
{
    __shared__ unsigned char WB[2][8192];   // 2 x (4KB w1-chunk + 4KB w2-chunk)
    __shared__ float HW[4][512];            // per-wave 16x32 f32, swizzled
    int blk = blockIdx.x;
    int ti = (blk >= P.n2) ? 2 : (blk >= P.n1) ? 1 : 0;
    int lb = blk - (ti == 2 ? P.n2 : ti == 1 ? P.n1 : 0);
    const float* h = P.h[ti];
    const unsigned* accp = P.ac[ti];
    const float* g = P.g[ti];
    const float* b = P.b[ti];
    const unsigned char* w1p = P.w1[ti];
    const float* b1 = P.bb1[ti];
    const unsigned char* w2p = P.w2[ti];
    const float* b2 = P.bb2[ti];
    float* out = P.out[ti];
    float invC = P.invC[ti];

    int t = threadIdx.x, w = t >> 6, l = t & 63;
    int l15 = l & 15, lq = l >> 4;
    size_t rw = (size_t)lb * 64 + w * 16;
    float* myHW = HW[w];

    // ---- LN + A-frag pack (fp8) for the wave's 16 rows
    long afq[4];
    {
        size_t myrow = rw + l15;
        const unsigned* ap = accp + myrow * 64 + lq * 8;
        uint4 ua0 = *(const uint4*)(ap);
        uint4 ua1 = *(const uint4*)(ap + 4);
        uint4 ub0 = *(const uint4*)(ap + 32);
        uint4 ub1 = *(const uint4*)(ap + 36);
        const float* hp = h + myrow * 128 + lq * 8;
        float4 hf[4][2];
        hf[0][0] = *(const float4*)(hp);      hf[0][1] = *(const float4*)(hp + 4);
        hf[1][0] = *(const float4*)(hp + 32); hf[1][1] = *(const float4*)(hp + 36);
        hf[2][0] = *(const float4*)(hp + 64); hf[2][1] = *(const float4*)(hp + 68);
        hf[3][0] = *(const float4*)(hp + 96); hf[3][1] = *(const float4*)(hp + 100);
        unsigned ua[8] = {ua0.x, ua0.y, ua0.z, ua0.w, ua1.x, ua1.y, ua1.z, ua1.w};
        unsigned ub[8] = {ub0.x, ub0.y, ub0.z, ub0.w, ub1.x, ub1.y, ub1.z, ub1.w};
        float hv[4][8];
#pragma unroll
        for (int j = 0; j < 8; ++j) {
            hv[0][j] = ((const float*)hf[0])[j] + bf2f(ua[j] & 0xffffu) * invC;
            hv[1][j] = ((const float*)hf[1])[j] + bf2f(ub[j] & 0xffffu) * invC;
            hv[2][j] = ((const float*)hf[2])[j] + bf2f(ua[j] >> 16) * invC;
            hv[3][j] = ((const float*)hf[3])[j] + bf2f(ub[j] >> 16) * invC;
        }
        float s = 0.f;
#pragma unroll
        for (int ks = 0; ks < 4; ++ks)
#pragma unroll
            for (int j = 0; j < 8; ++j) s += hv[ks][j];
        s += __shfl_xor(s, 16); s += __shfl_xor(s, 32);
        float mean = s * (1.0f / 128.0f);
        float v = 0.f;
#pragma unroll
        for (int ks = 0; ks < 4; ++ks)
#pragma unroll
            for (int j = 0; j < 8; ++j) { float dd = hv[ks][j] - mean; v += dd * dd; }
        v += __shfl_xor(v, 16); v += __shfl_xor(v, 32);
        float rstd = rsqrtf(v * (1.0f / 128.0f) + 1e-5f);
#pragma unroll
        for (int ks = 0; ks < 4; ++ks) {
            int col0 = ks * 32 + lq * 8;
            float y[8];
#pragma unroll
            for (int j = 0; j < 8; ++j)
                y[j] = g[col0 + j] * (hv[ks][j] - mean) * rstd + b[col0 + j];
            afq[ks] = pk8f8(y);
        }
    }

    // ---- stage chunk 0 (8 KB: 4 KB w1 + 4 KB w2)
    gll16(w1p + t * 16, (char*)WB[0] + t * 16);
    gll16(w2p + t * 16, (char*)WB[0] + 4096 + t * 16);
    f32x4 facc[8];
#pragma unroll
    for (int n = 0; n < 8; ++n) facc[n] = (f32x4){0.f, 0.f, 0.f, 0.f};
    __syncthreads();

    int buf = 0;
    int swR = (l15 & 7) << 2;
    for (int ch = 0; ch < 16; ++ch) {
        if (ch < 15) {
            gll16(w1p + (ch + 1) * 4096 + t * 16, (char*)WB[buf ^ 1] + t * 16);
            gll16(w2p + (ch + 1) * 4096 + t * 16, (char*)WB[buf ^ 1] + 4096 + t * 16);
        }
        // gemm1: 16 rows x 32 hidden cols (fp8 x fp8)
        f32x4 acc1[2];
#pragma unroll
        for (int n = 0; n < 2; ++n) acc1[n] = (f32x4){0.f, 0.f, 0.f, 0.f};
#pragma unroll
        for (int ks = 0; ks < 4; ++ks)
#pragma unroll
            for (int nfL = 0; nfL < 2; ++nfL) {
                long bw = *(const long*)(WB[buf] + ((nfL * 4 + ks) * 64 + l) * 8);
                acc1[nfL] = __builtin_amdgcn_mfma_f32_16x16x32_fp8_fp8(afq[ks], bw, acc1[nfL], 0, 0, 0);
            }
        // GELU + transpose through 2 KB wave LDS + gemm2
#pragma unroll
        for (int nfL = 0; nfL < 2; ++nfL) {
            float bv = b1[ch * 32 + nfL * 16 + l15];
#pragma unroll
            for (int reg = 0; reg < 4; ++reg) {
                int row = lq * 4 + reg;
                float x = acc1[nfL][reg] + bv;
                myHW[row * 32 + ((nfL * 16 + l15) ^ ((row & 7) << 2))] = gelu(x);
            }
        }
        {
            int cb = lq * 8;
            f32x4 x0 = *(const f32x4*)(myHW + l15 * 32 + (cb ^ swR));
            f32x4 x1 = *(const f32x4*)(myHW + l15 * 32 + ((cb + 4) ^ swR));
            long a2 = pk8f8v(x0, x1);
#pragma unroll
            for (int nf2 = 0; nf2 < 8; ++nf2) {
                long bw = *(const long*)(WB[buf] + 4096 + (nf2 * 64 + l) * 8);
                facc[nf2] = __builtin_amdgcn_mfma_f32_16x16x32_fp8_fp8(a2, bw, facc[nf2], 0, 0, 0);
            }
        }
        __syncthreads();
        buf ^= 1;
    }
    // ---- epilogue: out = h + acc*invC + ffn + b2 (D layout)
#pragma unroll
    for (int nf = 0; nf < 8; ++nf) {
        int col = nf * 16 + l15;
        float bv = b2[col];
        int ci = col & 63;
        bool hi = col >= 64;
#pragma unroll
        for (int reg = 0; reg < 4; ++reg) {
            size_t row = rw + lq * 4 + reg;
            unsigned pv = accp[row * 64 + ci];
            float av = bf2f(hi ? (pv >> 16) : (pv & 0xffffu));
            out[row * 128 + col] = h[row * 128 + col] + av * invC + facc[nf][reg] + bv;
        }
    }
}

// ---------------------------------------------------------------------------
extern "C" void kernel_launch(void* const* d_in, const int* in_sizes, int n_in,
                              void* d_out, int out_size, void* d_ws, size_t ws_size,
                              hipStream_t stream)
{
    const float* h_enz  = (const float*)d_in[0];
    const float* h_met  = (const float*)d_in[1];
    const float* h_rxn  = (const float*)d_in[2];
    const float* ef_mod = (const float*)d_in[3];
    const float* ef_sig = (const float*)d_in[4];
    const float* ef_brg = (const float*)d_in[5];
    const float* ef_trn = (const float*)d_in[6];
    const float* ln1_g  = (const float*)d_in[7];
    const float* ln1_b  = (const float*)d_in[8];
    const float* ln2_g  = (const float*)d_in[9];
    const float* ln2_b  = (const float*)d_in[10];
    const float* wp     = (const float*)d_in[11];
    const float* bp     = (const float*)d_in[12];
    const float* wl     = (const float*)d_in[13];
    const float* a_src  = (const float*)d_in[14];
    const float* a_dst  = (const float*)d_in[15];
    const float* we     = (const float*)d_in[16];
    const float* a_edge = (const float*)d_in[17];
    const float* w1     = (const float*)d_in[18];
    const float* b1     = (const float*)d_in[19];
    const float* w2     = (const float*)d_in[20];
    const float* b2     = (const float*)d_in[21];
    const int* src_sub  = (const int*)d_in[22];
    const int* dst_sub  = (const int*)d_in[23];
    const int* src_prod = (const int*)d_in[24];
    const int* dst_prod = (const int*)d_in[25];
    const int* src_cat  = (const int*)d_in[26];
    const int* dst_cat  = (const int*)d_in[27];
    const int* src_mod  = (const int*)d_in[28];
    const int* dst_mod  = (const int*)d_in[29];
    const int* src_reg  = (const int*)d_in[30];
    const int* dst_reg  = (const int*)d_in[31];
    const int* src_sig  = (const int*)d_in[32];
    const int* dst_sig  = (const int*)d_in[33];
    const int* src_brg  = (const int*)d_in[34];
    const int* dst_brg  = (const int*)d_in[35];
    const int* src_trn  = (const int*)d_in[36];
    const int* dst_trn  = (const int*)d_in[37];
    float* out = (float*)d_out;

    // workspace (~90 MB; proven budget >= 116.6 MB)
    char* p = (char*)d_ws;
    unsigned* accp = (unsigned*)p;            p += (size_t)NTOT * 64 * 4;
    unsigned short* ZpA = (unsigned short*)p; p += (size_t)NM * 64 * 2;
    unsigned long long* bukbuf = (unsigned long long*)p;                      // alias:
    unsigned short* ZpB = (unsigned short*)p; p += (size_t)8 * E2 * 8;
    int2* epair = (int2*)p;                   p += (size_t)8 * E2 * 8;
    uint2* ef4e = (uint2*)p;                  p += (size_t)4 * E2 * 8;
    float* ls3 = (float*)p;                   p += (size_t)NE * 4 * 4;
    float* ld3 = (float*)p;                   p += (size_t)NR * 4 * 4;
    float* ls4 = (float*)p;                   p += (size_t)NE * 4 * 4;
    float* ld4 = (float*)p;                   p += (size_t)NE * 4 * 4;
    float* ls5 = (float*)p;                   p += (size_t)NM * 4 * 4;
    float* ld5 = (float*)p;                   p += (size_t)NE * 4 * 4;
    float* ls6 = (float*)p;                   p += (size_t)NM * 4 * 4;
    float* ld6 = (float*)p;                   p += (size_t)NM * 4 * 4;
    float* ls7 = (float*)p;                   p += (size_t)NM * 4 * 4;
    float* ld7 = (float*)p;                   p += (size_t)NM * 4 * 4;
    unsigned short* wbf = (unsigned short*)p; p += (size_t)131072 * 2;   // square mats bf16
    unsigned char* wbf8 = (unsigned char*)p;  p += (size_t)393216;       // w1/w2 fp8
    unsigned short* wq  = (unsigned short*)p; p += (size_t)7 * 2048 * 2;
    unsigned* rowptr = (unsigned*)p;          p += (size_t)8 * RPS * 4;
    unsigned* bcnt = (unsigned*)p;            p += 2048 * 4;
    unsigned* bbase = (unsigned*)p;           p += 2049 * 4;
    unsigned* bcur = (unsigned*)p;            p += 2048 * 4;
    unsigned* blksum = (unsigned*)p;          p += (size_t)8 * 256 * 4;
    if (ws_size < (size_t)(p - (char*)d_ws)) return;

    unsigned* nrm32 = (unsigned*)d_out;
    const unsigned short* nbf_enz = (const unsigned short*)d_out;
    const unsigned short* nbf_met = nbf_enz + (size_t)NE * 128;
    const unsigned short* nbf_rxn = nbf_enz + (size_t)(NE + NM) * 128;
    unsigned* acc_enz = accp;
    unsigned* acc_met = accp + (size_t)NE * 64;
    unsigned* acc_rxn = accp + (size_t)(NE + NM) * 64;

    P8 dsts, srcs;
    dsts.a[0] = dst_sub;  srcs.a[0] = src_sub;
    dsts.a[1] = dst_prod; srcs.a[1] = src_prod;
    dsts.a[2] = dst_cat;  srcs.a[2] = src_cat;
    dsts.a[3] = dst_mod;  srcs.a[3] = src_mod;
    dsts.a[4] = dst_reg;  srcs.a[4] = src_reg;
    dsts.a[5] = dst_sig;  srcs.a[5] = src_sig;
    dsts.a[6] = dst_brg;  srcs.a[6] = src_brg;
    dsts.a[7] = dst_trn;  srcs.a[7] = src_trn;

    // ---- prep: LN1 + weights (bf16 square + fp8 ffn) + WQ, bucketed CSR, ef.M
    hipMemsetAsync(bcnt, 0, 2048 * 4, stream);
    prep_all<<<LN1_BLK + SQ_BLK + F8_BLK + 28, 256, 0, stream>>>(
        h_enz, h_met, h_rxn, ln1_g, ln1_b, nrm32,
        wp, wl, w1, w2, wbf, wbf8, a_src, a_dst, wq);
    bucket_count<<<1024, 256, 0, stream>>>(dsts, bcnt);
    scanB<<<1, 256, 0, stream>>>(bcnt, bbase, bcur);
    bucket_fill<<<1024, 256, 0, stream>>>(dsts, srcs, bcur, bukbuf);
    hist_scan<<<2048, 256, 0, stream>>>(bukbuf, bbase, rowptr, blksum);
    scan2<<<8, 256, 0, stream>>>(blksum, rowptr);
    scan3_place<<<2048, 256, 0, stream>>>(bukbuf, bbase, rowptr, blksum, epair);
    ef4e_kernel<<<4096, 256, 0, stream>>>(ef_mod, ef_sig, ef_brg, ef_trn, we, a_edge, ef4e);

#define RP(r) (rowptr + (size_t)(r) * RPS)
#define EP(r) (epair + (size_t)(r) * E2)
#define WQS(s) (wq + (size_t)(s) * 2048)
#define EF4(er) (ef4e + (size_t)(er) * E2)

    // ---- pair A: rel0 (met->rxn phys, ZpA) + rel2 (enz->rxn phys + ld5, ZpB)
    {
        G2 P = {nbf_met, wbf + 0 * 16384, bp + 0,   ZpA, nullptr, nullptr, nullptr,
                nbf_enz, wbf + 2 * 16384, bp + 256, ZpB, WQS(1),  ld5,     nullptr,
                NM / 128};
        gemm_pair<<<NM / 128 + NE / 128, 256, 0, stream>>>(P);
    }
    dual_phys<false><<<NR / 16, 256, 0, stream>>>(RP(0), EP(0), ZpA, RP(2), EP(2), ZpB,
                                                  acc_rxn, NR);
    // ---- pair B: rel1 (rxn->met phys + ld3, ZpA) + rel3 (enz->rxn gat ls3, ZpB)
    {
        G2 P = {nbf_rxn, wbf + 1 * 16384, bp + 128, ZpA, WQS(0), ld3, nullptr,
                nbf_enz, wbf + 3 * 16384, nullptr,  ZpB, WQS(2), ls3, nullptr,
                NR / 128};
        gemm_pair<<<NR / 128 + NE / 128, 256, 0, stream>>>(P);
    }
    phys_gather<false><<<NM / 16, 256, 0, stream>>>(RP(1), EP(1), ZpA, acc_met, NM);
    gat_gather<true, true><<<NR / 16, 256, 0, stream>>>(RP(3), EP(3), ZpB, ls3, ld3, EF4(0),
                                                        acc_rxn, NR);
    // ---- pair C: rel4 (enz->enz, ls4/ld4, ZpA) + rel5 (met->enz, ls5, ZpB)
    {
        G2 P = {nbf_enz, wbf + 4 * 16384, nullptr, ZpA, WQS(3), ls4, ld4,
                nbf_met, wbf + 5 * 16384, nullptr, ZpB, WQS(4), ls5, nullptr,
                NE / 128};
        gemm_pair<<<NE / 128 + NM / 128, 256, 0, stream>>>(P);
    }
    dual_gat<false, true, false><<<NE / 16, 256, 0, stream>>>(
        RP(4), EP(4), ZpA, ls4, ld4, nullptr,
        RP(5), EP(5), ZpB, ls5, ld5, EF4(1), acc_enz, NE);
    // ---- pair D: rel6 (met->met, ls6/ld6, ZpA) + rel7 (met->met, ls7/ld7, ZpB)
    {
        G2 P = {nbf_met, wbf + 6 * 16384, nullptr, ZpA, WQS(5), ls6, ld6,
                nbf_met, wbf + 7 * 16384, nullptr, ZpB, WQS(6), ls7, ld7,
                NM / 128};
        gemm_pair<<<NM / 128 + NM / 128, 256, 0, stream>>>(P);
    }
    dual_gat<true, true, true><<<NM / 16, 256, 0, stream>>>(
        RP(6), EP(6), ZpA, ls6, ld6, EF4(2),
        RP(7), EP(7), ZpB, ls7, ld7, EF4(3), acc_met, NM);

    // ---- merged FFN (fp8 weights, 64 rows/block) over all three node types
    {
        FP P;
        P.h[0] = h_enz; P.h[1] = h_met; P.h[2] = h_rxn;
        P.ac[0] = acc_enz; P.ac[1] = acc_met; P.ac[2] = acc_rxn;
        P.g[0] = ln2_g; P.g[1] = ln2_g + 128; P.g[2] = ln2_g + 256;
        P.b[0] = ln2_b; P.b[1] = ln2_b + 128; P.b[2] = ln2_b + 256;
        P.w1[0] = wbf8; P.w1[1] = wbf8 + 65536; P.w1[2] = wbf8 + 2 * 65536;
        P.bb1[0] = b1; P.bb1[1] = b1 + 512; P.bb1[2] = b1 + 1024;
        P.w2[0] = wbf8 + 196608; P.w2[1] = wbf8 + 196608 + 65536; P.w2[2] = wbf8 + 196608 + 2 * 65536;
        P.bb2[0] = b2; P.bb2[1] = b2 + 128; P.bb2[2] = b2 + 256;
        P.out[0] = out; P.out[1] = out + (size_t)NE * 128; P.out[2] = out + (size_t)(NE + NM) * 128;
        P.invC[0] = 0.5f; P.invC[1] = 1.0f / 3.0f; P.invC[2] = 1.0f / 3.0f;
        P.n1 = NE / 64; P.n2 = NE / 64 + NM / 64;
        ffn_all<<<NE / 64 + NM / 64 + NR / 64, 256, 0, stream>>>(P);
    }
#undef RP
#undef EP
#undef WQS
#undef EF4
}